// Round 8
// baseline (1334.144 us; speedup 1.0000x reference)
//
#include <hip/hip_runtime.h>
#include <hip/hip_bf16.h>

// ---------------- model constants ----------------
static constexpr int SEQ   = 2048;
static constexpr int DM    = 2048;
static constexpr int NHEAD = 16;
static constexpr int NKVH  = 8;
static constexpr int HDIM  = 128;
static constexpr int FFN   = 6144;
static constexpr int NLAYER = 2;
static constexpr float EPSV = 1e-6f;
static constexpr int QKVN  = NHEAD * HDIM + 2 * NKVH * HDIM;  // 4096 fused QKV cols

typedef __attribute__((ext_vector_type(8))) short bf16x8;
typedef __attribute__((ext_vector_type(4))) float f32x4;

__device__ __forceinline__ float wave_sum(float v) {
#pragma unroll
    for (int o = 32; o > 0; o >>= 1) v += __shfl_xor(v, o);
    return v;
}

// async global->LDS, 16B per lane
__device__ __forceinline__ void gload16(const void* g, void* l) {
    __builtin_amdgcn_global_load_lds(
        (const __attribute__((address_space(1))) void*)g,
        (__attribute__((address_space(3))) void*)l,
        16, 0, 0);
}

// ---------------- f32 -> bf16 weight convert ----------------
__global__ void cvt_bf16_k(const float* __restrict__ in, __hip_bfloat16* __restrict__ out) {
    const long b = ((long)blockIdx.x * 256 + threadIdx.x) * 8;
    const float4 a0 = *(const float4*)(in + b);
    const float4 a1 = *(const float4*)(in + b + 4);
    union { bf16x8 v; __hip_bfloat16 h[8]; } u;
    u.h[0] = __float2bfloat16(a0.x); u.h[1] = __float2bfloat16(a0.y);
    u.h[2] = __float2bfloat16(a0.z); u.h[3] = __float2bfloat16(a0.w);
    u.h[4] = __float2bfloat16(a1.x); u.h[5] = __float2bfloat16(a1.y);
    u.h[6] = __float2bfloat16(a1.z); u.h[7] = __float2bfloat16(a1.w);
    *(bf16x8*)(out + b) = u.v;
}

// ---------------- embedding gather ----------------
__global__ void embed_k(const int* __restrict__ ids, const float* __restrict__ emb,
                        float* __restrict__ h) {
    const int s = blockIdx.x;
    const long src = (long)ids[s] * DM;
    for (int t = threadIdx.x; t < DM; t += 256)
        h[(long)s * DM + t] = emb[src + t];
}

// ---------------- RMSNorm (f32 in -> bf16 out) ----------------
__global__ void rmsnorm_k(const float* __restrict__ in, const float* __restrict__ g,
                          __hip_bfloat16* __restrict__ out) {
    const int row = blockIdx.x;
    const float* r = in + (long)row * DM;
    const int tid = threadIdx.x;
    float v[8];
    float ss = 0.f;
#pragma unroll
    for (int t = 0; t < 8; ++t) { v[t] = r[tid + t * 256]; ss += v[t] * v[t]; }
    ss = wave_sum(ss);
    __shared__ float sp[4];
    if ((tid & 63) == 0) sp[tid >> 6] = ss;
    __syncthreads();
    ss = sp[0] + sp[1] + sp[2] + sp[3];
    const float inv = rsqrtf(ss * (1.f / DM) + EPSV);
    __hip_bfloat16* o_ = out + (long)row * DM;
#pragma unroll
    for (int t = 0; t < 8; ++t) {
        const int j = tid + t * 256;
        o_[j] = __float2bfloat16(v[t] * inv * g[j]);
    }
}

// ---------------- fused: h += sum of 4 split-K partials; x = rmsnorm(h)*g ----------------
__global__ void rmsnorm_res4_k(const float* __restrict__ part, long n,
                               float* __restrict__ h, const float* __restrict__ g,
                               __hip_bfloat16* __restrict__ x) {
    const int row = blockIdx.x;
    const int tid = threadIdx.x;
    float v[8];
    float ss = 0.f;
#pragma unroll
    for (int t = 0; t < 8; ++t) {
        const long idx = (long)row * DM + tid + t * 256;
        float s = h[idx];
#pragma unroll
        for (int z = 0; z < 4; ++z) s += part[(long)z * n + idx];
        h[idx] = s;
        v[t] = s;
        ss += s * s;
    }
    ss = wave_sum(ss);
    __shared__ float sp[4];
    if ((tid & 63) == 0) sp[tid >> 6] = ss;
    __syncthreads();
    ss = sp[0] + sp[1] + sp[2] + sp[3];
    const float inv = rsqrtf(ss * (1.f / DM) + EPSV);
    __hip_bfloat16* o_ = x + (long)row * DM;
#pragma unroll
    for (int t = 0; t < 8; ++t) {
        const int j = tid + t * 256;
        o_[j] = __float2bfloat16(v[t] * inv * g[j]);
    }
}

// ---------------- h += sum of 4 partials (final layer) ----------------
__global__ void red4res_k(const float* __restrict__ p, long n, float* __restrict__ h) {
    const long i = ((long)blockIdx.x * 256 + threadIdx.x) * 4;
    float4 s = *(const float4*)(h + i);
#pragma unroll
    for (int z = 0; z < 4; ++z) {
        const float4 b = *(const float4*)(p + (long)z * n + i);
        s.x += b.x; s.y += b.y; s.z += b.z; s.w += b.w;
    }
    *(float4*)(h + i) = s;
}

// ---------------- per-head RMSNorm + RoPE; input = sum of 2 split-K partials ----------------
// in: [s][QKVN] f32 (+ zStride for partial 1), head row at inOff + hh*HDIM.
// out: [hh][s][128] bf16 (single copy).
__global__ void qknorm_rope_k(const float* __restrict__ in, long zStride, int inOff,
                              const float* __restrict__ ns,
                              const float* __restrict__ cosT, const float* __restrict__ sinT,
                              __hip_bfloat16* __restrict__ out, int nheads) {
    const int idx = blockIdx.x * 4 + (threadIdx.x >> 6);
    const int lane = threadIdx.x & 63;
    const int s = idx / nheads;
    const int hh = idx - s * nheads;
    const long base = (long)s * QKVN + inOff + hh * HDIM;
    const float x1 = in[base + lane]      + in[zStride + base + lane];
    const float x2 = in[base + lane + 64] + in[zStride + base + lane + 64];
    float ss = wave_sum(x1 * x1 + x2 * x2);
    const float inv = rsqrtf(ss * (1.f / HDIM) + EPSV);
    const float n1 = x1 * inv * ns[lane];
    const float n2 = x2 * inv * ns[lane + 64];
    const float c1 = cosT[s * HDIM + lane],      c2 = cosT[s * HDIM + 64 + lane];
    const float s1 = sinT[s * HDIM + lane],      s2 = sinT[s * HDIM + 64 + lane];
    __hip_bfloat16* w = out + ((long)hh * SEQ + s) * HDIM;
    w[lane]      = __float2bfloat16(n1 * c1 - n2 * s1);
    w[lane + 64] = __float2bfloat16(n2 * c2 + n1 * s2);
}

// ---------------- V transpose+convert (2-partial f32 src -> vt [kv][d][s] bf16) ----------------
__global__ void vtrans_k(const float* __restrict__ vf, long zStride, int colOff,
                         __hip_bfloat16* __restrict__ vt) {
    __shared__ float tile[64][65];
    const int s0 = blockIdx.x * 64, d0 = blockIdx.y * 64, kv = blockIdx.z;
    const int lane = threadIdx.x & 63, part = threadIdx.x >> 6;
    for (int r = part; r < 64; r += 4) {
        const long idx = (long)(s0 + r) * QKVN + colOff + kv * HDIM + d0 + lane;
        tile[r][lane] = vf[idx] + vf[zStride + idx];
    }
    __syncthreads();
    for (int r = part; r < 64; r += 4)
        vt[((long)kv * HDIM + d0 + r) * SEQ + s0 + lane] = __float2bfloat16(tile[lane][r]);
}

// ---------------- silu(g)*u elementwise, in place on g ----------------
__global__ void silu_mul_k(__hip_bfloat16* __restrict__ g, const __hip_bfloat16* __restrict__ u) {
    const long i = ((long)blockIdx.x * 256 + threadIdx.x) * 8;
    union { bf16x8 v; __hip_bfloat16 h[8]; } a, b, o;
    a.v = *(const bf16x8*)(g + i);
    b.v = *(const bf16x8*)(u + i);
#pragma unroll
    for (int j = 0; j < 8; ++j) {
        const float xx = __bfloat162float(a.h[j]);
        const float yy = __bfloat162float(b.h[j]);
        const float sv = xx / (1.f + __expf(-xx));
        o.h[j] = __float2bfloat16(sv * yy);
    }
    *(bf16x8*)(g + i) = o.v;
}

// ============== flash attention: block = (head, 64-row q-slab), 4 waves ==============
// qb [H][S][128], kb [KV][S][128], vt [KV][128][S]  (bf16). ctx [S][H*128] bf16.
// Per KV tile (128): stage K,V (swizzled gload16) -> S=Q K^T (MFMA) -> online softmax
// (cross-wave LDS stats) -> P bf16 -> LDS -> O += P V (MFMA). Normalize at end.
__global__ __launch_bounds__(256)
void flash_k(const __hip_bfloat16* __restrict__ qb, const __hip_bfloat16* __restrict__ kb,
             const __hip_bfloat16* __restrict__ vt, __hip_bfloat16* __restrict__ ctx) {
    __shared__ __align__(16) char qs[64 * 256];     // [64 q][128 d]
    __shared__ __align__(16) char ks[128 * 256];    // [128 kv][128 d]
    __shared__ __align__(16) char vs[128 * 256];    // [128 d][128 kv]
    __shared__ __align__(16) char ps[64 * 256];     // [64 q][128 kv]
    __shared__ float m_lds[64], l_lds[64], mn_lds[64], al_lds[64];
    __shared__ float pmax[4][64], psum[4][64];

    const int tid = threadIdx.x;
    const int lane = tid & 63;
    const int wid = tid >> 6;        // wave = d/kv column quarter
    const int l15 = lane & 15;
    const int l4 = lane >> 4;

    const int x = blockIdx.x;        // 0..31: q-slab (64 rows)
    const int h = blockIdx.y;        // 0..15
    const int q0 = x * 64;
    const int kvh = h >> 1;          // GROUP = 2
    const int nkt = (x >> 1) + 1;    // causal kv-tile count
    const float scale = 0.0883883476483184405f;  // 1/sqrt(128)

    // stage Q once (1024 x 16B chunks, st-swizzled)
    {
        const __hip_bfloat16* qg = qb + ((long)h * SEQ + q0) * HDIM;
#pragma unroll
        for (int i = 0; i < 4; ++i) {
            const int c = i * 256 + tid;
            const int r = c >> 4, s = c & 15;
            gload16(qg + (long)r * HDIM + ((s ^ (r & 7)) * 8), qs + c * 16);
        }
    }
    if (tid < 64) { m_lds[tid] = -3.0e38f; l_lds[tid] = 0.f; }

    f32x4 oacc[4][2];
#pragma unroll
    for (int m = 0; m < 4; ++m)
#pragma unroll
        for (int n = 0; n < 2; ++n) oacc[m][n] = (f32x4){0.f, 0.f, 0.f, 0.f};

    for (int kt = 0; kt < nkt; ++kt) {
        const int kv0 = kt * 128;
        // ---- stage K [kv][d] and V^T [d][kv] ----
        const __hip_bfloat16* kg = kb + ((long)kvh * SEQ + kv0) * HDIM;
#pragma unroll
        for (int i = 0; i < 8; ++i) {
            const int c = i * 256 + tid;
            const int r = c >> 4, s = c & 15;
            gload16(kg + (long)r * HDIM + ((s ^ (r & 7)) * 8), ks + c * 16);
        }
        const __hip_bfloat16* vg = vt + (long)kvh * HDIM * SEQ + kv0;
#pragma unroll
        for (int i = 0; i < 8; ++i) {
            const int c = i * 256 + tid;
            const int r = c >> 4, s = c & 15;
            gload16(vg + (long)r * SEQ + ((s ^ (r & 7)) * 8), vs + c * 16);
        }
        __syncthreads();   // drains vmcnt: Q/K/V staged

        // ---- S = Q K^T for this wave's 32 kv cols: frags 4m x 2n x 4k ----
        f32x4 sac[4][2];
#pragma unroll
        for (int m = 0; m < 4; ++m)
#pragma unroll
            for (int n = 0; n < 2; ++n) sac[m][n] = (f32x4){0.f, 0.f, 0.f, 0.f};
#pragma unroll
        for (int kk = 0; kk < 4; ++kk) {
            bf16x8 aq[4], bk[2];
#pragma unroll
            for (int m = 0; m < 4; ++m) {
                const int r = m * 16 + l15;
                aq[m] = *(const bf16x8*)(qs + r * 256 + (((kk * 4 + l4) ^ (r & 7)) << 4));
            }
#pragma unroll
            for (int n = 0; n < 2; ++n) {
                const int r = wid * 32 + n * 16 + l15;
                bk[n] = *(const bf16x8*)(ks + r * 256 + (((kk * 4 + l4) ^ (r & 7)) << 4));
            }
#pragma unroll
            for (int m = 0; m < 4; ++m)
#pragma unroll
                for (int n = 0; n < 2; ++n)
                    sac[m][n] = __builtin_amdgcn_mfma_f32_16x16x32_bf16(aq[m], bk[n], sac[m][n], 0, 0, 0);
        }

        // ---- scale (+ causal mask on diagonal tile) ----
        const bool diag = (kt == nkt - 1);
#pragma unroll
        for (int m = 0; m < 4; ++m)
#pragma unroll
            for (int n = 0; n < 2; ++n)
#pragma unroll
                for (int j = 0; j < 4; ++j) {
                    float v = sac[m][n][j] * scale;
                    if (diag) {
                        const int qg_ = q0 + m * 16 + l4 * 4 + j;
                        const int kg_ = kv0 + wid * 32 + n * 16 + l15;
                        if (kg_ > qg_) v = -3.0e38f;
                    }
                    sac[m][n][j] = v;
                }

        // ---- partial row max (over n frags + 16 col-lanes) ----
#pragma unroll
        for (int m = 0; m < 4; ++m)
#pragma unroll
            for (int j = 0; j < 4; ++j) {
                float mx = fmaxf(sac[m][0][j], sac[m][1][j]);
#pragma unroll
                for (int o = 1; o < 16; o <<= 1) mx = fmaxf(mx, __shfl_xor(mx, o));
                if (l15 == 0) pmax[wid][m * 16 + l4 * 4 + j] = mx;
            }
        __syncthreads();   // bar1: pmax visible
        if (wid == 0) {    // wave 0: combine stats for its 64 rows
            const int r = lane;
            const float t = fmaxf(fmaxf(pmax[0][r], pmax[1][r]), fmaxf(pmax[2][r], pmax[3][r]));
            const float mo = m_lds[r];
            const float mn = fmaxf(mo, t);
            mn_lds[r] = mn;
            al_lds[r] = __expf(mo - mn);
            m_lds[r] = mn;
        }
        __syncthreads();   // bar2: mn/alpha visible

        // ---- P = exp(S - mn); row sums; rescale O; write P to LDS ----
#pragma unroll
        for (int m = 0; m < 4; ++m)
#pragma unroll
            for (int j = 0; j < 4; ++j) {
                const int r = m * 16 + l4 * 4 + j;
                const float mn = mn_lds[r];
                const float al = al_lds[r];
                const float e0 = __expf(sac[m][0][j] - mn);
                const float e1 = __expf(sac[m][1][j] - mn);
                sac[m][0][j] = e0;
                sac[m][1][j] = e1;
                float sum = e0 + e1;
#pragma unroll
                for (int o = 1; o < 16; o <<= 1) sum += __shfl_xor(sum, o);
                if (l15 == 0) psum[wid][r] = sum;
                oacc[m][0][j] *= al;
                oacc[m][1][j] *= al;
            }
#pragma unroll
        for (int m = 0; m < 4; ++m)
#pragma unroll
            for (int n = 0; n < 2; ++n)
#pragma unroll
                for (int j = 0; j < 4; ++j) {
                    const int r = m * 16 + l4 * 4 + j;
                    const int kv = wid * 32 + n * 16 + l15;
                    *(__hip_bfloat16*)(ps + r * 256 + ((((kv >> 3)) ^ (r & 7)) << 4) + (kv & 7) * 2) =
                        __float2bfloat16(sac[m][n][j]);
                }
        __syncthreads();   // bar3: psum + P visible
        if (wid == 0) {    // update l (consumed after loop-end barrier)
            const int r = lane;
            l_lds[r] = l_lds[r] * al_lds[r] + psum[0][r] + psum[1][r] + psum[2][r] + psum[3][r];
        }

        // ---- O += P V : A = ps rows (q), B = vs rows (d), k = kv (4 steps) ----
#pragma unroll
        for (int kk = 0; kk < 4; ++kk) {
            bf16x8 ap[4], bv[2];
#pragma unroll
            for (int m = 0; m < 4; ++m) {
                const int r = m * 16 + l15;
                ap[m] = *(const bf16x8*)(ps + r * 256 + (((kk * 4 + l4) ^ (r & 7)) << 4));
            }
#pragma unroll
            for (int n = 0; n < 2; ++n) {
                const int r = wid * 32 + n * 16 + l15;
                bv[n] = *(const bf16x8*)(vs + r * 256 + (((kk * 4 + l4) ^ (r & 7)) << 4));
            }
#pragma unroll
            for (int m = 0; m < 4; ++m)
#pragma unroll
                for (int n = 0; n < 2; ++n)
                    oacc[m][n] = __builtin_amdgcn_mfma_f32_16x16x32_bf16(ap[m], bv[n], oacc[m][n], 0, 0, 0);
        }
        __syncthreads();   // loop-end: PV reads done before next stage; l update visible
    }

    // ---- normalize and store ctx ----
#pragma unroll
    for (int m = 0; m < 4; ++m)
#pragma unroll
        for (int j = 0; j < 4; ++j) {
            const int r = m * 16 + l4 * 4 + j;
            const float inv = 1.f / l_lds[r];
#pragma unroll
            for (int n = 0; n < 2; ++n) {
                const int d = wid * 32 + n * 16 + l15;
                ctx[(long)(q0 + r) * (NHEAD * HDIM) + h * HDIM + d] =
                    __float2bfloat16(oacc[m][n][j] * inv);
            }
        }
}

// ============== 256x256 8-wave GEMM, m201-faithful phase schedule (unchanged from R7) ==============
template <int OUT>
__global__ __launch_bounds__(512, 2)
void g8p(const __hip_bfloat16* __restrict__ A, const __hip_bfloat16* __restrict__ B,
         void* __restrict__ Cv, int kLen, int ldA, int ldB, int ldC,
         long bZStride, long cZStride, int kZStride) {
    __shared__ __align__(16) char sA[2][2][16384];
    __shared__ __align__(16) char sB[2][2][16384];

    const int tid = threadIdx.x;
    const int lane = tid & 63;
    const int wid = tid >> 6;
    const int wr = wid >> 2;
    const int wc = wid & 3;
    const int l15 = lane & 15;
    const int l4 = lane >> 4;

    const int row0 = blockIdx.y * 256;
    const int col0 = blockIdx.x * 256;
    const int z = blockIdx.z;
    B += (long)z * bZStride;
    const long cOff = (long)z * cZStride;
    const int k0z = z * kZStride;
    const int nk = kLen / 64;

    f32x4 acc[8][4];
#pragma unroll
    for (int m = 0; m < 8; ++m)
#pragma unroll
        for (int n = 0; n < 4; ++n)
            acc[m][n] = (f32x4){0.f, 0.f, 0.f, 0.f};

    auto stage = [&](int kind, int kt) {
        const int k0 = k0z + kt * 64;
        const __hip_bfloat16* base;
        int ld_;
        char* dst;
        if (kind < 2) { base = A + (long)(row0 + kind * 128) * ldA; ld_ = ldA; dst = sA[kt & 1][kind]; }
        else          { base = B + (long)(col0 + (kind - 2) * 128) * ldB; ld_ = ldB; dst = sB[kt & 1][kind - 2]; }
#pragma unroll
        for (int i = 0; i < 2; ++i) {
            const int c = i * 512 + tid;
            const int r = c >> 3;
            const int s = c & 7;
            gload16(base + (long)r * ld_ + k0 + ((s ^ (r & 7)) * 8), dst + c * 16);
        }
    };

    auto readA = [&](int buf, int p, int mm, int ks) -> bf16x8 {
        const int r = p * 32 + mm * 16 + l15;
        const int q = ks * 4 + l4;
        return *(const bf16x8*)(sA[buf][wr] + r * 128 + ((q ^ (r & 7)) << 4));
    };
    auto readB = [&](int buf, int nn, int ks) -> bf16x8 {
        const int r = (wc & 1) * 64 + nn * 16 + l15;
        const int q = ks * 4 + l4;
        return *(const bf16x8*)(sB[buf][wc >> 1] + r * 128 + ((q ^ (r & 7)) << 4));
    };

    stage(0, 0); stage(1, 0); stage(2, 0); stage(3, 0);
    stage(2, 1); stage(3, 1);
    asm volatile("s_waitcnt vmcnt(4)" ::: "memory");
    __builtin_amdgcn_s_barrier();

    bf16x8 bfrag[4][2];
    for (int t = 0; t < nk; ++t) {
        const int cur = t & 1;
#pragma unroll
        for (int p = 0; p < 4; ++p) {
            bf16x8 a[2][2];
            a[0][0] = readA(cur, p, 0, 0); a[0][1] = readA(cur, p, 0, 1);
            a[1][0] = readA(cur, p, 1, 0); a[1][1] = readA(cur, p, 1, 1);
            if (p == 0) {
#pragma unroll
                for (int n = 0; n < 4; ++n) {
                    bfrag[n][0] = readB(cur, n, 0);
                    bfrag[n][1] = readB(cur, n, 1);
                }
            }
            if (p == 0 && t + 1 < nk) stage(0, t + 1);
            if (p == 1 && t + 1 < nk) stage(1, t + 1);
            if (p == 2 && t + 2 < nk) stage(2, t + 2);
            if (p == 3 && t + 2 < nk) stage(3, t + 2);

            if (p == 0) asm volatile("s_waitcnt lgkmcnt(8)" ::: "memory");
            __builtin_amdgcn_sched_barrier(0);
            if (p == 3) {
                if (t + 2 < nk)      asm volatile("s_waitcnt vmcnt(4)" ::: "memory");
                else if (t + 1 < nk) asm volatile("s_waitcnt vmcnt(0)" ::: "memory");
            }
            __builtin_amdgcn_s_barrier();
            asm volatile("s_waitcnt lgkmcnt(0)" ::: "memory");
            __builtin_amdgcn_sched_barrier(0);

            __builtin_amdgcn_s_setprio(1);
#pragma unroll
            for (int ks = 0; ks < 2; ++ks)
#pragma unroll
                for (int mm = 0; mm < 2; ++mm)
#pragma unroll
                    for (int n = 0; n < 4; ++n)
                        acc[p * 2 + mm][n] = __builtin_amdgcn_mfma_f32_16x16x32_bf16(
                            a[mm][ks], bfrag[n][ks], acc[p * 2 + mm][n], 0, 0, 0);
            __builtin_amdgcn_s_setprio(0);
            __builtin_amdgcn_sched_barrier(0);
            __builtin_amdgcn_s_barrier();
        }
    }

#pragma unroll
    for (int m = 0; m < 8; ++m) {
#pragma unroll
        for (int n = 0; n < 4; ++n) {
            const int rb = row0 + wr * 128 + m * 16 + l4 * 4;
            const int cc = col0 + wc * 64 + n * 16 + l15;
#pragma unroll
            for (int j = 0; j < 4; ++j) {
                const long idx = cOff + (long)(rb + j) * ldC + cc;
                if constexpr (OUT == 0) ((float*)Cv)[idx] = acc[m][n][j];
                else                    ((__hip_bfloat16*)Cv)[idx] = __float2bfloat16(acc[m][n][j]);
            }
        }
    }
}

// ---------------- host orchestration ----------------
extern "C" void kernel_launch(void* const* d_in, const int* in_sizes, int n_in,
                              void* d_out, int out_size, void* d_ws, size_t ws_size,
                              hipStream_t stream) {
    const int*   ids  = (const int*)d_in[0];
    const float* cosT = (const float*)d_in[2];
    const float* sinT = (const float*)d_in[3];
    const float* emb  = (const float*)d_in[4];
    const float* q_w  = (const float*)d_in[5];
    const float* k_w  = (const float*)d_in[6];
    const float* v_w  = (const float*)d_in[7];
    const float* o_w  = (const float*)d_in[8];
    const float* qn   = (const float*)d_in[9];
    const float* kn   = (const float*)d_in[10];
    const float* ln1  = (const float*)d_in[11];
    const float* ln2  = (const float*)d_in[12];
    const float* gw   = (const float*)d_in[13];
    const float* uw   = (const float*)d_in[14];
    const float* dw   = (const float*)d_in[15];

    char* W = (char*)d_ws;
    size_t off = 0;
    auto take = [&](size_t nb) { char* p = W + off; off += (nb + 255) & ~(size_t)255; return p; };

    // persistent bf16 weights
    __hip_bfloat16* wqkv = (__hip_bfloat16*) take((size_t)NLAYER * QKVN * DM * 2);
    __hip_bfloat16* wo   = (__hip_bfloat16*) take((size_t)NLAYER * DM * (NHEAD * HDIM) * 2);
    __hip_bfloat16* wgu  = (__hip_bfloat16*) take((size_t)NLAYER * 2 * FFN * DM * 2);
    __hip_bfloat16* wd   = (__hip_bfloat16*) take((size_t)NLAYER * DM * FFN * 2);
    // activations
    float*          h    = (float*)          take((size_t)SEQ * DM * 4);
    __hip_bfloat16* x    = (__hip_bfloat16*) take((size_t)SEQ * DM * 2);
    float*          part = (float*)          take((size_t)4 * SEQ * DM * 4);   // split-K partials (67 MB)
    __hip_bfloat16* qb   = (__hip_bfloat16*) take((size_t)NHEAD * SEQ * HDIM * 2);
    __hip_bfloat16* kb   = (__hip_bfloat16*) take((size_t)NKVH * SEQ * HDIM * 2);
    __hip_bfloat16* vt   = (__hip_bfloat16*) take((size_t)NKVH * HDIM * SEQ * 2);
    __hip_bfloat16* ctx  = (__hip_bfloat16*) take((size_t)SEQ * NHEAD * HDIM * 2);
    __hip_bfloat16* go2  = (__hip_bfloat16*) take((size_t)2 * SEQ * FFN * 2);
    if (off > ws_size) return;

    auto cvt = [&](const float* src, __hip_bfloat16* dst, long n) {
        cvt_bf16_k<<<(int)(n / 2048), 256, 0, stream>>>(src, dst);
    };

    // ---- convert all weights up front ----
    for (int l = 0; l < NLAYER; ++l) {
        __hip_bfloat16* base = wqkv + (size_t)l * QKVN * DM;
        cvt(q_w + (size_t)l * (NHEAD * HDIM) * DM, base,                               (long)(NHEAD * HDIM) * DM);
        cvt(k_w + (size_t)l * (NKVH * HDIM) * DM,  base + (size_t)(NHEAD * HDIM) * DM, (long)(NKVH * HDIM) * DM);
        cvt(v_w + (size_t)l * (NKVH * HDIM) * DM,  base + (size_t)(NHEAD * HDIM + NKVH * HDIM) * DM, (long)(NKVH * HDIM) * DM);
        cvt(gw + (size_t)l * FFN * DM, wgu + (size_t)(2 * l)     * FFN * DM, (long)FFN * DM);
        cvt(uw + (size_t)l * FFN * DM, wgu + (size_t)(2 * l + 1) * FFN * DM, (long)FFN * DM);
    }
    cvt(o_w, wo, (long)NLAYER * DM * (NHEAD * HDIM));
    cvt(dw,  wd, (long)NLAYER * DM * FFN);

    embed_k<<<SEQ, 256, 0, stream>>>(ids, emb, h);
    rmsnorm_k<<<SEQ, 256, 0, stream>>>(h, ln1, x);

    const long nQKV = (long)SEQ * QKVN;
    const long nDM  = (long)SEQ * DM;

    for (int l = 0; l < NLAYER; ++l) {
        // QKV: split-K x2 -> part (2 f32 partials; consumers sum them)
        g8p<0><<<dim3(QKVN / 256, SEQ / 256, 2), 512, 0, stream>>>(
            x, wqkv + (size_t)l * QKVN * DM, part, DM / 2, DM, DM, QKVN,
            0L, nQKV, DM / 2);

        qknorm_rope_k<<<SEQ * NHEAD / 4, 256, 0, stream>>>(
            part, nQKV, 0, qn + l * HDIM, cosT, sinT, qb, NHEAD);
        qknorm_rope_k<<<SEQ * NKVH / 4, 256, 0, stream>>>(
            part, nQKV, NHEAD * HDIM, kn + l * HDIM, cosT, sinT, kb, NKVH);
        vtrans_k<<<dim3(SEQ / 64, HDIM / 64, NKVH), 256, 0, stream>>>(
            part, nQKV, NHEAD * HDIM + NKVH * HDIM, vt);

        // flash attention: 32 q-slabs x 16 heads = 512 blocks
        flash_k<<<dim3(32, NHEAD), 256, 0, stream>>>(qb, kb, vt, ctx);

        // O: split-K x4 -> partials -> fused (h += sum; x = rmsnorm(h)*ln2)
        g8p<0><<<dim3(DM / 256, SEQ / 256, 4), 512, 0, stream>>>(
            ctx, wo + (size_t)l * DM * (NHEAD * HDIM), part, (NHEAD * HDIM) / 4,
            NHEAD * HDIM, NHEAD * HDIM, DM, 0L, nDM, (NHEAD * HDIM) / 4);
        rmsnorm_res4_k<<<SEQ, 256, 0, stream>>>(part, nDM, h, ln2 + l * DM, x);

        // gate+up merged (z picks weight & output)
        g8p<1><<<dim3(FFN / 256, SEQ / 256, 2), 512, 0, stream>>>(
            x, wgu + (size_t)(2 * l) * FFN * DM, go2, DM, DM, DM, FFN,
            (long)FFN * DM, (long)SEQ * FFN, 0);
        silu_mul_k<<<(int)(((long)SEQ * FFN) / 2048), 256, 0, stream>>>(go2, go2 + (size_t)SEQ * FFN);

        // down: split-K x4 -> partials -> fused with next layer's ln1 (or final reduce)
        g8p<0><<<dim3(DM / 256, SEQ / 256, 4), 512, 0, stream>>>(
            go2, wd + (size_t)l * DM * FFN, part, FFN / 4,
            FFN, FFN, DM, 0L, nDM, FFN / 4);
        if (l + 1 < NLAYER)
            rmsnorm_res4_k<<<SEQ, 256, 0, stream>>>(part, nDM, h, ln1 + (l + 1) * DM, x);
        else
            red4res_k<<<(int)(nDM / 1024), 256, 0, stream>>>(part, nDM, h);
    }

    hipMemcpyAsync(d_out, h, (size_t)out_size * sizeof(float), hipMemcpyDeviceToDevice, stream);
}

// Round 9
// 980.969 us; speedup vs baseline: 1.3600x; 1.3600x over previous
//
#include <hip/hip_runtime.h>
#include <hip/hip_bf16.h>

// ---------------- model constants ----------------
static constexpr int SEQ   = 2048;
static constexpr int DM    = 2048;
static constexpr int NHEAD = 16;
static constexpr int NKVH  = 8;
static constexpr int HDIM  = 128;
static constexpr int FFN   = 6144;
static constexpr int NLAYER = 2;
static constexpr float EPSV = 1e-6f;
static constexpr int QKVN  = NHEAD * HDIM + 2 * NKVH * HDIM;  // 4096 fused QKV cols

typedef __attribute__((ext_vector_type(8))) short bf16x8;
typedef __attribute__((ext_vector_type(4))) float f32x4;

__device__ __forceinline__ float wave_sum(float v) {
#pragma unroll
    for (int o = 32; o > 0; o >>= 1) v += __shfl_xor(v, o);
    return v;
}

// async global->LDS, 16B per lane
__device__ __forceinline__ void gload16(const void* g, void* l) {
    __builtin_amdgcn_global_load_lds(
        (const __attribute__((address_space(1))) void*)g,
        (__attribute__((address_space(3))) void*)l,
        16, 0, 0);
}

// ---------------- f32 -> bf16 weight convert ----------------
__global__ void cvt_bf16_k(const float* __restrict__ in, __hip_bfloat16* __restrict__ out) {
    const long b = ((long)blockIdx.x * 256 + threadIdx.x) * 8;
    const float4 a0 = *(const float4*)(in + b);
    const float4 a1 = *(const float4*)(in + b + 4);
    union { bf16x8 v; __hip_bfloat16 h[8]; } u;
    u.h[0] = __float2bfloat16(a0.x); u.h[1] = __float2bfloat16(a0.y);
    u.h[2] = __float2bfloat16(a0.z); u.h[3] = __float2bfloat16(a0.w);
    u.h[4] = __float2bfloat16(a1.x); u.h[5] = __float2bfloat16(a1.y);
    u.h[6] = __float2bfloat16(a1.z); u.h[7] = __float2bfloat16(a1.w);
    *(bf16x8*)(out + b) = u.v;
}

// ---------------- embedding gather ----------------
__global__ void embed_k(const int* __restrict__ ids, const float* __restrict__ emb,
                        float* __restrict__ h) {
    const int s = blockIdx.x;
    const long src = (long)ids[s] * DM;
    for (int t = threadIdx.x; t < DM; t += 256)
        h[(long)s * DM + t] = emb[src + t];
}

// ---------------- RMSNorm (f32 in -> bf16 out) ----------------
__global__ void rmsnorm_k(const float* __restrict__ in, const float* __restrict__ g,
                          __hip_bfloat16* __restrict__ out) {
    const int row = blockIdx.x;
    const float* r = in + (long)row * DM;
    const int tid = threadIdx.x;
    float v[8];
    float ss = 0.f;
#pragma unroll
    for (int t = 0; t < 8; ++t) { v[t] = r[tid + t * 256]; ss += v[t] * v[t]; }
    ss = wave_sum(ss);
    __shared__ float sp[4];
    if ((tid & 63) == 0) sp[tid >> 6] = ss;
    __syncthreads();
    ss = sp[0] + sp[1] + sp[2] + sp[3];
    const float inv = rsqrtf(ss * (1.f / DM) + EPSV);
    __hip_bfloat16* o_ = out + (long)row * DM;
#pragma unroll
    for (int t = 0; t < 8; ++t) {
        const int j = tid + t * 256;
        o_[j] = __float2bfloat16(v[t] * inv * g[j]);
    }
}

// ---------------- fused: h += sum of 4 split-K partials; x = rmsnorm(h)*g ----------------
__global__ void rmsnorm_res4_k(const float* __restrict__ part, long n,
                               float* __restrict__ h, const float* __restrict__ g,
                               __hip_bfloat16* __restrict__ x) {
    const int row = blockIdx.x;
    const int tid = threadIdx.x;
    float v[8];
    float ss = 0.f;
#pragma unroll
    for (int t = 0; t < 8; ++t) {
        const long idx = (long)row * DM + tid + t * 256;
        float s = h[idx];
#pragma unroll
        for (int z = 0; z < 4; ++z) s += part[(long)z * n + idx];
        h[idx] = s;
        v[t] = s;
        ss += s * s;
    }
    ss = wave_sum(ss);
    __shared__ float sp[4];
    if ((tid & 63) == 0) sp[tid >> 6] = ss;
    __syncthreads();
    ss = sp[0] + sp[1] + sp[2] + sp[3];
    const float inv = rsqrtf(ss * (1.f / DM) + EPSV);
    __hip_bfloat16* o_ = x + (long)row * DM;
#pragma unroll
    for (int t = 0; t < 8; ++t) {
        const int j = tid + t * 256;
        o_[j] = __float2bfloat16(v[t] * inv * g[j]);
    }
}

// ---------------- h += sum of 4 partials (final layer) ----------------
__global__ void red4res_k(const float* __restrict__ p, long n, float* __restrict__ h) {
    const long i = ((long)blockIdx.x * 256 + threadIdx.x) * 4;
    float4 s = *(const float4*)(h + i);
#pragma unroll
    for (int z = 0; z < 4; ++z) {
        const float4 b = *(const float4*)(p + (long)z * n + i);
        s.x += b.x; s.y += b.y; s.z += b.z; s.w += b.w;
    }
    *(float4*)(h + i) = s;
}

// ---------------- per-head RMSNorm + RoPE; input = sum of 2 split-K partials ----------------
__global__ void qknorm_rope_k(const float* __restrict__ in, long zStride, int inOff,
                              const float* __restrict__ ns,
                              const float* __restrict__ cosT, const float* __restrict__ sinT,
                              __hip_bfloat16* __restrict__ out, int nheads) {
    const int idx = blockIdx.x * 4 + (threadIdx.x >> 6);
    const int lane = threadIdx.x & 63;
    const int s = idx / nheads;
    const int hh = idx - s * nheads;
    const long base = (long)s * QKVN + inOff + hh * HDIM;
    const float x1 = in[base + lane]      + in[zStride + base + lane];
    const float x2 = in[base + lane + 64] + in[zStride + base + lane + 64];
    float ss = wave_sum(x1 * x1 + x2 * x2);
    const float inv = rsqrtf(ss * (1.f / HDIM) + EPSV);
    const float n1 = x1 * inv * ns[lane];
    const float n2 = x2 * inv * ns[lane + 64];
    const float c1 = cosT[s * HDIM + lane],      c2 = cosT[s * HDIM + 64 + lane];
    const float s1 = sinT[s * HDIM + lane],      s2 = sinT[s * HDIM + 64 + lane];
    __hip_bfloat16* w = out + ((long)hh * SEQ + s) * HDIM;
    w[lane]      = __float2bfloat16(n1 * c1 - n2 * s1);
    w[lane + 64] = __float2bfloat16(n2 * c2 + n1 * s2);
}

// ---------------- V transpose+convert (2-partial f32 src -> vt [kv][d][s] bf16) ----------------
__global__ void vtrans_k(const float* __restrict__ vf, long zStride, int colOff,
                         __hip_bfloat16* __restrict__ vt) {
    __shared__ float tile[64][65];
    const int s0 = blockIdx.x * 64, d0 = blockIdx.y * 64, kv = blockIdx.z;
    const int lane = threadIdx.x & 63, part = threadIdx.x >> 6;
    for (int r = part; r < 64; r += 4) {
        const long idx = (long)(s0 + r) * QKVN + colOff + kv * HDIM + d0 + lane;
        tile[r][lane] = vf[idx] + vf[zStride + idx];
    }
    __syncthreads();
    for (int r = part; r < 64; r += 4)
        vt[((long)kv * HDIM + d0 + r) * SEQ + s0 + lane] = __float2bfloat16(tile[lane][r]);
}

// ---------------- silu(g)*u elementwise, in place on g ----------------
__global__ void silu_mul_k(__hip_bfloat16* __restrict__ g, const __hip_bfloat16* __restrict__ u) {
    const long i = ((long)blockIdx.x * 256 + threadIdx.x) * 8;
    union { bf16x8 v; __hip_bfloat16 h[8]; } a, b, o;
    a.v = *(const bf16x8*)(g + i);
    b.v = *(const bf16x8*)(u + i);
#pragma unroll
    for (int j = 0; j < 8; ++j) {
        const float xx = __bfloat162float(a.h[j]);
        const float yy = __bfloat162float(b.h[j]);
        const float sv = xx / (1.f + __expf(-xx));
        o.h[j] = __float2bfloat16(sv * yy);
    }
    *(bf16x8*)(g + i) = o.v;
}

// ============== flash attention v2: row-split waves, wave-local softmax ==============
// Block = (64-q-row slab, head); 4 waves, wave w owns q rows w*16..w*16+15 (all kv cols).
// Q in regs (16 VGPR), O in regs (32 VGPR). kv-tile = 64, K/V LDS double-buffered
// (issue next tile's gload16 at tile start; vmcnt(0)+barrier at tile end only).
// Softmax fully wave-local: row max/sum via 16-lane __shfl_xor. One barrier per tile.
// qb [H][S][128], kb [KV][S][128], vt [KV][128][S] bf16 -> ctx [S][H*128] bf16.
__global__ __launch_bounds__(256)
void flash_k(const __hip_bfloat16* __restrict__ qb, const __hip_bfloat16* __restrict__ kb,
             const __hip_bfloat16* __restrict__ vt, __hip_bfloat16* __restrict__ ctx) {
    __shared__ __align__(16) char ks[2][16384];   // [64 kv][128 d], swizzled
    __shared__ __align__(16) char vs[2][16384];   // [128 d][64 kv], swizzled
    __shared__ __align__(16) char ps[4][2048];    // per-wave P [16 q][64 kv], swizzled

    const int tid = threadIdx.x;
    const int lane = tid & 63;
    const int wid = tid >> 6;
    const int l15 = lane & 15;
    const int l4 = lane >> 4;

    const int x = blockIdx.x;        // q-slab (64 rows)
    const int h = blockIdx.y;
    const int q0 = x * 64;
    const int kvh = h >> 1;          // GROUP = 2
    const int nkt = x + 1;           // causal 64-kv tiles
    const float scale = 0.0883883476483184405f;  // 1/sqrt(128)

    // Q -> registers: A-frag (row = lane&15, k-chunk = lane>>4), 4 k-steps of 32 d
    bf16x8 aq[4];
    {
        const __hip_bfloat16* qg = qb + ((long)h * SEQ + q0 + wid * 16 + l15) * HDIM + l4 * 8;
#pragma unroll
        for (int kk = 0; kk < 4; ++kk) aq[kk] = *(const bf16x8*)(qg + kk * 32);
    }

    float mreg[4], lreg[4];
#pragma unroll
    for (int j = 0; j < 4; ++j) { mreg[j] = -3.0e38f; lreg[j] = 0.f; }
    f32x4 oacc[8];
#pragma unroll
    for (int n = 0; n < 8; ++n) oacc[n] = (f32x4){0.f, 0.f, 0.f, 0.f};

    auto stageK = [&](int buf, int kt) {
        const __hip_bfloat16* kg = kb + ((long)kvh * SEQ + kt * 64) * HDIM;
#pragma unroll
        for (int i = 0; i < 4; ++i) {
            const int c = i * 256 + tid;          // row c>>4 (64 kv), slot c&15
            const int r = c >> 4, s = c & 15;
            gload16(kg + (long)r * HDIM + ((s ^ (r & 7)) * 8), ks[buf] + c * 16);
        }
    };
    auto stageV = [&](int buf, int kt) {
        const __hip_bfloat16* vg = vt + (long)kvh * HDIM * SEQ + kt * 64;
#pragma unroll
        for (int i = 0; i < 4; ++i) {
            const int c = i * 256 + tid;          // row c>>3 (128 d), slot c&7
            const int r = c >> 3, s = c & 7;
            gload16(vg + (long)r * SEQ + ((s ^ (r & 7)) * 8), vs[buf] + c * 16);
        }
    };

    stageK(0, 0); stageV(0, 0);
    asm volatile("s_waitcnt vmcnt(0)" ::: "memory");
    __builtin_amdgcn_s_barrier();

    for (int kt = 0; kt < nkt; ++kt) {
        const int cur = kt & 1;
        if (kt + 1 < nkt) { stageK(cur ^ 1, kt + 1); stageV(cur ^ 1, kt + 1); }  // in flight under compute

        // ---- S = Q K^T (wave rows x 64 kv): 4 n-frags, 4 k-steps ----
        f32x4 sac[4];
#pragma unroll
        for (int n = 0; n < 4; ++n) sac[n] = (f32x4){0.f, 0.f, 0.f, 0.f};
#pragma unroll
        for (int kk = 0; kk < 4; ++kk) {
#pragma unroll
            for (int n = 0; n < 4; ++n) {
                const int r = n * 16 + l15;
                const bf16x8 bk = *(const bf16x8*)(ks[cur] + r * 256 + (((kk * 4 + l4) ^ (r & 7)) << 4));
                sac[n] = __builtin_amdgcn_mfma_f32_16x16x32_bf16(aq[kk], bk, sac[n], 0, 0, 0);
            }
        }

        // ---- wave-local online softmax (row = wid*16 + l4*4 + j, col = n*16 + l15) ----
        const bool diag = (kt + 1 == nkt);
        float mnj[4], alj[4];
#pragma unroll
        for (int j = 0; j < 4; ++j) {
            float mx = -3.0e38f;
#pragma unroll
            for (int n = 0; n < 4; ++n) {
                float v = sac[n][j] * scale;
                if (diag && (n * 16 + l15 > wid * 16 + l4 * 4 + j)) v = -3.0e38f;
                sac[n][j] = v;
                mx = fmaxf(mx, v);
            }
#pragma unroll
            for (int o = 1; o < 16; o <<= 1) mx = fmaxf(mx, __shfl_xor(mx, o));
            const float mn = fmaxf(mreg[j], mx);
            mnj[j] = mn;
            alj[j] = __expf(mreg[j] - mn);
            mreg[j] = mn;
        }
#pragma unroll
        for (int j = 0; j < 4; ++j) {
            float rs = 0.f;
#pragma unroll
            for (int n = 0; n < 4; ++n) {
                const float e = __expf(sac[n][j] - mnj[j]);
                sac[n][j] = e;
                rs += e;
            }
#pragma unroll
            for (int o = 1; o < 16; o <<= 1) rs += __shfl_xor(rs, o);
            lreg[j] = lreg[j] * alj[j] + rs;
#pragma unroll
            for (int n2 = 0; n2 < 8; ++n2) oacc[n2][j] *= alj[j];
        }

        // ---- P -> per-wave LDS (swizzled), then O += P V ----
        char* pw = ps[wid];
#pragma unroll
        for (int n = 0; n < 4; ++n)
#pragma unroll
            for (int j = 0; j < 4; ++j) {
                const int r = l4 * 4 + j;
                const int col = n * 16 + l15;
                *(__hip_bfloat16*)(pw + r * 128 + (((col >> 3) ^ (r & 7)) << 4) + (col & 7) * 2) =
                    __float2bfloat16(sac[n][j]);
            }
        asm volatile("s_waitcnt lgkmcnt(0)" ::: "memory");
        __builtin_amdgcn_sched_barrier(0);
#pragma unroll
        for (int kk = 0; kk < 2; ++kk) {
            const bf16x8 ap = *(const bf16x8*)(pw + l15 * 128 + (((kk * 4 + l4) ^ (l15 & 7)) << 4));
#pragma unroll
            for (int n2 = 0; n2 < 8; ++n2) {
                const int r = n2 * 16 + l15;
                const bf16x8 bv = *(const bf16x8*)(vs[cur] + r * 128 + (((kk * 4 + l4) ^ (r & 7)) << 4));
                oacc[n2] = __builtin_amdgcn_mfma_f32_16x16x32_bf16(ap, bv, oacc[n2], 0, 0, 0);
            }
        }

        asm volatile("s_waitcnt vmcnt(0)" ::: "memory");   // next tile staged
        __builtin_amdgcn_s_barrier();                      // all waves done with cur
    }

    // ---- normalize and store ----
#pragma unroll
    for (int j = 0; j < 4; ++j) {
        const float inv = 1.f / lreg[j];
        const long rowb = (long)(q0 + wid * 16 + l4 * 4 + j) * (NHEAD * HDIM) + h * HDIM;
#pragma unroll
        for (int n2 = 0; n2 < 8; ++n2)
            ctx[rowb + n2 * 16 + l15] = __float2bfloat16(oacc[n2][j] * inv);
    }
}

// ============== 256x256 8-wave GEMM, m201-faithful phase schedule (unchanged from R7) ==============
template <int OUT>
__global__ __launch_bounds__(512, 2)
void g8p(const __hip_bfloat16* __restrict__ A, const __hip_bfloat16* __restrict__ B,
         void* __restrict__ Cv, int kLen, int ldA, int ldB, int ldC,
         long bZStride, long cZStride, int kZStride) {
    __shared__ __align__(16) char sA[2][2][16384];
    __shared__ __align__(16) char sB[2][2][16384];

    const int tid = threadIdx.x;
    const int lane = tid & 63;
    const int wid = tid >> 6;
    const int wr = wid >> 2;
    const int wc = wid & 3;
    const int l15 = lane & 15;
    const int l4 = lane >> 4;

    const int row0 = blockIdx.y * 256;
    const int col0 = blockIdx.x * 256;
    const int z = blockIdx.z;
    B += (long)z * bZStride;
    const long cOff = (long)z * cZStride;
    const int k0z = z * kZStride;
    const int nk = kLen / 64;

    f32x4 acc[8][4];
#pragma unroll
    for (int m = 0; m < 8; ++m)
#pragma unroll
        for (int n = 0; n < 4; ++n)
            acc[m][n] = (f32x4){0.f, 0.f, 0.f, 0.f};

    auto stage = [&](int kind, int kt) {
        const int k0 = k0z + kt * 64;
        const __hip_bfloat16* base;
        int ld_;
        char* dst;
        if (kind < 2) { base = A + (long)(row0 + kind * 128) * ldA; ld_ = ldA; dst = sA[kt & 1][kind]; }
        else          { base = B + (long)(col0 + (kind - 2) * 128) * ldB; ld_ = ldB; dst = sB[kt & 1][kind - 2]; }
#pragma unroll
        for (int i = 0; i < 2; ++i) {
            const int c = i * 512 + tid;
            const int r = c >> 3;
            const int s = c & 7;
            gload16(base + (long)r * ld_ + k0 + ((s ^ (r & 7)) * 8), dst + c * 16);
        }
    };

    auto readA = [&](int buf, int p, int mm, int ks) -> bf16x8 {
        const int r = p * 32 + mm * 16 + l15;
        const int q = ks * 4 + l4;
        return *(const bf16x8*)(sA[buf][wr] + r * 128 + ((q ^ (r & 7)) << 4));
    };
    auto readB = [&](int buf, int nn, int ks) -> bf16x8 {
        const int r = (wc & 1) * 64 + nn * 16 + l15;
        const int q = ks * 4 + l4;
        return *(const bf16x8*)(sB[buf][wc >> 1] + r * 128 + ((q ^ (r & 7)) << 4));
    };

    stage(0, 0); stage(1, 0); stage(2, 0); stage(3, 0);
    stage(2, 1); stage(3, 1);
    asm volatile("s_waitcnt vmcnt(4)" ::: "memory");
    __builtin_amdgcn_s_barrier();

    bf16x8 bfrag[4][2];
    for (int t = 0; t < nk; ++t) {
        const int cur = t & 1;
#pragma unroll
        for (int p = 0; p < 4; ++p) {
            bf16x8 a[2][2];
            a[0][0] = readA(cur, p, 0, 0); a[0][1] = readA(cur, p, 0, 1);
            a[1][0] = readA(cur, p, 1, 0); a[1][1] = readA(cur, p, 1, 1);
            if (p == 0) {
#pragma unroll
                for (int n = 0; n < 4; ++n) {
                    bfrag[n][0] = readB(cur, n, 0);
                    bfrag[n][1] = readB(cur, n, 1);
                }
            }
            if (p == 0 && t + 1 < nk) stage(0, t + 1);
            if (p == 1 && t + 1 < nk) stage(1, t + 1);
            if (p == 2 && t + 2 < nk) stage(2, t + 2);
            if (p == 3 && t + 2 < nk) stage(3, t + 2);

            if (p == 0) asm volatile("s_waitcnt lgkmcnt(8)" ::: "memory");
            __builtin_amdgcn_sched_barrier(0);
            if (p == 3) {
                if (t + 2 < nk)      asm volatile("s_waitcnt vmcnt(4)" ::: "memory");
                else if (t + 1 < nk) asm volatile("s_waitcnt vmcnt(0)" ::: "memory");
            }
            __builtin_amdgcn_s_barrier();
            asm volatile("s_waitcnt lgkmcnt(0)" ::: "memory");
            __builtin_amdgcn_sched_barrier(0);

            __builtin_amdgcn_s_setprio(1);
#pragma unroll
            for (int ks = 0; ks < 2; ++ks)
#pragma unroll
                for (int mm = 0; mm < 2; ++mm)
#pragma unroll
                    for (int n = 0; n < 4; ++n)
                        acc[p * 2 + mm][n] = __builtin_amdgcn_mfma_f32_16x16x32_bf16(
                            a[mm][ks], bfrag[n][ks], acc[p * 2 + mm][n], 0, 0, 0);
            __builtin_amdgcn_s_setprio(0);
            __builtin_amdgcn_sched_barrier(0);
            __builtin_amdgcn_s_barrier();
        }
    }

#pragma unroll
    for (int m = 0; m < 8; ++m) {
#pragma unroll
        for (int n = 0; n < 4; ++n) {
            const int rb = row0 + wr * 128 + m * 16 + l4 * 4;
            const int cc = col0 + wc * 64 + n * 16 + l15;
#pragma unroll
            for (int j = 0; j < 4; ++j) {
                const long idx = cOff + (long)(rb + j) * ldC + cc;
                if constexpr (OUT == 0) ((float*)Cv)[idx] = acc[m][n][j];
                else                    ((__hip_bfloat16*)Cv)[idx] = __float2bfloat16(acc[m][n][j]);
            }
        }
    }
}

// ---------------- host orchestration ----------------
extern "C" void kernel_launch(void* const* d_in, const int* in_sizes, int n_in,
                              void* d_out, int out_size, void* d_ws, size_t ws_size,
                              hipStream_t stream) {
    const int*   ids  = (const int*)d_in[0];
    const float* cosT = (const float*)d_in[2];
    const float* sinT = (const float*)d_in[3];
    const float* emb  = (const float*)d_in[4];
    const float* q_w  = (const float*)d_in[5];
    const float* k_w  = (const float*)d_in[6];
    const float* v_w  = (const float*)d_in[7];
    const float* o_w  = (const float*)d_in[8];
    const float* qn   = (const float*)d_in[9];
    const float* kn   = (const float*)d_in[10];
    const float* ln1  = (const float*)d_in[11];
    const float* ln2  = (const float*)d_in[12];
    const float* gw   = (const float*)d_in[13];
    const float* uw   = (const float*)d_in[14];
    const float* dw   = (const float*)d_in[15];

    char* W = (char*)d_ws;
    size_t off = 0;
    auto take = [&](size_t nb) { char* p = W + off; off += (nb + 255) & ~(size_t)255; return p; };

    // persistent bf16 weights
    __hip_bfloat16* wqkv = (__hip_bfloat16*) take((size_t)NLAYER * QKVN * DM * 2);
    __hip_bfloat16* wo   = (__hip_bfloat16*) take((size_t)NLAYER * DM * (NHEAD * HDIM) * 2);
    __hip_bfloat16* wgu  = (__hip_bfloat16*) take((size_t)NLAYER * 2 * FFN * DM * 2);
    __hip_bfloat16* wd   = (__hip_bfloat16*) take((size_t)NLAYER * DM * FFN * 2);
    // activations
    float*          h    = (float*)          take((size_t)SEQ * DM * 4);
    __hip_bfloat16* x    = (__hip_bfloat16*) take((size_t)SEQ * DM * 2);
    float*          part = (float*)          take((size_t)4 * SEQ * DM * 4);   // split-K partials
    __hip_bfloat16* qb   = (__hip_bfloat16*) take((size_t)NHEAD * SEQ * HDIM * 2);
    __hip_bfloat16* kb   = (__hip_bfloat16*) take((size_t)NKVH * SEQ * HDIM * 2);
    __hip_bfloat16* vt   = (__hip_bfloat16*) take((size_t)NKVH * HDIM * SEQ * 2);
    __hip_bfloat16* ctx  = (__hip_bfloat16*) take((size_t)SEQ * NHEAD * HDIM * 2);
    __hip_bfloat16* go2  = (__hip_bfloat16*) take((size_t)2 * SEQ * FFN * 2);
    if (off > ws_size) return;

    auto cvt = [&](const float* src, __hip_bfloat16* dst, long n) {
        cvt_bf16_k<<<(int)(n / 2048), 256, 0, stream>>>(src, dst);
    };

    // ---- convert all weights up front ----
    for (int l = 0; l < NLAYER; ++l) {
        __hip_bfloat16* base = wqkv + (size_t)l * QKVN * DM;
        cvt(q_w + (size_t)l * (NHEAD * HDIM) * DM, base,                               (long)(NHEAD * HDIM) * DM);
        cvt(k_w + (size_t)l * (NKVH * HDIM) * DM,  base + (size_t)(NHEAD * HDIM) * DM, (long)(NKVH * HDIM) * DM);
        cvt(v_w + (size_t)l * (NKVH * HDIM) * DM,  base + (size_t)(NHEAD * HDIM + NKVH * HDIM) * DM, (long)(NKVH * HDIM) * DM);
        cvt(gw + (size_t)l * FFN * DM, wgu + (size_t)(2 * l)     * FFN * DM, (long)FFN * DM);
        cvt(uw + (size_t)l * FFN * DM, wgu + (size_t)(2 * l + 1) * FFN * DM, (long)FFN * DM);
    }
    cvt(o_w, wo, (long)NLAYER * DM * (NHEAD * HDIM));
    cvt(dw,  wd, (long)NLAYER * DM * FFN);

    embed_k<<<SEQ, 256, 0, stream>>>(ids, emb, h);
    rmsnorm_k<<<SEQ, 256, 0, stream>>>(h, ln1, x);

    const long nQKV = (long)SEQ * QKVN;
    const long nDM  = (long)SEQ * DM;

    for (int l = 0; l < NLAYER; ++l) {
        // QKV: split-K x2 -> part (2 f32 partials; consumers sum them)
        g8p<0><<<dim3(QKVN / 256, SEQ / 256, 2), 512, 0, stream>>>(
            x, wqkv + (size_t)l * QKVN * DM, part, DM / 2, DM, DM, QKVN,
            0L, nQKV, DM / 2);

        qknorm_rope_k<<<SEQ * NHEAD / 4, 256, 0, stream>>>(
            part, nQKV, 0, qn + l * HDIM, cosT, sinT, qb, NHEAD);
        qknorm_rope_k<<<SEQ * NKVH / 4, 256, 0, stream>>>(
            part, nQKV, NHEAD * HDIM, kn + l * HDIM, cosT, sinT, kb, NKVH);
        vtrans_k<<<dim3(SEQ / 64, HDIM / 64, NKVH), 256, 0, stream>>>(
            part, nQKV, NHEAD * HDIM + NKVH * HDIM, vt);

        // flash attention v2: 32 q-slabs x 16 heads = 512 blocks, 2 blocks/CU
        flash_k<<<dim3(32, NHEAD), 256, 0, stream>>>(qb, kb, vt, ctx);

        // O: split-K x4 -> partials -> fused (h += sum; x = rmsnorm(h)*ln2)
        g8p<0><<<dim3(DM / 256, SEQ / 256, 4), 512, 0, stream>>>(
            ctx, wo + (size_t)l * DM * (NHEAD * HDIM), part, (NHEAD * HDIM) / 4,
            NHEAD * HDIM, NHEAD * HDIM, DM, 0L, nDM, (NHEAD * HDIM) / 4);
        rmsnorm_res4_k<<<SEQ, 256, 0, stream>>>(part, nDM, h, ln2 + l * DM, x);

        // gate+up merged (z picks weight & output)
        g8p<1><<<dim3(FFN / 256, SEQ / 256, 2), 512, 0, stream>>>(
            x, wgu + (size_t)(2 * l) * FFN * DM, go2, DM, DM, DM, FFN,
            (long)FFN * DM, (long)SEQ * FFN, 0);
        silu_mul_k<<<(int)(((long)SEQ * FFN) / 2048), 256, 0, stream>>>(go2, go2 + (size_t)SEQ * FFN);

        // down: split-K x4 -> partials -> fused with next layer's ln1 (or final reduce)
        g8p<0><<<dim3(DM / 256, SEQ / 256, 4), 512, 0, stream>>>(
            go2, wd + (size_t)l * DM * FFN, part, FFN / 4,
            FFN, FFN, DM, 0L, nDM, FFN / 4);
        if (l + 1 < NLAYER)
            rmsnorm_res4_k<<<SEQ, 256, 0, stream>>>(part, nDM, h, ln1 + (l + 1) * DM, x);
        else
            red4res_k<<<(int)(nDM / 1024), 256, 0, stream>>>(part, nDM, h);
    }

    hipMemcpyAsync(d_out, h, (size_t)out_size * sizeof(float), hipMemcpyDeviceToDevice, stream);
}

// Round 10
// 965.699 us; speedup vs baseline: 1.3815x; 1.0158x over previous
//
#include <hip/hip_runtime.h>
#include <hip/hip_bf16.h>

// ---------------- model constants ----------------
static constexpr int SEQ   = 2048;
static constexpr int DM    = 2048;
static constexpr int NHEAD = 16;
static constexpr int NKVH  = 8;
static constexpr int HDIM  = 128;
static constexpr int FFN   = 6144;
static constexpr int NLAYER = 2;
static constexpr float EPSV = 1e-6f;
static constexpr int QKVN  = NHEAD * HDIM + 2 * NKVH * HDIM;  // 4096 fused QKV cols

typedef __attribute__((ext_vector_type(8))) short bf16x8;
typedef __attribute__((ext_vector_type(4))) float f32x4;

__device__ __forceinline__ float wave_sum(float v) {
#pragma unroll
    for (int o = 32; o > 0; o >>= 1) v += __shfl_xor(v, o);
    return v;
}

// async global->LDS, 16B per lane
__device__ __forceinline__ void gload16(const void* g, void* l) {
    __builtin_amdgcn_global_load_lds(
        (const __attribute__((address_space(1))) void*)g,
        (__attribute__((address_space(3))) void*)l,
        16, 0, 0);
}

// ---------------- f32 -> bf16 weight convert ----------------
__global__ void cvt_bf16_k(const float* __restrict__ in, __hip_bfloat16* __restrict__ out) {
    const long b = ((long)blockIdx.x * 256 + threadIdx.x) * 8;
    const float4 a0 = *(const float4*)(in + b);
    const float4 a1 = *(const float4*)(in + b + 4);
    union { bf16x8 v; __hip_bfloat16 h[8]; } u;
    u.h[0] = __float2bfloat16(a0.x); u.h[1] = __float2bfloat16(a0.y);
    u.h[2] = __float2bfloat16(a0.z); u.h[3] = __float2bfloat16(a0.w);
    u.h[4] = __float2bfloat16(a1.x); u.h[5] = __float2bfloat16(a1.y);
    u.h[6] = __float2bfloat16(a1.z); u.h[7] = __float2bfloat16(a1.w);
    *(bf16x8*)(out + b) = u.v;
}

// ---------------- embedding gather ----------------
__global__ void embed_k(const int* __restrict__ ids, const float* __restrict__ emb,
                        float* __restrict__ h) {
    const int s = blockIdx.x;
    const long src = (long)ids[s] * DM;
    for (int t = threadIdx.x; t < DM; t += 256)
        h[(long)s * DM + t] = emb[src + t];
}

// ---------------- RMSNorm (f32 in -> bf16 out) ----------------
__global__ void rmsnorm_k(const float* __restrict__ in, const float* __restrict__ g,
                          __hip_bfloat16* __restrict__ out) {
    const int row = blockIdx.x;
    const float* r = in + (long)row * DM;
    const int tid = threadIdx.x;
    float v[8];
    float ss = 0.f;
#pragma unroll
    for (int t = 0; t < 8; ++t) { v[t] = r[tid + t * 256]; ss += v[t] * v[t]; }
    ss = wave_sum(ss);
    __shared__ float sp[4];
    if ((tid & 63) == 0) sp[tid >> 6] = ss;
    __syncthreads();
    ss = sp[0] + sp[1] + sp[2] + sp[3];
    const float inv = rsqrtf(ss * (1.f / DM) + EPSV);
    __hip_bfloat16* o_ = out + (long)row * DM;
#pragma unroll
    for (int t = 0; t < 8; ++t) {
        const int j = tid + t * 256;
        o_[j] = __float2bfloat16(v[t] * inv * g[j]);
    }
}

// ---------------- fused: h += sum of 4 bf16 split-K partials; x = rmsnorm(h)*g ----------------
__global__ void rmsnorm_res4_k(const __hip_bfloat16* __restrict__ part, long n,
                               float* __restrict__ h, const float* __restrict__ g,
                               __hip_bfloat16* __restrict__ x) {
    const int row = blockIdx.x;
    const int tid = threadIdx.x;
    const long base = (long)row * DM + tid * 8;
    float v[8];
    *(float4*)&v[0] = *(const float4*)(h + base);
    *(float4*)&v[4] = *(const float4*)(h + base + 4);
#pragma unroll
    for (int z = 0; z < 4; ++z) {
        union { bf16x8 vv; __hip_bfloat16 e[8]; } p;
        p.vv = *(const bf16x8*)(part + (long)z * n + base);
#pragma unroll
        for (int j = 0; j < 8; ++j) v[j] += __bfloat162float(p.e[j]);
    }
    *(float4*)(h + base) = *(float4*)&v[0];
    *(float4*)(h + base + 4) = *(float4*)&v[4];
    float ss = 0.f;
#pragma unroll
    for (int j = 0; j < 8; ++j) ss += v[j] * v[j];
    ss = wave_sum(ss);
    __shared__ float sp[4];
    if ((tid & 63) == 0) sp[tid >> 6] = ss;
    __syncthreads();
    ss = sp[0] + sp[1] + sp[2] + sp[3];
    const float inv = rsqrtf(ss * (1.f / DM) + EPSV);
    const float4 g0 = *(const float4*)(g + tid * 8);
    const float4 g1 = *(const float4*)(g + tid * 8 + 4);
    union { bf16x8 vv; __hip_bfloat16 e[8]; } o;
    o.e[0] = __float2bfloat16(v[0] * inv * g0.x); o.e[1] = __float2bfloat16(v[1] * inv * g0.y);
    o.e[2] = __float2bfloat16(v[2] * inv * g0.z); o.e[3] = __float2bfloat16(v[3] * inv * g0.w);
    o.e[4] = __float2bfloat16(v[4] * inv * g1.x); o.e[5] = __float2bfloat16(v[5] * inv * g1.y);
    o.e[6] = __float2bfloat16(v[6] * inv * g1.z); o.e[7] = __float2bfloat16(v[7] * inv * g1.w);
    *(bf16x8*)(x + base) = o.vv;
}

// ---------------- h += sum of 4 bf16 partials (final layer) ----------------
__global__ void red4res_k(const __hip_bfloat16* __restrict__ p, long n, float* __restrict__ h) {
    const long i = ((long)blockIdx.x * 256 + threadIdx.x) * 8;
    float v[8];
    *(float4*)&v[0] = *(const float4*)(h + i);
    *(float4*)&v[4] = *(const float4*)(h + i + 4);
#pragma unroll
    for (int z = 0; z < 4; ++z) {
        union { bf16x8 vv; __hip_bfloat16 e[8]; } b;
        b.vv = *(const bf16x8*)(p + (long)z * n + i);
#pragma unroll
        for (int j = 0; j < 8; ++j) v[j] += __bfloat162float(b.e[j]);
    }
    *(float4*)(h + i) = *(float4*)&v[0];
    *(float4*)(h + i + 4) = *(float4*)&v[4];
}

// ---------------- per-head RMSNorm + RoPE; input = sum of 2 bf16 split-K partials ----------------
__global__ void qknorm_rope_k(const __hip_bfloat16* __restrict__ in, long zStride, int inOff,
                              const float* __restrict__ ns,
                              const float* __restrict__ cosT, const float* __restrict__ sinT,
                              __hip_bfloat16* __restrict__ out, int nheads) {
    const int idx = blockIdx.x * 4 + (threadIdx.x >> 6);
    const int lane = threadIdx.x & 63;
    const int s = idx / nheads;
    const int hh = idx - s * nheads;
    const long base = (long)s * QKVN + inOff + hh * HDIM;
    const float x1 = __bfloat162float(in[base + lane]) + __bfloat162float(in[zStride + base + lane]);
    const float x2 = __bfloat162float(in[base + lane + 64]) + __bfloat162float(in[zStride + base + lane + 64]);
    float ss = wave_sum(x1 * x1 + x2 * x2);
    const float inv = rsqrtf(ss * (1.f / HDIM) + EPSV);
    const float n1 = x1 * inv * ns[lane];
    const float n2 = x2 * inv * ns[lane + 64];
    const float c1 = cosT[s * HDIM + lane],      c2 = cosT[s * HDIM + 64 + lane];
    const float s1 = sinT[s * HDIM + lane],      s2 = sinT[s * HDIM + 64 + lane];
    __hip_bfloat16* w = out + ((long)hh * SEQ + s) * HDIM;
    w[lane]      = __float2bfloat16(n1 * c1 - n2 * s1);
    w[lane + 64] = __float2bfloat16(n2 * c2 + n1 * s2);
}

// ---------------- V transpose (2 bf16 partials -> vt [kv][d][s] bf16) ----------------
__global__ void vtrans_k(const __hip_bfloat16* __restrict__ vf, long zStride, int colOff,
                         __hip_bfloat16* __restrict__ vt) {
    __shared__ float tile[64][65];
    const int s0 = blockIdx.x * 64, d0 = blockIdx.y * 64, kv = blockIdx.z;
    const int lane = threadIdx.x & 63, part = threadIdx.x >> 6;
    for (int r = part; r < 64; r += 4) {
        const long idx = (long)(s0 + r) * QKVN + colOff + kv * HDIM + d0 + lane;
        tile[r][lane] = __bfloat162float(vf[idx]) + __bfloat162float(vf[zStride + idx]);
    }
    __syncthreads();
    for (int r = part; r < 64; r += 4)
        vt[((long)kv * HDIM + d0 + r) * SEQ + s0 + lane] = __float2bfloat16(tile[lane][r]);
}

// ---------------- silu(g)*u elementwise, in place on g ----------------
__global__ void silu_mul_k(__hip_bfloat16* __restrict__ g, const __hip_bfloat16* __restrict__ u) {
    const long i = ((long)blockIdx.x * 256 + threadIdx.x) * 8;
    union { bf16x8 v; __hip_bfloat16 h[8]; } a, b, o;
    a.v = *(const bf16x8*)(g + i);
    b.v = *(const bf16x8*)(u + i);
#pragma unroll
    for (int j = 0; j < 8; ++j) {
        const float xx = __bfloat162float(a.h[j]);
        const float yy = __bfloat162float(b.h[j]);
        const float sv = xx / (1.f + __expf(-xx));
        o.h[j] = __float2bfloat16(sv * yy);
    }
    *(bf16x8*)(g + i) = o.v;
}

// ============== flash attention v3: paired q-slabs for uniform load ==============
// Block = (slab pair, head); 4 waves; wave w owns q rows w*16..w*16+15 of the active slab.
// Slab pair (x, 31-x): (x+1) + (32-x) = 33 kv-tiles per block -- exactly uniform.
// Q/O in regs; kv-tile 64; K/V LDS double-buffered (next tile's gload16 issued at tile
// start, vmcnt(0)+barrier at tile end); softmax wave-local (16-lane shfl).
__global__ __launch_bounds__(256)
void flash_k(const __hip_bfloat16* __restrict__ qb, const __hip_bfloat16* __restrict__ kb,
             const __hip_bfloat16* __restrict__ vt, __hip_bfloat16* __restrict__ ctx) {
    __shared__ __align__(16) char ks[2][16384];   // [64 kv][128 d], swizzled
    __shared__ __align__(16) char vs[2][16384];   // [128 d][64 kv], swizzled
    __shared__ __align__(16) char ps[4][2048];    // per-wave P [16 q][64 kv], swizzled

    const int tid = threadIdx.x;
    const int lane = tid & 63;
    const int wid = tid >> 6;
    const int l15 = lane & 15;
    const int l4 = lane >> 4;

    const int h = blockIdx.y;
    const int kvh = h >> 1;          // GROUP = 2
    const float scale = 0.0883883476483184405f;  // 1/sqrt(128)

    auto stageK = [&](int buf, int kt) {
        const __hip_bfloat16* kg = kb + ((long)kvh * SEQ + kt * 64) * HDIM;
#pragma unroll
        for (int i = 0; i < 4; ++i) {
            const int c = i * 256 + tid;          // row c>>4 (64 kv), slot c&15
            const int r = c >> 4, s = c & 15;
            gload16(kg + (long)r * HDIM + ((s ^ (r & 7)) * 8), ks[buf] + c * 16);
        }
    };
    auto stageV = [&](int buf, int kt) {
        const __hip_bfloat16* vg = vt + (long)kvh * HDIM * SEQ + kt * 64;
#pragma unroll
        for (int i = 0; i < 4; ++i) {
            const int c = i * 256 + tid;          // row c>>3 (128 d), slot c&7
            const int r = c >> 3, s = c & 7;
            gload16(vg + (long)r * SEQ + ((s ^ (r & 7)) * 8), vs[buf] + c * 16);
        }
    };

#pragma unroll
    for (int half = 0; half < 2; ++half) {
        const int x = half ? 31 - blockIdx.x : blockIdx.x;
        const int q0 = x * 64;
        const int nkt = x + 1;

        // Q -> registers: A-frag (row = lane&15, k-chunk = lane>>4), 4 k-steps of 32 d
        bf16x8 aq[4];
        {
            const __hip_bfloat16* qg = qb + ((long)h * SEQ + q0 + wid * 16 + l15) * HDIM + l4 * 8;
#pragma unroll
            for (int kk = 0; kk < 4; ++kk) aq[kk] = *(const bf16x8*)(qg + kk * 32);
        }

        float mreg[4], lreg[4];
#pragma unroll
        for (int j = 0; j < 4; ++j) { mreg[j] = -3.0e38f; lreg[j] = 0.f; }
        f32x4 oacc[8];
#pragma unroll
        for (int n = 0; n < 8; ++n) oacc[n] = (f32x4){0.f, 0.f, 0.f, 0.f};

        stageK(0, 0); stageV(0, 0);
        asm volatile("s_waitcnt vmcnt(0)" ::: "memory");
        __builtin_amdgcn_s_barrier();

        for (int kt = 0; kt < nkt; ++kt) {
            const int cur = kt & 1;
            if (kt + 1 < nkt) { stageK(cur ^ 1, kt + 1); stageV(cur ^ 1, kt + 1); }

            // ---- S = Q K^T ----
            f32x4 sac[4];
#pragma unroll
            for (int n = 0; n < 4; ++n) sac[n] = (f32x4){0.f, 0.f, 0.f, 0.f};
            __builtin_amdgcn_s_setprio(1);
#pragma unroll
            for (int kk = 0; kk < 4; ++kk) {
#pragma unroll
                for (int n = 0; n < 4; ++n) {
                    const int r = n * 16 + l15;
                    const bf16x8 bk = *(const bf16x8*)(ks[cur] + r * 256 + (((kk * 4 + l4) ^ (r & 7)) << 4));
                    sac[n] = __builtin_amdgcn_mfma_f32_16x16x32_bf16(aq[kk], bk, sac[n], 0, 0, 0);
                }
            }
            __builtin_amdgcn_s_setprio(0);

            // ---- wave-local online softmax ----
            const bool diag = (kt + 1 == nkt);
            float mnj[4], alj[4];
#pragma unroll
            for (int j = 0; j < 4; ++j) {
                float mx = -3.0e38f;
#pragma unroll
                for (int n = 0; n < 4; ++n) {
                    float v = sac[n][j] * scale;
                    if (diag && (n * 16 + l15 > wid * 16 + l4 * 4 + j)) v = -3.0e38f;
                    sac[n][j] = v;
                    mx = fmaxf(mx, v);
                }
#pragma unroll
                for (int o = 1; o < 16; o <<= 1) mx = fmaxf(mx, __shfl_xor(mx, o));
                const float mn = fmaxf(mreg[j], mx);
                mnj[j] = mn;
                alj[j] = __expf(mreg[j] - mn);
                mreg[j] = mn;
            }
#pragma unroll
            for (int j = 0; j < 4; ++j) {
                float rs = 0.f;
#pragma unroll
                for (int n = 0; n < 4; ++n) {
                    const float e = __expf(sac[n][j] - mnj[j]);
                    sac[n][j] = e;
                    rs += e;
                }
#pragma unroll
                for (int o = 1; o < 16; o <<= 1) rs += __shfl_xor(rs, o);
                lreg[j] = lreg[j] * alj[j] + rs;
#pragma unroll
                for (int n2 = 0; n2 < 8; ++n2) oacc[n2][j] *= alj[j];
            }

            // ---- P -> per-wave LDS (swizzled), then O += P V ----
            char* pw = ps[wid];
#pragma unroll
            for (int n = 0; n < 4; ++n)
#pragma unroll
                for (int j = 0; j < 4; ++j) {
                    const int r = l4 * 4 + j;
                    const int col = n * 16 + l15;
                    *(__hip_bfloat16*)(pw + r * 128 + (((col >> 3) ^ (r & 7)) << 4) + (col & 7) * 2) =
                        __float2bfloat16(sac[n][j]);
                }
            asm volatile("s_waitcnt lgkmcnt(0)" ::: "memory");
            __builtin_amdgcn_sched_barrier(0);
            __builtin_amdgcn_s_setprio(1);
#pragma unroll
            for (int kk = 0; kk < 2; ++kk) {
                const bf16x8 ap = *(const bf16x8*)(pw + l15 * 128 + (((kk * 4 + l4) ^ (l15 & 7)) << 4));
#pragma unroll
                for (int n2 = 0; n2 < 8; ++n2) {
                    const int r = n2 * 16 + l15;
                    const bf16x8 bv = *(const bf16x8*)(vs[cur] + r * 128 + (((kk * 4 + l4) ^ (r & 7)) << 4));
                    oacc[n2] = __builtin_amdgcn_mfma_f32_16x16x32_bf16(ap, bv, oacc[n2], 0, 0, 0);
                }
            }
            __builtin_amdgcn_s_setprio(0);

            asm volatile("s_waitcnt vmcnt(0)" ::: "memory");   // next tile staged
            __builtin_amdgcn_s_barrier();                      // all waves done with cur
        }

        // ---- normalize and store this slab ----
#pragma unroll
        for (int j = 0; j < 4; ++j) {
            const float inv = 1.f / lreg[j];
            const long rowb = (long)(q0 + wid * 16 + l4 * 4 + j) * (NHEAD * HDIM) + h * HDIM;
#pragma unroll
            for (int n2 = 0; n2 < 8; ++n2)
                ctx[rowb + n2 * 16 + l15] = __float2bfloat16(oacc[n2][j] * inv);
        }
    }
}

// ============== 256x256 8-wave GEMM, m201 phase schedule + T1 XCD swizzle ==============
// OUT: 0 = f32 store, 1 = bf16 store. (All callers use OUT=1 now.)
template <int OUT>
__global__ __launch_bounds__(512, 2)
void g8p(const __hip_bfloat16* __restrict__ A, const __hip_bfloat16* __restrict__ B,
         void* __restrict__ Cv, int kLen, int ldA, int ldB, int ldC,
         long bZStride, long cZStride, int kZStride) {
    __shared__ __align__(16) char sA[2][2][16384];
    __shared__ __align__(16) char sB[2][2][16384];

    const int tid = threadIdx.x;
    const int lane = tid & 63;
    const int wid = tid >> 6;
    const int wr = wid >> 2;
    const int wc = wid & 3;
    const int l15 = lane & 15;
    const int l4 = lane >> 4;

    // T1: XCD-contiguous tile mapping (all grids have gx*gy % 8 == 0)
    const int gx = gridDim.x;
    const int nwg = gx * gridDim.y;
    const int lin = blockIdx.y * gx + blockIdx.x;
    const int cpx = nwg >> 3;
    const int swz = (lin & 7) * cpx + (lin >> 3);
    const int row0 = (swz / gx) * 256;
    const int col0 = (swz % gx) * 256;

    const int z = blockIdx.z;
    B += (long)z * bZStride;
    const long cOff = (long)z * cZStride;
    const int k0z = z * kZStride;
    const int nk = kLen / 64;

    f32x4 acc[8][4];
#pragma unroll
    for (int m = 0; m < 8; ++m)
#pragma unroll
        for (int n = 0; n < 4; ++n)
            acc[m][n] = (f32x4){0.f, 0.f, 0.f, 0.f};

    auto stage = [&](int kind, int kt) {
        const int k0 = k0z + kt * 64;
        const __hip_bfloat16* base;
        int ld_;
        char* dst;
        if (kind < 2) { base = A + (long)(row0 + kind * 128) * ldA; ld_ = ldA; dst = sA[kt & 1][kind]; }
        else          { base = B + (long)(col0 + (kind - 2) * 128) * ldB; ld_ = ldB; dst = sB[kt & 1][kind - 2]; }
#pragma unroll
        for (int i = 0; i < 2; ++i) {
            const int c = i * 512 + tid;
            const int r = c >> 3;
            const int s = c & 7;
            gload16(base + (long)r * ld_ + k0 + ((s ^ (r & 7)) * 8), dst + c * 16);
        }
    };

    auto readA = [&](int buf, int p, int mm, int ks) -> bf16x8 {
        const int r = p * 32 + mm * 16 + l15;
        const int q = ks * 4 + l4;
        return *(const bf16x8*)(sA[buf][wr] + r * 128 + ((q ^ (r & 7)) << 4));
    };
    auto readB = [&](int buf, int nn, int ks) -> bf16x8 {
        const int r = (wc & 1) * 64 + nn * 16 + l15;
        const int q = ks * 4 + l4;
        return *(const bf16x8*)(sB[buf][wc >> 1] + r * 128 + ((q ^ (r & 7)) << 4));
    };

    stage(0, 0); stage(1, 0); stage(2, 0); stage(3, 0);
    stage(2, 1); stage(3, 1);
    asm volatile("s_waitcnt vmcnt(4)" ::: "memory");
    __builtin_amdgcn_s_barrier();

    bf16x8 bfrag[4][2];
    for (int t = 0; t < nk; ++t) {
        const int cur = t & 1;
#pragma unroll
        for (int p = 0; p < 4; ++p) {
            bf16x8 a[2][2];
            a[0][0] = readA(cur, p, 0, 0); a[0][1] = readA(cur, p, 0, 1);
            a[1][0] = readA(cur, p, 1, 0); a[1][1] = readA(cur, p, 1, 1);
            if (p == 0) {
#pragma unroll
                for (int n = 0; n < 4; ++n) {
                    bfrag[n][0] = readB(cur, n, 0);
                    bfrag[n][1] = readB(cur, n, 1);
                }
            }
            if (p == 0 && t + 1 < nk) stage(0, t + 1);
            if (p == 1 && t + 1 < nk) stage(1, t + 1);
            if (p == 2 && t + 2 < nk) stage(2, t + 2);
            if (p == 3 && t + 2 < nk) stage(3, t + 2);

            if (p == 0) asm volatile("s_waitcnt lgkmcnt(8)" ::: "memory");
            __builtin_amdgcn_sched_barrier(0);
            if (p == 3) {
                if (t + 2 < nk)      asm volatile("s_waitcnt vmcnt(4)" ::: "memory");
                else if (t + 1 < nk) asm volatile("s_waitcnt vmcnt(0)" ::: "memory");
            }
            __builtin_amdgcn_s_barrier();
            asm volatile("s_waitcnt lgkmcnt(0)" ::: "memory");
            __builtin_amdgcn_sched_barrier(0);

            __builtin_amdgcn_s_setprio(1);
#pragma unroll
            for (int ks = 0; ks < 2; ++ks)
#pragma unroll
                for (int mm = 0; mm < 2; ++mm)
#pragma unroll
                    for (int n = 0; n < 4; ++n)
                        acc[p * 2 + mm][n] = __builtin_amdgcn_mfma_f32_16x16x32_bf16(
                            a[mm][ks], bfrag[n][ks], acc[p * 2 + mm][n], 0, 0, 0);
            __builtin_amdgcn_s_setprio(0);
            __builtin_amdgcn_sched_barrier(0);
            __builtin_amdgcn_s_barrier();
        }
    }

#pragma unroll
    for (int m = 0; m < 8; ++m) {
#pragma unroll
        for (int n = 0; n < 4; ++n) {
            const int rb = row0 + wr * 128 + m * 16 + l4 * 4;
            const int cc = col0 + wc * 64 + n * 16 + l15;
#pragma unroll
            for (int j = 0; j < 4; ++j) {
                const long idx = cOff + (long)(rb + j) * ldC + cc;
                if constexpr (OUT == 0) ((float*)Cv)[idx] = acc[m][n][j];
                else                    ((__hip_bfloat16*)Cv)[idx] = __float2bfloat16(acc[m][n][j]);
            }
        }
    }
}

// ---------------- host orchestration ----------------
extern "C" void kernel_launch(void* const* d_in, const int* in_sizes, int n_in,
                              void* d_out, int out_size, void* d_ws, size_t ws_size,
                              hipStream_t stream) {
    const int*   ids  = (const int*)d_in[0];
    const float* cosT = (const float*)d_in[2];
    const float* sinT = (const float*)d_in[3];
    const float* emb  = (const float*)d_in[4];
    const float* q_w  = (const float*)d_in[5];
    const float* k_w  = (const float*)d_in[6];
    const float* v_w  = (const float*)d_in[7];
    const float* o_w  = (const float*)d_in[8];
    const float* qn   = (const float*)d_in[9];
    const float* kn   = (const float*)d_in[10];
    const float* ln1  = (const float*)d_in[11];
    const float* ln2  = (const float*)d_in[12];
    const float* gw   = (const float*)d_in[13];
    const float* uw   = (const float*)d_in[14];
    const float* dw   = (const float*)d_in[15];

    char* W = (char*)d_ws;
    size_t off = 0;
    auto take = [&](size_t nb) { char* p = W + off; off += (nb + 255) & ~(size_t)255; return p; };

    // persistent bf16 weights
    __hip_bfloat16* wqkv = (__hip_bfloat16*) take((size_t)NLAYER * QKVN * DM * 2);
    __hip_bfloat16* wo   = (__hip_bfloat16*) take((size_t)NLAYER * DM * (NHEAD * HDIM) * 2);
    __hip_bfloat16* wgu  = (__hip_bfloat16*) take((size_t)NLAYER * 2 * FFN * DM * 2);
    __hip_bfloat16* wd   = (__hip_bfloat16*) take((size_t)NLAYER * DM * FFN * 2);
    // activations
    float*          h    = (float*)          take((size_t)SEQ * DM * 4);
    __hip_bfloat16* x    = (__hip_bfloat16*) take((size_t)SEQ * DM * 2);
    __hip_bfloat16* part = (__hip_bfloat16*) take((size_t)4 * SEQ * DM * 2);   // bf16 split-K partials
    __hip_bfloat16* qb   = (__hip_bfloat16*) take((size_t)NHEAD * SEQ * HDIM * 2);
    __hip_bfloat16* kb   = (__hip_bfloat16*) take((size_t)NKVH * SEQ * HDIM * 2);
    __hip_bfloat16* vt   = (__hip_bfloat16*) take((size_t)NKVH * HDIM * SEQ * 2);
    __hip_bfloat16* ctx  = (__hip_bfloat16*) take((size_t)SEQ * NHEAD * HDIM * 2);
    __hip_bfloat16* go2  = (__hip_bfloat16*) take((size_t)2 * SEQ * FFN * 2);
    if (off > ws_size) return;

    auto cvt = [&](const float* src, __hip_bfloat16* dst, long n) {
        cvt_bf16_k<<<(int)(n / 2048), 256, 0, stream>>>(src, dst);
    };

    // ---- convert all weights up front ----
    for (int l = 0; l < NLAYER; ++l) {
        __hip_bfloat16* base = wqkv + (size_t)l * QKVN * DM;
        cvt(q_w + (size_t)l * (NHEAD * HDIM) * DM, base,                               (long)(NHEAD * HDIM) * DM);
        cvt(k_w + (size_t)l * (NKVH * HDIM) * DM,  base + (size_t)(NHEAD * HDIM) * DM, (long)(NKVH * HDIM) * DM);
        cvt(v_w + (size_t)l * (NKVH * HDIM) * DM,  base + (size_t)(NHEAD * HDIM + NKVH * HDIM) * DM, (long)(NKVH * HDIM) * DM);
        cvt(gw + (size_t)l * FFN * DM, wgu + (size_t)(2 * l)     * FFN * DM, (long)FFN * DM);
        cvt(uw + (size_t)l * FFN * DM, wgu + (size_t)(2 * l + 1) * FFN * DM, (long)FFN * DM);
    }
    cvt(o_w, wo, (long)NLAYER * DM * (NHEAD * HDIM));
    cvt(dw,  wd, (long)NLAYER * DM * FFN);

    embed_k<<<SEQ, 256, 0, stream>>>(ids, emb, h);
    rmsnorm_k<<<SEQ, 256, 0, stream>>>(h, ln1, x);

    const long nQKV = (long)SEQ * QKVN;
    const long nDM  = (long)SEQ * DM;

    for (int l = 0; l < NLAYER; ++l) {
        // QKV: split-K x2 -> bf16 partials (consumers sum them)
        g8p<1><<<dim3(QKVN / 256, SEQ / 256, 2), 512, 0, stream>>>(
            x, wqkv + (size_t)l * QKVN * DM, part, DM / 2, DM, DM, QKVN,
            0L, nQKV, DM / 2);

        qknorm_rope_k<<<SEQ * NHEAD / 4, 256, 0, stream>>>(
            part, nQKV, 0, qn + l * HDIM, cosT, sinT, qb, NHEAD);
        qknorm_rope_k<<<SEQ * NKVH / 4, 256, 0, stream>>>(
            part, nQKV, NHEAD * HDIM, kn + l * HDIM, cosT, sinT, kb, NKVH);
        vtrans_k<<<dim3(SEQ / 64, HDIM / 64, NKVH), 256, 0, stream>>>(
            part, nQKV, NHEAD * HDIM + NKVH * HDIM, vt);

        // flash attention v3: 16 slab-pairs x 16 heads = 256 blocks, uniform 33 tiles each
        flash_k<<<dim3(16, NHEAD), 256, 0, stream>>>(qb, kb, vt, ctx);

        // O: split-K x4 -> bf16 partials -> fused (h += sum; x = rmsnorm(h)*ln2)
        g8p<1><<<dim3(DM / 256, SEQ / 256, 4), 512, 0, stream>>>(
            ctx, wo + (size_t)l * DM * (NHEAD * HDIM), part, (NHEAD * HDIM) / 4,
            NHEAD * HDIM, NHEAD * HDIM, DM, 0L, nDM, (NHEAD * HDIM) / 4);
        rmsnorm_res4_k<<<SEQ, 256, 0, stream>>>(part, nDM, h, ln2 + l * DM, x);

        // gate+up merged (z picks weight & output)
        g8p<1><<<dim3(FFN / 256, SEQ / 256, 2), 512, 0, stream>>>(
            x, wgu + (size_t)(2 * l) * FFN * DM, go2, DM, DM, DM, FFN,
            (long)FFN * DM, (long)SEQ * FFN, 0);
        silu_mul_k<<<(int)(((long)SEQ * FFN) / 2048), 256, 0, stream>>>(go2, go2 + (size_t)SEQ * FFN);

        // down: split-K x4 -> bf16 partials -> fused with next layer's ln1 (or final reduce)
        g8p<1><<<dim3(DM / 256, SEQ / 256, 4), 512, 0, stream>>>(
            go2, wd + (size_t)l * DM * FFN, part, FFN / 4,
            FFN, FFN, DM, 0L, nDM, FFN / 4);
        if (l + 1 < NLAYER)
            rmsnorm_res4_k<<<SEQ, 256, 0, stream>>>(part, nDM, h, ln1 + (l + 1) * DM, x);
        else
            red4res_k<<<(int)(nDM / 2048), 256, 0, stream>>>(part, nDM, h);
    }

    hipMemcpyAsync(d_out, h, (size_t)out_size * sizeof(float), hipMemcpyDeviceToDevice, stream);
}

// Round 11
// 913.476 us; speedup vs baseline: 1.4605x; 1.0572x over previous
//
#include <hip/hip_runtime.h>
#include <hip/hip_bf16.h>

// ---------------- model constants ----------------
static constexpr int SEQ   = 2048;
static constexpr int DM    = 2048;
static constexpr int NHEAD = 16;
static constexpr int NKVH  = 8;
static constexpr int HDIM  = 128;
static constexpr int FFN   = 6144;
static constexpr int NLAYER = 2;
static constexpr float EPSV = 1e-6f;
static constexpr int QKVN  = NHEAD * HDIM + 2 * NKVH * HDIM;  // 4096 fused QKV cols

typedef __attribute__((ext_vector_type(8))) short bf16x8;
typedef __attribute__((ext_vector_type(4))) float f32x4;

__device__ __forceinline__ float wave_sum(float v) {
#pragma unroll
    for (int o = 32; o > 0; o >>= 1) v += __shfl_xor(v, o);
    return v;
}

// async global->LDS, 16B per lane
__device__ __forceinline__ void gload16(const void* g, void* l) {
    __builtin_amdgcn_global_load_lds(
        (const __attribute__((address_space(1))) void*)g,
        (__attribute__((address_space(3))) void*)l,
        16, 0, 0);
}

// ---------------- f32 -> bf16 weight convert ----------------
__global__ void cvt_bf16_k(const float* __restrict__ in, __hip_bfloat16* __restrict__ out) {
    const long b = ((long)blockIdx.x * 256 + threadIdx.x) * 8;
    const float4 a0 = *(const float4*)(in + b);
    const float4 a1 = *(const float4*)(in + b + 4);
    union { bf16x8 v; __hip_bfloat16 h[8]; } u;
    u.h[0] = __float2bfloat16(a0.x); u.h[1] = __float2bfloat16(a0.y);
    u.h[2] = __float2bfloat16(a0.z); u.h[3] = __float2bfloat16(a0.w);
    u.h[4] = __float2bfloat16(a1.x); u.h[5] = __float2bfloat16(a1.y);
    u.h[6] = __float2bfloat16(a1.z); u.h[7] = __float2bfloat16(a1.w);
    *(bf16x8*)(out + b) = u.v;
}

// ---------------- embedding gather ----------------
__global__ void embed_k(const int* __restrict__ ids, const float* __restrict__ emb,
                        float* __restrict__ h) {
    const int s = blockIdx.x;
    const long src = (long)ids[s] * DM;
    for (int t = threadIdx.x; t < DM; t += 256)
        h[(long)s * DM + t] = emb[src + t];
}

// ---------------- RMSNorm (f32 in -> bf16 out) ----------------
__global__ void rmsnorm_k(const float* __restrict__ in, const float* __restrict__ g,
                          __hip_bfloat16* __restrict__ out) {
    const int row = blockIdx.x;
    const float* r = in + (long)row * DM;
    const int tid = threadIdx.x;
    float v[8];
    float ss = 0.f;
#pragma unroll
    for (int t = 0; t < 8; ++t) { v[t] = r[tid + t * 256]; ss += v[t] * v[t]; }
    ss = wave_sum(ss);
    __shared__ float sp[4];
    if ((tid & 63) == 0) sp[tid >> 6] = ss;
    __syncthreads();
    ss = sp[0] + sp[1] + sp[2] + sp[3];
    const float inv = rsqrtf(ss * (1.f / DM) + EPSV);
    __hip_bfloat16* o_ = out + (long)row * DM;
#pragma unroll
    for (int t = 0; t < 8; ++t) {
        const int j = tid + t * 256;
        o_[j] = __float2bfloat16(v[t] * inv * g[j]);
    }
}

// ---------------- fused: h += sum of 4 bf16 split-K partials; x = rmsnorm(h)*g ----------------
__global__ void rmsnorm_res4_k(const __hip_bfloat16* __restrict__ part, long n,
                               float* __restrict__ h, const float* __restrict__ g,
                               __hip_bfloat16* __restrict__ x) {
    const int row = blockIdx.x;
    const int tid = threadIdx.x;
    const long base = (long)row * DM + tid * 8;
    float v[8];
    *(float4*)&v[0] = *(const float4*)(h + base);
    *(float4*)&v[4] = *(const float4*)(h + base + 4);
#pragma unroll
    for (int z = 0; z < 4; ++z) {
        union { bf16x8 vv; __hip_bfloat16 e[8]; } p;
        p.vv = *(const bf16x8*)(part + (long)z * n + base);
#pragma unroll
        for (int j = 0; j < 8; ++j) v[j] += __bfloat162float(p.e[j]);
    }
    *(float4*)(h + base) = *(float4*)&v[0];
    *(float4*)(h + base + 4) = *(float4*)&v[4];
    float ss = 0.f;
#pragma unroll
    for (int j = 0; j < 8; ++j) ss += v[j] * v[j];
    ss = wave_sum(ss);
    __shared__ float sp[4];
    if ((tid & 63) == 0) sp[tid >> 6] = ss;
    __syncthreads();
    ss = sp[0] + sp[1] + sp[2] + sp[3];
    const float inv = rsqrtf(ss * (1.f / DM) + EPSV);
    const float4 g0 = *(const float4*)(g + tid * 8);
    const float4 g1 = *(const float4*)(g + tid * 8 + 4);
    union { bf16x8 vv; __hip_bfloat16 e[8]; } o;
    o.e[0] = __float2bfloat16(v[0] * inv * g0.x); o.e[1] = __float2bfloat16(v[1] * inv * g0.y);
    o.e[2] = __float2bfloat16(v[2] * inv * g0.z); o.e[3] = __float2bfloat16(v[3] * inv * g0.w);
    o.e[4] = __float2bfloat16(v[4] * inv * g1.x); o.e[5] = __float2bfloat16(v[5] * inv * g1.y);
    o.e[6] = __float2bfloat16(v[6] * inv * g1.z); o.e[7] = __float2bfloat16(v[7] * inv * g1.w);
    *(bf16x8*)(x + base) = o.vv;
}

// ---------------- h += sum of 4 bf16 partials (final layer) ----------------
__global__ void red4res_k(const __hip_bfloat16* __restrict__ p, long n, float* __restrict__ h) {
    const long i = ((long)blockIdx.x * 256 + threadIdx.x) * 8;
    float v[8];
    *(float4*)&v[0] = *(const float4*)(h + i);
    *(float4*)&v[4] = *(const float4*)(h + i + 4);
#pragma unroll
    for (int z = 0; z < 4; ++z) {
        union { bf16x8 vv; __hip_bfloat16 e[8]; } b;
        b.vv = *(const bf16x8*)(p + (long)z * n + i);
#pragma unroll
        for (int j = 0; j < 8; ++j) v[j] += __bfloat162float(b.e[j]);
    }
    *(float4*)(h + i) = *(float4*)&v[0];
    *(float4*)(h + i + 4) = *(float4*)&v[4];
}

// ---------------- per-head RMSNorm + RoPE; input = sum of 2 bf16 split-K partials ----------------
__global__ void qknorm_rope_k(const __hip_bfloat16* __restrict__ in, long zStride, int inOff,
                              const float* __restrict__ ns,
                              const float* __restrict__ cosT, const float* __restrict__ sinT,
                              __hip_bfloat16* __restrict__ out, int nheads) {
    const int idx = blockIdx.x * 4 + (threadIdx.x >> 6);
    const int lane = threadIdx.x & 63;
    const int s = idx / nheads;
    const int hh = idx - s * nheads;
    const long base = (long)s * QKVN + inOff + hh * HDIM;
    const float x1 = __bfloat162float(in[base + lane]) + __bfloat162float(in[zStride + base + lane]);
    const float x2 = __bfloat162float(in[base + lane + 64]) + __bfloat162float(in[zStride + base + lane + 64]);
    float ss = wave_sum(x1 * x1 + x2 * x2);
    const float inv = rsqrtf(ss * (1.f / HDIM) + EPSV);
    const float n1 = x1 * inv * ns[lane];
    const float n2 = x2 * inv * ns[lane + 64];
    const float c1 = cosT[s * HDIM + lane],      c2 = cosT[s * HDIM + 64 + lane];
    const float s1 = sinT[s * HDIM + lane],      s2 = sinT[s * HDIM + 64 + lane];
    __hip_bfloat16* w = out + ((long)hh * SEQ + s) * HDIM;
    w[lane]      = __float2bfloat16(n1 * c1 - n2 * s1);
    w[lane + 64] = __float2bfloat16(n2 * c2 + n1 * s2);
}

// ---------------- V transpose (2 bf16 partials -> vt [kv][d][s] bf16) ----------------
__global__ void vtrans_k(const __hip_bfloat16* __restrict__ vf, long zStride, int colOff,
                         __hip_bfloat16* __restrict__ vt) {
    __shared__ float tile[64][65];
    const int s0 = blockIdx.x * 64, d0 = blockIdx.y * 64, kv = blockIdx.z;
    const int lane = threadIdx.x & 63, part = threadIdx.x >> 6;
    for (int r = part; r < 64; r += 4) {
        const long idx = (long)(s0 + r) * QKVN + colOff + kv * HDIM + d0 + lane;
        tile[r][lane] = __bfloat162float(vf[idx]) + __bfloat162float(vf[zStride + idx]);
    }
    __syncthreads();
    for (int r = part; r < 64; r += 4)
        vt[((long)kv * HDIM + d0 + r) * SEQ + s0 + lane] = __float2bfloat16(tile[lane][r]);
}

// ---------------- fused: out = silu(p0+p1) * (p2+p3)  (gate/up split-K partials) ----------------
__global__ void silu_red2_k(const __hip_bfloat16* __restrict__ p, long n,
                            __hip_bfloat16* __restrict__ out) {
    const long i = ((long)blockIdx.x * 256 + threadIdx.x) * 8;
    union { bf16x8 v; __hip_bfloat16 e[8]; } g0, g1, u0, u1, o;
    g0.v = *(const bf16x8*)(p + i);
    g1.v = *(const bf16x8*)(p + n + i);
    u0.v = *(const bf16x8*)(p + 2 * n + i);
    u1.v = *(const bf16x8*)(p + 3 * n + i);
#pragma unroll
    for (int j = 0; j < 8; ++j) {
        const float g = __bfloat162float(g0.e[j]) + __bfloat162float(g1.e[j]);
        const float u = __bfloat162float(u0.e[j]) + __bfloat162float(u1.e[j]);
        const float sv = g / (1.f + __expf(-g));
        o.e[j] = __float2bfloat16(sv * u);
    }
    *(bf16x8*)(out + i) = o.v;
}

// ============== flash attention v3: paired q-slabs for uniform load (unchanged, R10-passing) ==============
__global__ __launch_bounds__(256)
void flash_k(const __hip_bfloat16* __restrict__ qb, const __hip_bfloat16* __restrict__ kb,
             const __hip_bfloat16* __restrict__ vt, __hip_bfloat16* __restrict__ ctx) {
    __shared__ __align__(16) char ks[2][16384];   // [64 kv][128 d], swizzled
    __shared__ __align__(16) char vs[2][16384];   // [128 d][64 kv], swizzled
    __shared__ __align__(16) char ps[4][2048];    // per-wave P [16 q][64 kv], swizzled

    const int tid = threadIdx.x;
    const int lane = tid & 63;
    const int wid = tid >> 6;
    const int l15 = lane & 15;
    const int l4 = lane >> 4;

    const int h = blockIdx.y;
    const int kvh = h >> 1;          // GROUP = 2
    const float scale = 0.0883883476483184405f;  // 1/sqrt(128)

    auto stageK = [&](int buf, int kt) {
        const __hip_bfloat16* kg = kb + ((long)kvh * SEQ + kt * 64) * HDIM;
#pragma unroll
        for (int i = 0; i < 4; ++i) {
            const int c = i * 256 + tid;
            const int r = c >> 4, s = c & 15;
            gload16(kg + (long)r * HDIM + ((s ^ (r & 7)) * 8), ks[buf] + c * 16);
        }
    };
    auto stageV = [&](int buf, int kt) {
        const __hip_bfloat16* vg = vt + (long)kvh * HDIM * SEQ + kt * 64;
#pragma unroll
        for (int i = 0; i < 4; ++i) {
            const int c = i * 256 + tid;
            const int r = c >> 3, s = c & 7;
            gload16(vg + (long)r * SEQ + ((s ^ (r & 7)) * 8), vs[buf] + c * 16);
        }
    };

#pragma unroll
    for (int half = 0; half < 2; ++half) {
        const int x = half ? 31 - blockIdx.x : blockIdx.x;
        const int q0 = x * 64;
        const int nkt = x + 1;

        bf16x8 aq[4];
        {
            const __hip_bfloat16* qg = qb + ((long)h * SEQ + q0 + wid * 16 + l15) * HDIM + l4 * 8;
#pragma unroll
            for (int kk = 0; kk < 4; ++kk) aq[kk] = *(const bf16x8*)(qg + kk * 32);
        }

        float mreg[4], lreg[4];
#pragma unroll
        for (int j = 0; j < 4; ++j) { mreg[j] = -3.0e38f; lreg[j] = 0.f; }
        f32x4 oacc[8];
#pragma unroll
        for (int n = 0; n < 8; ++n) oacc[n] = (f32x4){0.f, 0.f, 0.f, 0.f};

        stageK(0, 0); stageV(0, 0);
        asm volatile("s_waitcnt vmcnt(0)" ::: "memory");
        __builtin_amdgcn_s_barrier();

        for (int kt = 0; kt < nkt; ++kt) {
            const int cur = kt & 1;
            if (kt + 1 < nkt) { stageK(cur ^ 1, kt + 1); stageV(cur ^ 1, kt + 1); }

            f32x4 sac[4];
#pragma unroll
            for (int n = 0; n < 4; ++n) sac[n] = (f32x4){0.f, 0.f, 0.f, 0.f};
            __builtin_amdgcn_s_setprio(1);
#pragma unroll
            for (int kk = 0; kk < 4; ++kk) {
#pragma unroll
                for (int n = 0; n < 4; ++n) {
                    const int r = n * 16 + l15;
                    const bf16x8 bk = *(const bf16x8*)(ks[cur] + r * 256 + (((kk * 4 + l4) ^ (r & 7)) << 4));
                    sac[n] = __builtin_amdgcn_mfma_f32_16x16x32_bf16(aq[kk], bk, sac[n], 0, 0, 0);
                }
            }
            __builtin_amdgcn_s_setprio(0);

            const bool diag = (kt + 1 == nkt);
            float mnj[4], alj[4];
#pragma unroll
            for (int j = 0; j < 4; ++j) {
                float mx = -3.0e38f;
#pragma unroll
                for (int n = 0; n < 4; ++n) {
                    float v = sac[n][j] * scale;
                    if (diag && (n * 16 + l15 > wid * 16 + l4 * 4 + j)) v = -3.0e38f;
                    sac[n][j] = v;
                    mx = fmaxf(mx, v);
                }
#pragma unroll
                for (int o = 1; o < 16; o <<= 1) mx = fmaxf(mx, __shfl_xor(mx, o));
                const float mn = fmaxf(mreg[j], mx);
                mnj[j] = mn;
                alj[j] = __expf(mreg[j] - mn);
                mreg[j] = mn;
            }
#pragma unroll
            for (int j = 0; j < 4; ++j) {
                float rs = 0.f;
#pragma unroll
                for (int n = 0; n < 4; ++n) {
                    const float e = __expf(sac[n][j] - mnj[j]);
                    sac[n][j] = e;
                    rs += e;
                }
#pragma unroll
                for (int o = 1; o < 16; o <<= 1) rs += __shfl_xor(rs, o);
                lreg[j] = lreg[j] * alj[j] + rs;
#pragma unroll
                for (int n2 = 0; n2 < 8; ++n2) oacc[n2][j] *= alj[j];
            }

            char* pw = ps[wid];
#pragma unroll
            for (int n = 0; n < 4; ++n)
#pragma unroll
                for (int j = 0; j < 4; ++j) {
                    const int r = l4 * 4 + j;
                    const int col = n * 16 + l15;
                    *(__hip_bfloat16*)(pw + r * 128 + (((col >> 3) ^ (r & 7)) << 4) + (col & 7) * 2) =
                        __float2bfloat16(sac[n][j]);
                }
            asm volatile("s_waitcnt lgkmcnt(0)" ::: "memory");
            __builtin_amdgcn_sched_barrier(0);
            __builtin_amdgcn_s_setprio(1);
#pragma unroll
            for (int kk = 0; kk < 2; ++kk) {
                const bf16x8 ap = *(const bf16x8*)(pw + l15 * 128 + (((kk * 4 + l4) ^ (l15 & 7)) << 4));
#pragma unroll
                for (int n2 = 0; n2 < 8; ++n2) {
                    const int r = n2 * 16 + l15;
                    const bf16x8 bv = *(const bf16x8*)(vs[cur] + r * 128 + (((kk * 4 + l4) ^ (r & 7)) << 4));
                    oacc[n2] = __builtin_amdgcn_mfma_f32_16x16x32_bf16(ap, bv, oacc[n2], 0, 0, 0);
                }
            }
            __builtin_amdgcn_s_setprio(0);

            asm volatile("s_waitcnt vmcnt(0)" ::: "memory");
            __builtin_amdgcn_s_barrier();
        }

#pragma unroll
        for (int j = 0; j < 4; ++j) {
            const float inv = 1.f / lreg[j];
            const long rowb = (long)(q0 + wid * 16 + l4 * 4 + j) * (NHEAD * HDIM) + h * HDIM;
#pragma unroll
            for (int n2 = 0; n2 < 8; ++n2)
                ctx[rowb + n2 * 16 + l15] = __float2bfloat16(oacc[n2][j] * inv);
        }
    }
}

// ============== 256x256 8-wave GEMM, m201 phase schedule (default block mapping) ==============
// z-mapping: B += (z/zDiv)*bZStride; k0 += (z%zDiv)*kZStride; C += z*cZStride.
// OUT: 0 = f32 store, 1 = bf16 store.
template <int OUT>
__global__ __launch_bounds__(512, 2)
void g8p(const __hip_bfloat16* __restrict__ A, const __hip_bfloat16* __restrict__ B,
         void* __restrict__ Cv, int kLen, int ldA, int ldB, int ldC,
         long bZStride, long cZStride, int kZStride, int zDiv) {
    __shared__ __align__(16) char sA[2][2][16384];
    __shared__ __align__(16) char sB[2][2][16384];

    const int tid = threadIdx.x;
    const int lane = tid & 63;
    const int wid = tid >> 6;
    const int wr = wid >> 2;
    const int wc = wid & 3;
    const int l15 = lane & 15;
    const int l4 = lane >> 4;

    const int row0 = blockIdx.y * 256;
    const int col0 = blockIdx.x * 256;

    const int z = blockIdx.z;
    B += (long)(z / zDiv) * bZStride;
    const long cOff = (long)z * cZStride;
    const int k0z = (z % zDiv) * kZStride;
    const int nk = kLen / 64;

    f32x4 acc[8][4];
#pragma unroll
    for (int m = 0; m < 8; ++m)
#pragma unroll
        for (int n = 0; n < 4; ++n)
            acc[m][n] = (f32x4){0.f, 0.f, 0.f, 0.f};

    auto stage = [&](int kind, int kt) {
        const int k0 = k0z + kt * 64;
        const __hip_bfloat16* base;
        int ld_;
        char* dst;
        if (kind < 2) { base = A + (long)(row0 + kind * 128) * ldA; ld_ = ldA; dst = sA[kt & 1][kind]; }
        else          { base = B + (long)(col0 + (kind - 2) * 128) * ldB; ld_ = ldB; dst = sB[kt & 1][kind - 2]; }
#pragma unroll
        for (int i = 0; i < 2; ++i) {
            const int c = i * 512 + tid;
            const int r = c >> 3;
            const int s = c & 7;
            gload16(base + (long)r * ld_ + k0 + ((s ^ (r & 7)) * 8), dst + c * 16);
        }
    };

    auto readA = [&](int buf, int p, int mm, int ks) -> bf16x8 {
        const int r = p * 32 + mm * 16 + l15;
        const int q = ks * 4 + l4;
        return *(const bf16x8*)(sA[buf][wr] + r * 128 + ((q ^ (r & 7)) << 4));
    };
    auto readB = [&](int buf, int nn, int ks) -> bf16x8 {
        const int r = (wc & 1) * 64 + nn * 16 + l15;
        const int q = ks * 4 + l4;
        return *(const bf16x8*)(sB[buf][wc >> 1] + r * 128 + ((q ^ (r & 7)) << 4));
    };

    stage(0, 0); stage(1, 0); stage(2, 0); stage(3, 0);
    stage(2, 1); stage(3, 1);
    asm volatile("s_waitcnt vmcnt(4)" ::: "memory");
    __builtin_amdgcn_s_barrier();

    bf16x8 bfrag[4][2];
    for (int t = 0; t < nk; ++t) {
        const int cur = t & 1;
#pragma unroll
        for (int p = 0; p < 4; ++p) {
            bf16x8 a[2][2];
            a[0][0] = readA(cur, p, 0, 0); a[0][1] = readA(cur, p, 0, 1);
            a[1][0] = readA(cur, p, 1, 0); a[1][1] = readA(cur, p, 1, 1);
            if (p == 0) {
#pragma unroll
                for (int n = 0; n < 4; ++n) {
                    bfrag[n][0] = readB(cur, n, 0);
                    bfrag[n][1] = readB(cur, n, 1);
                }
            }
            if (p == 0 && t + 1 < nk) stage(0, t + 1);
            if (p == 1 && t + 1 < nk) stage(1, t + 1);
            if (p == 2 && t + 2 < nk) stage(2, t + 2);
            if (p == 3 && t + 2 < nk) stage(3, t + 2);

            if (p == 0) asm volatile("s_waitcnt lgkmcnt(8)" ::: "memory");
            __builtin_amdgcn_sched_barrier(0);
            if (p == 3) {
                if (t + 2 < nk)      asm volatile("s_waitcnt vmcnt(4)" ::: "memory");
                else if (t + 1 < nk) asm volatile("s_waitcnt vmcnt(0)" ::: "memory");
            }
            __builtin_amdgcn_s_barrier();
            asm volatile("s_waitcnt lgkmcnt(0)" ::: "memory");
            __builtin_amdgcn_sched_barrier(0);

            __builtin_amdgcn_s_setprio(1);
#pragma unroll
            for (int ks = 0; ks < 2; ++ks)
#pragma unroll
                for (int mm = 0; mm < 2; ++mm)
#pragma unroll
                    for (int n = 0; n < 4; ++n)
                        acc[p * 2 + mm][n] = __builtin_amdgcn_mfma_f32_16x16x32_bf16(
                            a[mm][ks], bfrag[n][ks], acc[p * 2 + mm][n], 0, 0, 0);
            __builtin_amdgcn_s_setprio(0);
            __builtin_amdgcn_sched_barrier(0);
            __builtin_amdgcn_s_barrier();
        }
    }

#pragma unroll
    for (int m = 0; m < 8; ++m) {
#pragma unroll
        for (int n = 0; n < 4; ++n) {
            const int rb = row0 + wr * 128 + m * 16 + l4 * 4;
            const int cc = col0 + wc * 64 + n * 16 + l15;
#pragma unroll
            for (int j = 0; j < 4; ++j) {
                const long idx = cOff + (long)(rb + j) * ldC + cc;
                if constexpr (OUT == 0) ((float*)Cv)[idx] = acc[m][n][j];
                else                    ((__hip_bfloat16*)Cv)[idx] = __float2bfloat16(acc[m][n][j]);
            }
        }
    }
}

// ---------------- host orchestration ----------------
extern "C" void kernel_launch(void* const* d_in, const int* in_sizes, int n_in,
                              void* d_out, int out_size, void* d_ws, size_t ws_size,
                              hipStream_t stream) {
    const int*   ids  = (const int*)d_in[0];
    const float* cosT = (const float*)d_in[2];
    const float* sinT = (const float*)d_in[3];
    const float* emb  = (const float*)d_in[4];
    const float* q_w  = (const float*)d_in[5];
    const float* k_w  = (const float*)d_in[6];
    const float* v_w  = (const float*)d_in[7];
    const float* o_w  = (const float*)d_in[8];
    const float* qn   = (const float*)d_in[9];
    const float* kn   = (const float*)d_in[10];
    const float* ln1  = (const float*)d_in[11];
    const float* ln2  = (const float*)d_in[12];
    const float* gw   = (const float*)d_in[13];
    const float* uw   = (const float*)d_in[14];
    const float* dw   = (const float*)d_in[15];

    char* W = (char*)d_ws;
    size_t off = 0;
    auto take = [&](size_t nb) { char* p = W + off; off += (nb + 255) & ~(size_t)255; return p; };

    // persistent bf16 weights
    __hip_bfloat16* wqkv = (__hip_bfloat16*) take((size_t)NLAYER * QKVN * DM * 2);
    __hip_bfloat16* wo   = (__hip_bfloat16*) take((size_t)NLAYER * DM * (NHEAD * HDIM) * 2);
    __hip_bfloat16* wgu  = (__hip_bfloat16*) take((size_t)NLAYER * 2 * FFN * DM * 2);
    __hip_bfloat16* wd   = (__hip_bfloat16*) take((size_t)NLAYER * DM * FFN * 2);
    // activations
    float*          h    = (float*)          take((size_t)SEQ * DM * 4);
    __hip_bfloat16* x    = (__hip_bfloat16*) take((size_t)SEQ * DM * 2);
    __hip_bfloat16* part = (__hip_bfloat16*) take((size_t)4 * SEQ * FFN * 2);  // bf16 split-K partials (max: gate/up)
    __hip_bfloat16* qb   = (__hip_bfloat16*) take((size_t)NHEAD * SEQ * HDIM * 2);
    __hip_bfloat16* kb   = (__hip_bfloat16*) take((size_t)NKVH * SEQ * HDIM * 2);
    __hip_bfloat16* vt   = (__hip_bfloat16*) take((size_t)NKVH * HDIM * SEQ * 2);
    __hip_bfloat16* ctx  = (__hip_bfloat16*) take((size_t)SEQ * NHEAD * HDIM * 2);
    __hip_bfloat16* go   = (__hip_bfloat16*) take((size_t)SEQ * FFN * 2);
    if (off > ws_size) return;

    auto cvt = [&](const float* src, __hip_bfloat16* dst, long n) {
        cvt_bf16_k<<<(int)(n / 2048), 256, 0, stream>>>(src, dst);
    };

    // ---- convert all weights up front ----
    for (int l = 0; l < NLAYER; ++l) {
        __hip_bfloat16* base = wqkv + (size_t)l * QKVN * DM;
        cvt(q_w + (size_t)l * (NHEAD * HDIM) * DM, base,                               (long)(NHEAD * HDIM) * DM);
        cvt(k_w + (size_t)l * (NKVH * HDIM) * DM,  base + (size_t)(NHEAD * HDIM) * DM, (long)(NKVH * HDIM) * DM);
        cvt(v_w + (size_t)l * (NKVH * HDIM) * DM,  base + (size_t)(NHEAD * HDIM + NKVH * HDIM) * DM, (long)(NKVH * HDIM) * DM);
        cvt(gw + (size_t)l * FFN * DM, wgu + (size_t)(2 * l)     * FFN * DM, (long)FFN * DM);
        cvt(uw + (size_t)l * FFN * DM, wgu + (size_t)(2 * l + 1) * FFN * DM, (long)FFN * DM);
    }
    cvt(o_w, wo, (long)NLAYER * DM * (NHEAD * HDIM));
    cvt(dw,  wd, (long)NLAYER * DM * FFN);

    embed_k<<<SEQ, 256, 0, stream>>>(ids, emb, h);
    rmsnorm_k<<<SEQ, 256, 0, stream>>>(h, ln1, x);

    const long nQKV = (long)SEQ * QKVN;
    const long nDM  = (long)SEQ * DM;
    const long nFFN = (long)SEQ * FFN;

    for (int l = 0; l < NLAYER; ++l) {
        // QKV: split-K x2 -> bf16 partials (z%2 selects K-half; same weight)
        g8p<1><<<dim3(QKVN / 256, SEQ / 256, 2), 512, 0, stream>>>(
            x, wqkv + (size_t)l * QKVN * DM, part, DM / 2, DM, DM, QKVN,
            0L, nQKV, DM / 2, 2);

        qknorm_rope_k<<<SEQ * NHEAD / 4, 256, 0, stream>>>(
            part, nQKV, 0, qn + l * HDIM, cosT, sinT, qb, NHEAD);
        qknorm_rope_k<<<SEQ * NKVH / 4, 256, 0, stream>>>(
            part, nQKV, NHEAD * HDIM, kn + l * HDIM, cosT, sinT, kb, NKVH);
        vtrans_k<<<dim3(SEQ / 64, HDIM / 64, NKVH), 256, 0, stream>>>(
            part, nQKV, NHEAD * HDIM + NKVH * HDIM, vt);

        // flash attention v3: 16 slab-pairs x 16 heads = 256 blocks, uniform 33 tiles each
        flash_k<<<dim3(16, NHEAD), 256, 0, stream>>>(qb, kb, vt, ctx);

        // O: split-K x4 (z%4 selects K-quarter) -> fused (h += sum; x = rmsnorm(h)*ln2)
        g8p<1><<<dim3(DM / 256, SEQ / 256, 4), 512, 0, stream>>>(
            ctx, wo + (size_t)l * DM * (NHEAD * HDIM), part, (NHEAD * HDIM) / 4,
            NHEAD * HDIM, NHEAD * HDIM, DM, 0L, nDM, (NHEAD * HDIM) / 4, 4);
        rmsnorm_res4_k<<<SEQ, 256, 0, stream>>>(part, nDM, h, ln2 + l * DM, x);

        // gate+up: z/2 selects weight (gate|up), z%2 selects K-half -> 768 blocks (3 full rounds)
        g8p<1><<<dim3(FFN / 256, SEQ / 256, 4), 512, 0, stream>>>(
            x, wgu + (size_t)(2 * l) * FFN * DM, part, DM / 2, DM, DM, FFN,
            (long)FFN * DM, nFFN, DM / 2, 2);
        silu_red2_k<<<(int)(nFFN / 2048), 256, 0, stream>>>(part, nFFN, go);

        // down: split-K x4 -> fused with next layer's ln1 (or final reduce)
        g8p<1><<<dim3(DM / 256, SEQ / 256, 4), 512, 0, stream>>>(
            go, wd + (size_t)l * DM * FFN, part, FFN / 4,
            FFN, FFN, DM, 0L, nDM, FFN / 4, 4);
        if (l + 1 < NLAYER)
            rmsnorm_res4_k<<<SEQ, 256, 0, stream>>>(part, nDM, h, ln1 + (l + 1) * DM, x);
        else
            red4res_k<<<(int)(nDM / 2048), 256, 0, stream>>>(part, nDM, h);
    }

    hipMemcpyAsync(d_out, h, (size_t)out_size * sizeof(float), hipMemcpyDeviceToDevice, stream);
}

// Round 12
// 847.907 us; speedup vs baseline: 1.5735x; 1.0773x over previous
//
#include <hip/hip_runtime.h>
#include <hip/hip_bf16.h>

// ---------------- model constants ----------------
static constexpr int SEQ   = 2048;
static constexpr int DM    = 2048;
static constexpr int NHEAD = 16;
static constexpr int NKVH  = 8;
static constexpr int HDIM  = 128;
static constexpr int FFN   = 6144;
static constexpr int NLAYER = 2;
static constexpr float EPSV = 1e-6f;
static constexpr int QKVN  = NHEAD * HDIM + 2 * NKVH * HDIM;  // 4096 fused QKV cols

typedef __attribute__((ext_vector_type(8))) short bf16x8;
typedef __attribute__((ext_vector_type(4))) float f32x4;

__device__ __forceinline__ float wave_sum(float v) {
#pragma unroll
    for (int o = 32; o > 0; o >>= 1) v += __shfl_xor(v, o);
    return v;
}

// async global->LDS, 16B per lane
__device__ __forceinline__ void gload16(const void* g, void* l) {
    __builtin_amdgcn_global_load_lds(
        (const __attribute__((address_space(1))) void*)g,
        (__attribute__((address_space(3))) void*)l,
        16, 0, 0);
}

// ---------------- embedding gather ----------------
__global__ void embed_k(const int* __restrict__ ids, const float* __restrict__ emb,
                        float* __restrict__ h) {
    const int s = blockIdx.x;
    const long src = (long)ids[s] * DM;
    for (int t = threadIdx.x; t < DM; t += 256)
        h[(long)s * DM + t] = emb[src + t];
}

// ---------------- RMSNorm (f32 in -> bf16 out) ----------------
__global__ void rmsnorm_k(const float* __restrict__ in, const float* __restrict__ g,
                          __hip_bfloat16* __restrict__ out) {
    const int row = blockIdx.x;
    const float* r = in + (long)row * DM;
    const int tid = threadIdx.x;
    float v[8];
    float ss = 0.f;
#pragma unroll
    for (int t = 0; t < 8; ++t) { v[t] = r[tid + t * 256]; ss += v[t] * v[t]; }
    ss = wave_sum(ss);
    __shared__ float sp[4];
    if ((tid & 63) == 0) sp[tid >> 6] = ss;
    __syncthreads();
    ss = sp[0] + sp[1] + sp[2] + sp[3];
    const float inv = rsqrtf(ss * (1.f / DM) + EPSV);
    __hip_bfloat16* o_ = out + (long)row * DM;
#pragma unroll
    for (int t = 0; t < 8; ++t) {
        const int j = tid + t * 256;
        o_[j] = __float2bfloat16(v[t] * inv * g[j]);
    }
}

// ---------------- fused: h += sum of 4 bf16 split-K partials; x = rmsnorm(h)*g ----------------
__global__ void rmsnorm_res4_k(const __hip_bfloat16* __restrict__ part, long n,
                               float* __restrict__ h, const float* __restrict__ g,
                               __hip_bfloat16* __restrict__ x) {
    const int row = blockIdx.x;
    const int tid = threadIdx.x;
    const long base = (long)row * DM + tid * 8;
    float v[8];
    *(float4*)&v[0] = *(const float4*)(h + base);
    *(float4*)&v[4] = *(const float4*)(h + base + 4);
#pragma unroll
    for (int z = 0; z < 4; ++z) {
        union { bf16x8 vv; __hip_bfloat16 e[8]; } p;
        p.vv = *(const bf16x8*)(part + (long)z * n + base);
#pragma unroll
        for (int j = 0; j < 8; ++j) v[j] += __bfloat162float(p.e[j]);
    }
    *(float4*)(h + base) = *(float4*)&v[0];
    *(float4*)(h + base + 4) = *(float4*)&v[4];
    float ss = 0.f;
#pragma unroll
    for (int j = 0; j < 8; ++j) ss += v[j] * v[j];
    ss = wave_sum(ss);
    __shared__ float sp[4];
    if ((tid & 63) == 0) sp[tid >> 6] = ss;
    __syncthreads();
    ss = sp[0] + sp[1] + sp[2] + sp[3];
    const float inv = rsqrtf(ss * (1.f / DM) + EPSV);
    const float4 g0 = *(const float4*)(g + tid * 8);
    const float4 g1 = *(const float4*)(g + tid * 8 + 4);
    union { bf16x8 vv; __hip_bfloat16 e[8]; } o;
    o.e[0] = __float2bfloat16(v[0] * inv * g0.x); o.e[1] = __float2bfloat16(v[1] * inv * g0.y);
    o.e[2] = __float2bfloat16(v[2] * inv * g0.z); o.e[3] = __float2bfloat16(v[3] * inv * g0.w);
    o.e[4] = __float2bfloat16(v[4] * inv * g1.x); o.e[5] = __float2bfloat16(v[5] * inv * g1.y);
    o.e[6] = __float2bfloat16(v[6] * inv * g1.z); o.e[7] = __float2bfloat16(v[7] * inv * g1.w);
    *(bf16x8*)(x + base) = o.vv;
}

// ---------------- h += sum of 4 bf16 partials (final layer) ----------------
__global__ void red4res_k(const __hip_bfloat16* __restrict__ p, long n, float* __restrict__ h) {
    const long i = ((long)blockIdx.x * 256 + threadIdx.x) * 8;
    float v[8];
    *(float4*)&v[0] = *(const float4*)(h + i);
    *(float4*)&v[4] = *(const float4*)(h + i + 4);
#pragma unroll
    for (int z = 0; z < 4; ++z) {
        union { bf16x8 vv; __hip_bfloat16 e[8]; } b;
        b.vv = *(const bf16x8*)(p + (long)z * n + i);
#pragma unroll
        for (int j = 0; j < 8; ++j) v[j] += __bfloat162float(b.e[j]);
    }
    *(float4*)(h + i) = *(float4*)&v[0];
    *(float4*)(h + i + 4) = *(float4*)&v[4];
}

// ---------------- per-head RMSNorm + RoPE; input = sum of 2 bf16 split-K partials ----------------
__global__ void qknorm_rope_k(const __hip_bfloat16* __restrict__ in, long zStride, int inOff,
                              const float* __restrict__ ns,
                              const float* __restrict__ cosT, const float* __restrict__ sinT,
                              __hip_bfloat16* __restrict__ out, int nheads) {
    const int idx = blockIdx.x * 4 + (threadIdx.x >> 6);
    const int lane = threadIdx.x & 63;
    const int s = idx / nheads;
    const int hh = idx - s * nheads;
    const long base = (long)s * QKVN + inOff + hh * HDIM;
    const float x1 = __bfloat162float(in[base + lane]) + __bfloat162float(in[zStride + base + lane]);
    const float x2 = __bfloat162float(in[base + lane + 64]) + __bfloat162float(in[zStride + base + lane + 64]);
    float ss = wave_sum(x1 * x1 + x2 * x2);
    const float inv = rsqrtf(ss * (1.f / HDIM) + EPSV);
    const float n1 = x1 * inv * ns[lane];
    const float n2 = x2 * inv * ns[lane + 64];
    const float c1 = cosT[s * HDIM + lane],      c2 = cosT[s * HDIM + 64 + lane];
    const float s1 = sinT[s * HDIM + lane],      s2 = sinT[s * HDIM + 64 + lane];
    __hip_bfloat16* w = out + ((long)hh * SEQ + s) * HDIM;
    w[lane]      = __float2bfloat16(n1 * c1 - n2 * s1);
    w[lane + 64] = __float2bfloat16(n2 * c2 + n1 * s2);
}

// ---------------- V transpose (2 bf16 partials -> vt [kv][d][s] bf16) ----------------
__global__ void vtrans_k(const __hip_bfloat16* __restrict__ vf, long zStride, int colOff,
                         __hip_bfloat16* __restrict__ vt) {
    __shared__ float tile[64][65];
    const int s0 = blockIdx.x * 64, d0 = blockIdx.y * 64, kv = blockIdx.z;
    const int lane = threadIdx.x & 63, part = threadIdx.x >> 6;
    for (int r = part; r < 64; r += 4) {
        const long idx = (long)(s0 + r) * QKVN + colOff + kv * HDIM + d0 + lane;
        tile[r][lane] = __bfloat162float(vf[idx]) + __bfloat162float(vf[zStride + idx]);
    }
    __syncthreads();
    for (int r = part; r < 64; r += 4)
        vt[((long)kv * HDIM + d0 + r) * SEQ + s0 + lane] = __float2bfloat16(tile[lane][r]);
}

// ---------------- fused: out = silu(p0+p1) * (p2+p3)  (gate/up split-K partials) ----------------
__global__ void silu_red2_k(const __hip_bfloat16* __restrict__ p, long n,
                            __hip_bfloat16* __restrict__ out) {
    const long i = ((long)blockIdx.x * 256 + threadIdx.x) * 8;
    union { bf16x8 v; __hip_bfloat16 e[8]; } g0, g1, u0, u1, o;
    g0.v = *(const bf16x8*)(p + i);
    g1.v = *(const bf16x8*)(p + n + i);
    u0.v = *(const bf16x8*)(p + 2 * n + i);
    u1.v = *(const bf16x8*)(p + 3 * n + i);
#pragma unroll
    for (int j = 0; j < 8; ++j) {
        const float g = __bfloat162float(g0.e[j]) + __bfloat162float(g1.e[j]);
        const float u = __bfloat162float(u0.e[j]) + __bfloat162float(u1.e[j]);
        const float sv = g / (1.f + __expf(-g));
        o.e[j] = __float2bfloat16(sv * u);
    }
    *(bf16x8*)(out + i) = o.v;
}

// ============== flash attention v3: paired q-slabs for uniform load (unchanged, R11-passing) ==============
__global__ __launch_bounds__(256)
void flash_k(const __hip_bfloat16* __restrict__ qb, const __hip_bfloat16* __restrict__ kb,
             const __hip_bfloat16* __restrict__ vt, __hip_bfloat16* __restrict__ ctx) {
    __shared__ __align__(16) char ks[2][16384];   // [64 kv][128 d], swizzled
    __shared__ __align__(16) char vs[2][16384];   // [128 d][64 kv], swizzled
    __shared__ __align__(16) char ps[4][2048];    // per-wave P [16 q][64 kv], swizzled

    const int tid = threadIdx.x;
    const int lane = tid & 63;
    const int wid = tid >> 6;
    const int l15 = lane & 15;
    const int l4 = lane >> 4;

    const int h = blockIdx.y;
    const int kvh = h >> 1;          // GROUP = 2
    const float scale = 0.0883883476483184405f;  // 1/sqrt(128)

    auto stageK = [&](int buf, int kt) {
        const __hip_bfloat16* kg = kb + ((long)kvh * SEQ + kt * 64) * HDIM;
#pragma unroll
        for (int i = 0; i < 4; ++i) {
            const int c = i * 256 + tid;
            const int r = c >> 4, s = c & 15;
            gload16(kg + (long)r * HDIM + ((s ^ (r & 7)) * 8), ks[buf] + c * 16);
        }
    };
    auto stageV = [&](int buf, int kt) {
        const __hip_bfloat16* vg = vt + (long)kvh * HDIM * SEQ + kt * 64;
#pragma unroll
        for (int i = 0; i < 4; ++i) {
            const int c = i * 256 + tid;
            const int r = c >> 3, s = c & 7;
            gload16(vg + (long)r * SEQ + ((s ^ (r & 7)) * 8), vs[buf] + c * 16);
        }
    };

#pragma unroll
    for (int half = 0; half < 2; ++half) {
        const int x = half ? 31 - blockIdx.x : blockIdx.x;
        const int q0 = x * 64;
        const int nkt = x + 1;

        bf16x8 aq[4];
        {
            const __hip_bfloat16* qg = qb + ((long)h * SEQ + q0 + wid * 16 + l15) * HDIM + l4 * 8;
#pragma unroll
            for (int kk = 0; kk < 4; ++kk) aq[kk] = *(const bf16x8*)(qg + kk * 32);
        }

        float mreg[4], lreg[4];
#pragma unroll
        for (int j = 0; j < 4; ++j) { mreg[j] = -3.0e38f; lreg[j] = 0.f; }
        f32x4 oacc[8];
#pragma unroll
        for (int n = 0; n < 8; ++n) oacc[n] = (f32x4){0.f, 0.f, 0.f, 0.f};

        stageK(0, 0); stageV(0, 0);
        asm volatile("s_waitcnt vmcnt(0)" ::: "memory");
        __builtin_amdgcn_s_barrier();

        for (int kt = 0; kt < nkt; ++kt) {
            const int cur = kt & 1;
            if (kt + 1 < nkt) { stageK(cur ^ 1, kt + 1); stageV(cur ^ 1, kt + 1); }

            f32x4 sac[4];
#pragma unroll
            for (int n = 0; n < 4; ++n) sac[n] = (f32x4){0.f, 0.f, 0.f, 0.f};
            __builtin_amdgcn_s_setprio(1);
#pragma unroll
            for (int kk = 0; kk < 4; ++kk) {
#pragma unroll
                for (int n = 0; n < 4; ++n) {
                    const int r = n * 16 + l15;
                    const bf16x8 bk = *(const bf16x8*)(ks[cur] + r * 256 + (((kk * 4 + l4) ^ (r & 7)) << 4));
                    sac[n] = __builtin_amdgcn_mfma_f32_16x16x32_bf16(aq[kk], bk, sac[n], 0, 0, 0);
                }
            }
            __builtin_amdgcn_s_setprio(0);

            const bool diag = (kt + 1 == nkt);
            float mnj[4], alj[4];
#pragma unroll
            for (int j = 0; j < 4; ++j) {
                float mx = -3.0e38f;
#pragma unroll
                for (int n = 0; n < 4; ++n) {
                    float v = sac[n][j] * scale;
                    if (diag && (n * 16 + l15 > wid * 16 + l4 * 4 + j)) v = -3.0e38f;
                    sac[n][j] = v;
                    mx = fmaxf(mx, v);
                }
#pragma unroll
                for (int o = 1; o < 16; o <<= 1) mx = fmaxf(mx, __shfl_xor(mx, o));
                const float mn = fmaxf(mreg[j], mx);
                mnj[j] = mn;
                alj[j] = __expf(mreg[j] - mn);
                mreg[j] = mn;
            }
#pragma unroll
            for (int j = 0; j < 4; ++j) {
                float rs = 0.f;
#pragma unroll
                for (int n = 0; n < 4; ++n) {
                    const float e = __expf(sac[n][j] - mnj[j]);
                    sac[n][j] = e;
                    rs += e;
                }
#pragma unroll
                for (int o = 1; o < 16; o <<= 1) rs += __shfl_xor(rs, o);
                lreg[j] = lreg[j] * alj[j] + rs;
#pragma unroll
                for (int n2 = 0; n2 < 8; ++n2) oacc[n2][j] *= alj[j];
            }

            char* pw = ps[wid];
#pragma unroll
            for (int n = 0; n < 4; ++n)
#pragma unroll
                for (int j = 0; j < 4; ++j) {
                    const int r = l4 * 4 + j;
                    const int col = n * 16 + l15;
                    *(__hip_bfloat16*)(pw + r * 128 + (((col >> 3) ^ (r & 7)) << 4) + (col & 7) * 2) =
                        __float2bfloat16(sac[n][j]);
                }
            asm volatile("s_waitcnt lgkmcnt(0)" ::: "memory");
            __builtin_amdgcn_sched_barrier(0);
            __builtin_amdgcn_s_setprio(1);
#pragma unroll
            for (int kk = 0; kk < 2; ++kk) {
                const bf16x8 ap = *(const bf16x8*)(pw + l15 * 128 + (((kk * 4 + l4) ^ (l15 & 7)) << 4));
#pragma unroll
                for (int n2 = 0; n2 < 8; ++n2) {
                    const int r = n2 * 16 + l15;
                    const bf16x8 bv = *(const bf16x8*)(vs[cur] + r * 128 + (((kk * 4 + l4) ^ (r & 7)) << 4));
                    oacc[n2] = __builtin_amdgcn_mfma_f32_16x16x32_bf16(ap, bv, oacc[n2], 0, 0, 0);
                }
            }
            __builtin_amdgcn_s_setprio(0);

            asm volatile("s_waitcnt vmcnt(0)" ::: "memory");
            __builtin_amdgcn_s_barrier();
        }

#pragma unroll
        for (int j = 0; j < 4; ++j) {
            const float inv = 1.f / lreg[j];
            const long rowb = (long)(q0 + wid * 16 + l4 * 4 + j) * (NHEAD * HDIM) + h * HDIM;
#pragma unroll
            for (int n2 = 0; n2 < 8; ++n2)
                ctx[rowb + n2 * 16 + l15] = __float2bfloat16(oacc[n2][j] * inv);
        }
    }
}

// ============== 256x256 8-wave GEMM, m201 phase schedule; B = f32 weights reg-staged+cvt ==============
// A: bf16 (global_load_lds). B: f32 weights, staged global->reg (float4 x4) -> cvt -> ds_write_b128.
// B prefetch 2 K-tiles ahead (loads at p2/p3, cvt+write at next tile's p0/p1); A 1 tile ahead (p0/p1).
// Steady-state vmcnt: p3 asm vmcnt(8) confirms A(t+1) gload_lds, leaves 8 B reg-loads in flight;
// compiler inserts exact waits for the cvt's register reads. C store: bf16.
// ZSEL=1: B weight selected by z/zDiv (gate|up). ZSEL=0: by col0 segment (QKV fused; else single).
template <int ZSEL>
__global__ __launch_bounds__(512, 2)
void g8p(const __hip_bfloat16* __restrict__ A,
         const float* __restrict__ Ba, const float* __restrict__ Bb, const float* __restrict__ Bc,
         __hip_bfloat16* __restrict__ C, int kLen, int ldA, int ldB, int ldC,
         int seg1, int seg2, long cZStride, int kZStride, int zDiv) {
    __shared__ __align__(16) char sA[2][2][16384];   // [buf][half][128 rows x 64 bf16]
    __shared__ __align__(16) char sB[2][2][16384];

    const int tid = threadIdx.x;
    const int lane = tid & 63;
    const int wid = tid >> 6;
    const int wr = wid >> 2;
    const int wc = wid & 3;
    const int l15 = lane & 15;
    const int l4 = lane >> 4;

    const int row0 = blockIdx.y * 256;
    const int col0 = blockIdx.x * 256;
    const int z = blockIdx.z;

    // resolve this block's weight segment (blocks never straddle segment boundaries)
    const float* B;
    int colB;
    if (ZSEL) {
        B = (z / zDiv) ? Bb : Ba; colB = col0;
    } else {
        if (col0 >= seg2)      { B = Bc; colB = col0 - seg2; }
        else if (col0 >= seg1) { B = Bb; colB = col0 - seg1; }
        else                   { B = Ba; colB = col0; }
    }
    const long cOff = (long)z * cZStride;
    const int k0z = (z % zDiv) * kZStride;
    const int nk = kLen / 64;

    f32x4 acc[8][4];
#pragma unroll
    for (int m = 0; m < 8; ++m)
#pragma unroll
        for (int n = 0; n < 4; ++n)
            acc[m][n] = (f32x4){0.f, 0.f, 0.f, 0.f};

    // A half-tile via global_load_lds (2 x 16B chunks per thread)
    auto stageA = [&](int half, int kt) {
        const __hip_bfloat16* base = A + (long)(row0 + half * 128) * ldA;
        char* dst = sA[kt & 1][half];
        const int k0 = k0z + kt * 64;
#pragma unroll
        for (int i = 0; i < 2; ++i) {
            const int c = i * 512 + tid;
            const int r = c >> 3, s = c & 7;
            gload16(base + (long)r * ldA + k0 + ((s ^ (r & 7)) * 8), dst + c * 16);
        }
    };
    // B half-tile: f32 global -> 4x float4 regs (thread covers bf16-slots tid and tid+512)
    auto loadB = [&](float4* rb, int half, int kt) {
        const int k0 = k0z + kt * 64;
        const float* base = B + (long)(colB + half * 128) * ldB + k0;
#pragma unroll
        for (int i = 0; i < 2; ++i) {
            const int sidx = i * 512 + tid;
            const int r = sidx >> 3, q = sidx & 7;
            const float* p = base + (long)r * ldB + q * 8;
            rb[i * 2]     = *(const float4*)p;
            rb[i * 2 + 1] = *(const float4*)(p + 4);
        }
    };
    // cvt regs -> bf16, swizzled ds_write_b128 (2 per thread)
    auto writeB = [&](const float4* rb, int half, int kt) {
        char* dst = sB[kt & 1][half];
#pragma unroll
        for (int i = 0; i < 2; ++i) {
            const int sidx = i * 512 + tid;
            const int r = sidx >> 3, q = sidx & 7;
            union { bf16x8 v; __hip_bfloat16 e[8]; } u;
            const float* f = (const float*)&rb[i * 2];
#pragma unroll
            for (int j = 0; j < 8; ++j) u.e[j] = __float2bfloat16(f[j]);
            *(bf16x8*)(dst + (r * 8 + (q ^ (r & 7))) * 16) = u.v;
        }
    };

    auto readA = [&](int buf, int p, int mm, int ks) -> bf16x8 {
        const int r = p * 32 + mm * 16 + l15;
        const int q = ks * 4 + l4;
        return *(const bf16x8*)(sA[buf][wr] + r * 128 + ((q ^ (r & 7)) << 4));
    };
    auto readB = [&](int buf, int nn, int ks) -> bf16x8 {
        const int r = (wc & 1) * 64 + nn * 16 + l15;
        const int q = ks * 4 + l4;
        return *(const bf16x8*)(sB[buf][wc >> 1] + r * 128 + ((q ^ (r & 7)) << 4));
    };

    float4 rb0[4], rb1[4];
    // ---- prologue: tile 0 fully staged; B(1) reg-loads left in flight ----
    loadB(rb0, 0, 0);
    stageA(0, 0); stageA(1, 0);
    asm volatile("s_waitcnt vmcnt(4)" ::: "memory");   // rb0 landed
    writeB(rb0, 0, 0);
    loadB(rb1, 1, 0);
    asm volatile("s_waitcnt vmcnt(0)" ::: "memory");   // rb1 + A(0) landed
    writeB(rb1, 1, 0);
    if (nk > 1) { loadB(rb0, 0, 1); loadB(rb1, 1, 1); }
    asm volatile("s_waitcnt lgkmcnt(0)" ::: "memory"); // ds_writes committed
    __builtin_amdgcn_sched_barrier(0);
    __builtin_amdgcn_s_barrier();

    bf16x8 bfrag[4][2];
    for (int t = 0; t < nk; ++t) {
        const int cur = t & 1;
#pragma unroll
        for (int p = 0; p < 4; ++p) {
            bf16x8 a[2][2];
            a[0][0] = readA(cur, p, 0, 0); a[0][1] = readA(cur, p, 0, 1);
            a[1][0] = readA(cur, p, 1, 0); a[1][1] = readA(cur, p, 1, 1);
            if (p == 0) {
#pragma unroll
                for (int n = 0; n < 4; ++n) {
                    bfrag[n][0] = readB(cur, n, 0);
                    bfrag[n][1] = readB(cur, n, 1);
                }
            }
            // staging: A(t+1) at p0/p1; B(t+1) cvt+write at p0/p1 (loads from t-1); B(t+2) loads at p2/p3
            if (p == 0 && t + 1 < nk) { stageA(0, t + 1); writeB(rb0, 0, t + 1); }
            if (p == 1 && t + 1 < nk) { stageA(1, t + 1); writeB(rb1, 1, t + 1); }
            if (p == 2 && t + 2 < nk) loadB(rb0, 0, t + 2);
            if (p == 3 && t + 2 < nk) loadB(rb1, 1, t + 2);

            if (p == 0) asm volatile("s_waitcnt lgkmcnt(8)" ::: "memory");
            __builtin_amdgcn_sched_barrier(0);
            if (p == 3) {
                if (t + 2 < nk)      asm volatile("s_waitcnt vmcnt(8)" ::: "memory");  // A(t+1) landed; 8 B loads flying
                else if (t + 1 < nk) asm volatile("s_waitcnt vmcnt(0)" ::: "memory");  // final A drain
            }
            __builtin_amdgcn_s_barrier();
            asm volatile("s_waitcnt lgkmcnt(0)" ::: "memory");
            __builtin_amdgcn_sched_barrier(0);

            __builtin_amdgcn_s_setprio(1);
#pragma unroll
            for (int ks = 0; ks < 2; ++ks)
#pragma unroll
                for (int mm = 0; mm < 2; ++mm)
#pragma unroll
                    for (int n = 0; n < 4; ++n)
                        acc[p * 2 + mm][n] = __builtin_amdgcn_mfma_f32_16x16x32_bf16(
                            a[mm][ks], bfrag[n][ks], acc[p * 2 + mm][n], 0, 0, 0);
            __builtin_amdgcn_s_setprio(0);
            __builtin_amdgcn_sched_barrier(0);
            __builtin_amdgcn_s_barrier();
        }
    }

    // epilogue: C/D layout col = lane&15, row = (lane>>4)*4 + reg (m89-verified)
#pragma unroll
    for (int m = 0; m < 8; ++m) {
#pragma unroll
        for (int n = 0; n < 4; ++n) {
            const int rb = row0 + wr * 128 + m * 16 + l4 * 4;
            const int cc = col0 + wc * 64 + n * 16 + l15;
#pragma unroll
            for (int j = 0; j < 4; ++j)
                C[cOff + (long)(rb + j) * ldC + cc] = __float2bfloat16(acc[m][n][j]);
        }
    }
}

// ---------------- host orchestration ----------------
extern "C" void kernel_launch(void* const* d_in, const int* in_sizes, int n_in,
                              void* d_out, int out_size, void* d_ws, size_t ws_size,
                              hipStream_t stream) {
    const int*   ids  = (const int*)d_in[0];
    const float* cosT = (const float*)d_in[2];
    const float* sinT = (const float*)d_in[3];
    const float* emb  = (const float*)d_in[4];
    const float* q_w  = (const float*)d_in[5];
    const float* k_w  = (const float*)d_in[6];
    const float* v_w  = (const float*)d_in[7];
    const float* o_w  = (const float*)d_in[8];
    const float* qn   = (const float*)d_in[9];
    const float* kn   = (const float*)d_in[10];
    const float* ln1  = (const float*)d_in[11];
    const float* ln2  = (const float*)d_in[12];
    const float* gw   = (const float*)d_in[13];
    const float* uw   = (const float*)d_in[14];
    const float* dw   = (const float*)d_in[15];

    char* W = (char*)d_ws;
    size_t off = 0;
    auto take = [&](size_t nb) { char* p = W + off; off += (nb + 255) & ~(size_t)255; return p; };

    // activations (weights now read directly from d_in as f32)
    float*          h    = (float*)          take((size_t)SEQ * DM * 4);
    __hip_bfloat16* x    = (__hip_bfloat16*) take((size_t)SEQ * DM * 2);
    __hip_bfloat16* part = (__hip_bfloat16*) take((size_t)4 * SEQ * FFN * 2);  // bf16 split-K partials
    __hip_bfloat16* qb   = (__hip_bfloat16*) take((size_t)NHEAD * SEQ * HDIM * 2);
    __hip_bfloat16* kb   = (__hip_bfloat16*) take((size_t)NKVH * SEQ * HDIM * 2);
    __hip_bfloat16* vt   = (__hip_bfloat16*) take((size_t)NKVH * HDIM * SEQ * 2);
    __hip_bfloat16* ctx  = (__hip_bfloat16*) take((size_t)SEQ * NHEAD * HDIM * 2);
    __hip_bfloat16* go   = (__hip_bfloat16*) take((size_t)SEQ * FFN * 2);
    if (off > ws_size) return;

    embed_k<<<SEQ, 256, 0, stream>>>(ids, emb, h);
    rmsnorm_k<<<SEQ, 256, 0, stream>>>(h, ln1, x);

    const long nQKV = (long)SEQ * QKVN;
    const long nDM  = (long)SEQ * DM;
    const long nFFN = (long)SEQ * FFN;
    const int BIG = 1 << 30;

    for (int l = 0; l < NLAYER; ++l) {
        const float* qwl = q_w + (size_t)l * (NHEAD * HDIM) * DM;
        const float* kwl = k_w + (size_t)l * (NKVH * HDIM) * DM;
        const float* vwl = v_w + (size_t)l * (NKVH * HDIM) * DM;
        const float* owl = o_w + (size_t)l * DM * (NHEAD * HDIM);
        const float* gwl = gw  + (size_t)l * FFN * DM;
        const float* uwl = uw  + (size_t)l * FFN * DM;
        const float* dwl = dw  + (size_t)l * DM * FFN;

        // QKV fused (col segments q|k|v): split-K x2 -> bf16 partials
        g8p<0><<<dim3(QKVN / 256, SEQ / 256, 2), 512, 0, stream>>>(
            x, qwl, kwl, vwl, part, DM / 2, DM, DM, QKVN,
            NHEAD * HDIM, NHEAD * HDIM + NKVH * HDIM, nQKV, DM / 2, 2);

        qknorm_rope_k<<<SEQ * NHEAD / 4, 256, 0, stream>>>(
            part, nQKV, 0, qn + l * HDIM, cosT, sinT, qb, NHEAD);
        qknorm_rope_k<<<SEQ * NKVH / 4, 256, 0, stream>>>(
            part, nQKV, NHEAD * HDIM, kn + l * HDIM, cosT, sinT, kb, NKVH);
        vtrans_k<<<dim3(SEQ / 64, HDIM / 64, NKVH), 256, 0, stream>>>(
            part, nQKV, NHEAD * HDIM + NKVH * HDIM, vt);

        // flash attention v3: 16 slab-pairs x 16 heads = 256 blocks
        flash_k<<<dim3(16, NHEAD), 256, 0, stream>>>(qb, kb, vt, ctx);

        // O: split-K x4 -> fused (h += sum; x = rmsnorm(h)*ln2)
        g8p<0><<<dim3(DM / 256, SEQ / 256, 4), 512, 0, stream>>>(
            ctx, owl, owl, owl, part, (NHEAD * HDIM) / 4, NHEAD * HDIM, NHEAD * HDIM, DM,
            BIG, BIG, nDM, (NHEAD * HDIM) / 4, 4);
        rmsnorm_res4_k<<<SEQ, 256, 0, stream>>>(part, nDM, h, ln2 + l * DM, x);

        // gate+up: z/2 selects weight, z%2 selects K-half -> 768 blocks
        g8p<1><<<dim3(FFN / 256, SEQ / 256, 4), 512, 0, stream>>>(
            x, gwl, uwl, uwl, part, DM / 2, DM, DM, FFN,
            BIG, BIG, nFFN, DM / 2, 2);
        silu_red2_k<<<(int)(nFFN / 2048), 256, 0, stream>>>(part, nFFN, go);

        // down: split-K x4 -> fused with next layer's ln1 (or final reduce)
        g8p<0><<<dim3(DM / 256, SEQ / 256, 4), 512, 0, stream>>>(
            go, dwl, dwl, dwl, part, FFN / 4, FFN, FFN, DM,
            BIG, BIG, nDM, FFN / 4, 4);
        if (l + 1 < NLAYER)
            rmsnorm_res4_k<<<SEQ, 256, 0, stream>>>(part, nDM, h, ln1 + (l + 1) * DM, x);
        else
            red4res_k<<<(int)(nDM / 2048), 256, 0, stream>>>(part, nDM, h);
    }

    hipMemcpyAsync(d_out, h, (size_t)out_size * sizeof(float), hipMemcpyDeviceToDevice, stream);
}

// Round 13
// 842.687 us; speedup vs baseline: 1.5832x; 1.0062x over previous
//
#include <hip/hip_runtime.h>
#include <hip/hip_bf16.h>

// ---------------- model constants ----------------
static constexpr int SEQ   = 2048;
static constexpr int DM    = 2048;
static constexpr int NHEAD = 16;
static constexpr int NKVH  = 8;
static constexpr int HDIM  = 128;
static constexpr int FFN   = 6144;
static constexpr int NLAYER = 2;
static constexpr float EPSV = 1e-6f;
static constexpr int QKVN  = NHEAD * HDIM + 2 * NKVH * HDIM;  // 4096 fused QKV cols

typedef __attribute__((ext_vector_type(8))) short bf16x8;
typedef __attribute__((ext_vector_type(4))) float f32x4;

__device__ __forceinline__ float wave_sum(float v) {
#pragma unroll
    for (int o = 32; o > 0; o >>= 1) v += __shfl_xor(v, o);
    return v;
}

// async global->LDS, 16B per lane
__device__ __forceinline__ void gload16(const void* g, void* l) {
    __builtin_amdgcn_global_load_lds(
        (const __attribute__((address_space(1))) void*)g,
        (__attribute__((address_space(3))) void*)l,
        16, 0, 0);
}

// ---------------- embedding gather ----------------
__global__ void embed_k(const int* __restrict__ ids, const float* __restrict__ emb,
                        float* __restrict__ h) {
    const int s = blockIdx.x;
    const long src = (long)ids[s] * DM;
    for (int t = threadIdx.x; t < DM; t += 256)
        h[(long)s * DM + t] = emb[src + t];
}

// ---------------- RMSNorm (f32 in -> bf16 out) ----------------
__global__ void rmsnorm_k(const float* __restrict__ in, const float* __restrict__ g,
                          __hip_bfloat16* __restrict__ out) {
    const int row = blockIdx.x;
    const float* r = in + (long)row * DM;
    const int tid = threadIdx.x;
    float v[8];
    float ss = 0.f;
#pragma unroll
    for (int t = 0; t < 8; ++t) { v[t] = r[tid + t * 256]; ss += v[t] * v[t]; }
    ss = wave_sum(ss);
    __shared__ float sp[4];
    if ((tid & 63) == 0) sp[tid >> 6] = ss;
    __syncthreads();
    ss = sp[0] + sp[1] + sp[2] + sp[3];
    const float inv = rsqrtf(ss * (1.f / DM) + EPSV);
    __hip_bfloat16* o_ = out + (long)row * DM;
#pragma unroll
    for (int t = 0; t < 8; ++t) {
        const int j = tid + t * 256;
        o_[j] = __float2bfloat16(v[t] * inv * g[j]);
    }
}

// ---------------- fused: h += sum of 4 bf16 split-K partials; x = rmsnorm(h)*g ----------------
__global__ void rmsnorm_res4_k(const __hip_bfloat16* __restrict__ part, long n,
                               float* __restrict__ h, const float* __restrict__ g,
                               __hip_bfloat16* __restrict__ x) {
    const int row = blockIdx.x;
    const int tid = threadIdx.x;
    const long base = (long)row * DM + tid * 8;
    float v[8];
    *(float4*)&v[0] = *(const float4*)(h + base);
    *(float4*)&v[4] = *(const float4*)(h + base + 4);
#pragma unroll
    for (int z = 0; z < 4; ++z) {
        union { bf16x8 vv; __hip_bfloat16 e[8]; } p;
        p.vv = *(const bf16x8*)(part + (long)z * n + base);
#pragma unroll
        for (int j = 0; j < 8; ++j) v[j] += __bfloat162float(p.e[j]);
    }
    *(float4*)(h + base) = *(float4*)&v[0];
    *(float4*)(h + base + 4) = *(float4*)&v[4];
    float ss = 0.f;
#pragma unroll
    for (int j = 0; j < 8; ++j) ss += v[j] * v[j];
    ss = wave_sum(ss);
    __shared__ float sp[4];
    if ((tid & 63) == 0) sp[tid >> 6] = ss;
    __syncthreads();
    ss = sp[0] + sp[1] + sp[2] + sp[3];
    const float inv = rsqrtf(ss * (1.f / DM) + EPSV);
    const float4 g0 = *(const float4*)(g + tid * 8);
    const float4 g1 = *(const float4*)(g + tid * 8 + 4);
    union { bf16x8 vv; __hip_bfloat16 e[8]; } o;
    o.e[0] = __float2bfloat16(v[0] * inv * g0.x); o.e[1] = __float2bfloat16(v[1] * inv * g0.y);
    o.e[2] = __float2bfloat16(v[2] * inv * g0.z); o.e[3] = __float2bfloat16(v[3] * inv * g0.w);
    o.e[4] = __float2bfloat16(v[4] * inv * g1.x); o.e[5] = __float2bfloat16(v[5] * inv * g1.y);
    o.e[6] = __float2bfloat16(v[6] * inv * g1.z); o.e[7] = __float2bfloat16(v[7] * inv * g1.w);
    *(bf16x8*)(x + base) = o.vv;
}

// ---------------- h += sum of 4 bf16 partials (final layer) ----------------
__global__ void red4res_k(const __hip_bfloat16* __restrict__ p, long n, float* __restrict__ h) {
    const long i = ((long)blockIdx.x * 256 + threadIdx.x) * 8;
    float v[8];
    *(float4*)&v[0] = *(const float4*)(h + i);
    *(float4*)&v[4] = *(const float4*)(h + i + 4);
#pragma unroll
    for (int z = 0; z < 4; ++z) {
        union { bf16x8 vv; __hip_bfloat16 e[8]; } b;
        b.vv = *(const bf16x8*)(p + (long)z * n + i);
#pragma unroll
        for (int j = 0; j < 8; ++j) v[j] += __bfloat162float(b.e[j]);
    }
    *(float4*)(h + i) = *(float4*)&v[0];
    *(float4*)(h + i + 4) = *(float4*)&v[4];
}

// ---------------- per-head RMSNorm + RoPE; input = sum of 2 bf16 split-K partials ----------------
__global__ void qknorm_rope_k(const __hip_bfloat16* __restrict__ in, long zStride, int inOff,
                              const float* __restrict__ ns,
                              const float* __restrict__ cosT, const float* __restrict__ sinT,
                              __hip_bfloat16* __restrict__ out, int nheads) {
    const int idx = blockIdx.x * 4 + (threadIdx.x >> 6);
    const int lane = threadIdx.x & 63;
    const int s = idx / nheads;
    const int hh = idx - s * nheads;
    const long base = (long)s * QKVN + inOff + hh * HDIM;
    const float x1 = __bfloat162float(in[base + lane]) + __bfloat162float(in[zStride + base + lane]);
    const float x2 = __bfloat162float(in[base + lane + 64]) + __bfloat162float(in[zStride + base + lane + 64]);
    float ss = wave_sum(x1 * x1 + x2 * x2);
    const float inv = rsqrtf(ss * (1.f / HDIM) + EPSV);
    const float n1 = x1 * inv * ns[lane];
    const float n2 = x2 * inv * ns[lane + 64];
    const float c1 = cosT[s * HDIM + lane],      c2 = cosT[s * HDIM + 64 + lane];
    const float s1 = sinT[s * HDIM + lane],      s2 = sinT[s * HDIM + 64 + lane];
    __hip_bfloat16* w = out + ((long)hh * SEQ + s) * HDIM;
    w[lane]      = __float2bfloat16(n1 * c1 - n2 * s1);
    w[lane + 64] = __float2bfloat16(n2 * c2 + n1 * s2);
}

// ---------------- V transpose (2 bf16 partials -> vt [kv][d][s] bf16) ----------------
__global__ void vtrans_k(const __hip_bfloat16* __restrict__ vf, long zStride, int colOff,
                         __hip_bfloat16* __restrict__ vt) {
    __shared__ float tile[64][65];
    const int s0 = blockIdx.x * 64, d0 = blockIdx.y * 64, kv = blockIdx.z;
    const int lane = threadIdx.x & 63, part = threadIdx.x >> 6;
    for (int r = part; r < 64; r += 4) {
        const long idx = (long)(s0 + r) * QKVN + colOff + kv * HDIM + d0 + lane;
        tile[r][lane] = __bfloat162float(vf[idx]) + __bfloat162float(vf[zStride + idx]);
    }
    __syncthreads();
    for (int r = part; r < 64; r += 4)
        vt[((long)kv * HDIM + d0 + r) * SEQ + s0 + lane] = __float2bfloat16(tile[lane][r]);
}

// ---------------- fused: out = silu(p0+p1) * (p2+p3)  (gate/up split-K partials) ----------------
__global__ void silu_red2_k(const __hip_bfloat16* __restrict__ p, long n,
                            __hip_bfloat16* __restrict__ out) {
    const long i = ((long)blockIdx.x * 256 + threadIdx.x) * 8;
    union { bf16x8 v; __hip_bfloat16 e[8]; } g0, g1, u0, u1, o;
    g0.v = *(const bf16x8*)(p + i);
    g1.v = *(const bf16x8*)(p + n + i);
    u0.v = *(const bf16x8*)(p + 2 * n + i);
    u1.v = *(const bf16x8*)(p + 3 * n + i);
#pragma unroll
    for (int j = 0; j < 8; ++j) {
        const float g = __bfloat162float(g0.e[j]) + __bfloat162float(g1.e[j]);
        const float u = __bfloat162float(u0.e[j]) + __bfloat162float(u1.e[j]);
        const float sv = g / (1.f + __expf(-g));
        o.e[j] = __float2bfloat16(sv * u);
    }
    *(bf16x8*)(out + i) = o.v;
}

// ============== flash attention v3: paired q-slabs for uniform load (unchanged, R12-passing) ==============
__global__ __launch_bounds__(256)
void flash_k(const __hip_bfloat16* __restrict__ qb, const __hip_bfloat16* __restrict__ kb,
             const __hip_bfloat16* __restrict__ vt, __hip_bfloat16* __restrict__ ctx) {
    __shared__ __align__(16) char ks[2][16384];   // [64 kv][128 d], swizzled
    __shared__ __align__(16) char vs[2][16384];   // [128 d][64 kv], swizzled
    __shared__ __align__(16) char ps[4][2048];    // per-wave P [16 q][64 kv], swizzled

    const int tid = threadIdx.x;
    const int lane = tid & 63;
    const int wid = tid >> 6;
    const int l15 = lane & 15;
    const int l4 = lane >> 4;

    const int h = blockIdx.y;
    const int kvh = h >> 1;          // GROUP = 2
    const float scale = 0.0883883476483184405f;  // 1/sqrt(128)

    auto stageK = [&](int buf, int kt) {
        const __hip_bfloat16* kg = kb + ((long)kvh * SEQ + kt * 64) * HDIM;
#pragma unroll
        for (int i = 0; i < 4; ++i) {
            const int c = i * 256 + tid;
            const int r = c >> 4, s = c & 15;
            gload16(kg + (long)r * HDIM + ((s ^ (r & 7)) * 8), ks[buf] + c * 16);
        }
    };
    auto stageV = [&](int buf, int kt) {
        const __hip_bfloat16* vg = vt + (long)kvh * HDIM * SEQ + kt * 64;
#pragma unroll
        for (int i = 0; i < 4; ++i) {
            const int c = i * 256 + tid;
            const int r = c >> 3, s = c & 7;
            gload16(vg + (long)r * SEQ + ((s ^ (r & 7)) * 8), vs[buf] + c * 16);
        }
    };

#pragma unroll
    for (int half = 0; half < 2; ++half) {
        const int x = half ? 31 - blockIdx.x : blockIdx.x;
        const int q0 = x * 64;
        const int nkt = x + 1;

        bf16x8 aq[4];
        {
            const __hip_bfloat16* qg = qb + ((long)h * SEQ + q0 + wid * 16 + l15) * HDIM + l4 * 8;
#pragma unroll
            for (int kk = 0; kk < 4; ++kk) aq[kk] = *(const bf16x8*)(qg + kk * 32);
        }

        float mreg[4], lreg[4];
#pragma unroll
        for (int j = 0; j < 4; ++j) { mreg[j] = -3.0e38f; lreg[j] = 0.f; }
        f32x4 oacc[8];
#pragma unroll
        for (int n = 0; n < 8; ++n) oacc[n] = (f32x4){0.f, 0.f, 0.f, 0.f};

        stageK(0, 0); stageV(0, 0);
        asm volatile("s_waitcnt vmcnt(0)" ::: "memory");
        __builtin_amdgcn_s_barrier();

        for (int kt = 0; kt < nkt; ++kt) {
            const int cur = kt & 1;
            if (kt + 1 < nkt) { stageK(cur ^ 1, kt + 1); stageV(cur ^ 1, kt + 1); }

            f32x4 sac[4];
#pragma unroll
            for (int n = 0; n < 4; ++n) sac[n] = (f32x4){0.f, 0.f, 0.f, 0.f};
            __builtin_amdgcn_s_setprio(1);
#pragma unroll
            for (int kk = 0; kk < 4; ++kk) {
#pragma unroll
                for (int n = 0; n < 4; ++n) {
                    const int r = n * 16 + l15;
                    const bf16x8 bk = *(const bf16x8*)(ks[cur] + r * 256 + (((kk * 4 + l4) ^ (r & 7)) << 4));
                    sac[n] = __builtin_amdgcn_mfma_f32_16x16x32_bf16(aq[kk], bk, sac[n], 0, 0, 0);
                }
            }
            __builtin_amdgcn_s_setprio(0);

            const bool diag = (kt + 1 == nkt);
            float mnj[4], alj[4];
#pragma unroll
            for (int j = 0; j < 4; ++j) {
                float mx = -3.0e38f;
#pragma unroll
                for (int n = 0; n < 4; ++n) {
                    float v = sac[n][j] * scale;
                    if (diag && (n * 16 + l15 > wid * 16 + l4 * 4 + j)) v = -3.0e38f;
                    sac[n][j] = v;
                    mx = fmaxf(mx, v);
                }
#pragma unroll
                for (int o = 1; o < 16; o <<= 1) mx = fmaxf(mx, __shfl_xor(mx, o));
                const float mn = fmaxf(mreg[j], mx);
                mnj[j] = mn;
                alj[j] = __expf(mreg[j] - mn);
                mreg[j] = mn;
            }
#pragma unroll
            for (int j = 0; j < 4; ++j) {
                float rs = 0.f;
#pragma unroll
                for (int n = 0; n < 4; ++n) {
                    const float e = __expf(sac[n][j] - mnj[j]);
                    sac[n][j] = e;
                    rs += e;
                }
#pragma unroll
                for (int o = 1; o < 16; o <<= 1) rs += __shfl_xor(rs, o);
                lreg[j] = lreg[j] * alj[j] + rs;
#pragma unroll
                for (int n2 = 0; n2 < 8; ++n2) oacc[n2][j] *= alj[j];
            }

            char* pw = ps[wid];
#pragma unroll
            for (int n = 0; n < 4; ++n)
#pragma unroll
                for (int j = 0; j < 4; ++j) {
                    const int r = l4 * 4 + j;
                    const int col = n * 16 + l15;
                    *(__hip_bfloat16*)(pw + r * 128 + (((col >> 3) ^ (r & 7)) << 4) + (col & 7) * 2) =
                        __float2bfloat16(sac[n][j]);
                }
            asm volatile("s_waitcnt lgkmcnt(0)" ::: "memory");
            __builtin_amdgcn_sched_barrier(0);
            __builtin_amdgcn_s_setprio(1);
#pragma unroll
            for (int kk = 0; kk < 2; ++kk) {
                const bf16x8 ap = *(const bf16x8*)(pw + l15 * 128 + (((kk * 4 + l4) ^ (l15 & 7)) << 4));
#pragma unroll
                for (int n2 = 0; n2 < 8; ++n2) {
                    const int r = n2 * 16 + l15;
                    const bf16x8 bv = *(const bf16x8*)(vs[cur] + r * 128 + (((kk * 4 + l4) ^ (r & 7)) << 4));
                    oacc[n2] = __builtin_amdgcn_mfma_f32_16x16x32_bf16(ap, bv, oacc[n2], 0, 0, 0);
                }
            }
            __builtin_amdgcn_s_setprio(0);

            asm volatile("s_waitcnt vmcnt(0)" ::: "memory");
            __builtin_amdgcn_s_barrier();
        }

#pragma unroll
        for (int j = 0; j < 4; ++j) {
            const float inv = 1.f / lreg[j];
            const long rowb = (long)(q0 + wid * 16 + l4 * 4 + j) * (NHEAD * HDIM) + h * HDIM;
#pragma unroll
            for (int n2 = 0; n2 < 8; ++n2)
                ctx[rowb + n2 * 16 + l15] = __float2bfloat16(oacc[n2][j] * inv);
        }
    }
}

// ============== 256x256 8-wave GEMM, 2-phase/K-tile (32 MFMA per barrier); B = f32 reg-staged+cvt ==============
// A: bf16 (global_load_lds). B: f32 weights -> reg (float4 x4) -> cvt -> swizzled ds_write_b128.
// Per K-tile: P0 = {24 ds_read (A-quads 0,1 + B) || writeB(t+1) + stageA(t+1) -> lgkmcnt(8) ->
//   barrier -> lgkmcnt(0) -> 32 MFMA -> barrier};  P1 = {8 ds_read (A-quads 2,3) || loadB(t+2) ->
//   [vmcnt(8): A(t+1) landed, B(t+2) regs in flight] -> barrier -> lgkmcnt(0) -> 32 MFMA -> barrier}.
// ZSEL=1: B weight by z/zDiv (gate|up). ZSEL=0: by col0 segment (QKV fused; else single).
template <int ZSEL>
__global__ __launch_bounds__(512, 2)
void g8p(const __hip_bfloat16* __restrict__ A,
         const float* __restrict__ Ba, const float* __restrict__ Bb, const float* __restrict__ Bc,
         __hip_bfloat16* __restrict__ C, int kLen, int ldA, int ldB, int ldC,
         int seg1, int seg2, long cZStride, int kZStride, int zDiv) {
    __shared__ __align__(16) char sA[2][2][16384];   // [buf][half][128 rows x 64 bf16]
    __shared__ __align__(16) char sB[2][2][16384];

    const int tid = threadIdx.x;
    const int lane = tid & 63;
    const int wid = tid >> 6;
    const int wr = wid >> 2;
    const int wc = wid & 3;
    const int l15 = lane & 15;
    const int l4 = lane >> 4;

    const int row0 = blockIdx.y * 256;
    const int col0 = blockIdx.x * 256;
    const int z = blockIdx.z;

    // resolve this block's weight segment (blocks never straddle segment boundaries)
    const float* B;
    int colB;
    if (ZSEL) {
        B = (z / zDiv) ? Bb : Ba; colB = col0;
    } else {
        if (col0 >= seg2)      { B = Bc; colB = col0 - seg2; }
        else if (col0 >= seg1) { B = Bb; colB = col0 - seg1; }
        else                   { B = Ba; colB = col0; }
    }
    const long cOff = (long)z * cZStride;
    const int k0z = (z % zDiv) * kZStride;
    const int nk = kLen / 64;

    f32x4 acc[8][4];
#pragma unroll
    for (int m = 0; m < 8; ++m)
#pragma unroll
        for (int n = 0; n < 4; ++n)
            acc[m][n] = (f32x4){0.f, 0.f, 0.f, 0.f};

    // A half-tile via global_load_lds (2 x 16B chunks per thread)
    auto stageA = [&](int half, int kt) {
        const __hip_bfloat16* base = A + (long)(row0 + half * 128) * ldA;
        char* dst = sA[kt & 1][half];
        const int k0 = k0z + kt * 64;
#pragma unroll
        for (int i = 0; i < 2; ++i) {
            const int c = i * 512 + tid;
            const int r = c >> 3, s = c & 7;
            gload16(base + (long)r * ldA + k0 + ((s ^ (r & 7)) * 8), dst + c * 16);
        }
    };
    // B half-tile: f32 global -> 4x float4 regs (thread covers bf16-slots tid and tid+512)
    auto loadB = [&](float4* rb, int half, int kt) {
        const int k0 = k0z + kt * 64;
        const float* base = B + (long)(colB + half * 128) * ldB + k0;
#pragma unroll
        for (int i = 0; i < 2; ++i) {
            const int sidx = i * 512 + tid;
            const int r = sidx >> 3, q = sidx & 7;
            const float* p = base + (long)r * ldB + q * 8;
            rb[i * 2]     = *(const float4*)p;
            rb[i * 2 + 1] = *(const float4*)(p + 4);
        }
    };
    // cvt regs -> bf16, swizzled ds_write_b128 (2 per thread)
    auto writeB = [&](const float4* rb, int half, int kt) {
        char* dst = sB[kt & 1][half];
#pragma unroll
        for (int i = 0; i < 2; ++i) {
            const int sidx = i * 512 + tid;
            const int r = sidx >> 3, q = sidx & 7;
            union { bf16x8 v; __hip_bfloat16 e[8]; } u;
            const float* f = (const float*)&rb[i * 2];
#pragma unroll
            for (int j = 0; j < 8; ++j) u.e[j] = __float2bfloat16(f[j]);
            *(bf16x8*)(dst + (r * 8 + (q ^ (r & 7))) * 16) = u.v;
        }
    };

    auto readA = [&](int buf, int p, int mm, int ks) -> bf16x8 {
        const int r = p * 32 + mm * 16 + l15;
        const int q = ks * 4 + l4;
        return *(const bf16x8*)(sA[buf][wr] + r * 128 + ((q ^ (r & 7)) << 4));
    };
    auto readB = [&](int buf, int nn, int ks) -> bf16x8 {
        const int r = (wc & 1) * 64 + nn * 16 + l15;
        const int q = ks * 4 + l4;
        return *(const bf16x8*)(sB[buf][wc >> 1] + r * 128 + ((q ^ (r & 7)) << 4));
    };

    float4 rb0[4], rb1[4];
    // ---- prologue: tile 0 fully staged; B(1) reg-loads left in flight ----
    loadB(rb0, 0, 0);
    stageA(0, 0); stageA(1, 0);
    asm volatile("s_waitcnt vmcnt(4)" ::: "memory");   // rb0 landed
    writeB(rb0, 0, 0);
    loadB(rb1, 1, 0);
    asm volatile("s_waitcnt vmcnt(0)" ::: "memory");   // rb1 + A(0) landed
    writeB(rb1, 1, 0);
    if (nk > 1) { loadB(rb0, 0, 1); loadB(rb1, 1, 1); }
    asm volatile("s_waitcnt lgkmcnt(0)" ::: "memory"); // ds_writes committed
    __builtin_amdgcn_sched_barrier(0);
    __builtin_amdgcn_s_barrier();

    bf16x8 bfrag[4][2];
    for (int t = 0; t < nk; ++t) {
        const int cur = t & 1;

        // ======== phase 0: A-quads 0,1 + all B; stage tile t+1 (A gload_lds, B cvt+write) ========
        {
            bf16x8 a0[2][2], a1[2][2];
            a0[0][0] = readA(cur, 0, 0, 0); a0[0][1] = readA(cur, 0, 0, 1);
            a0[1][0] = readA(cur, 0, 1, 0); a0[1][1] = readA(cur, 0, 1, 1);
            a1[0][0] = readA(cur, 1, 0, 0); a1[0][1] = readA(cur, 1, 0, 1);
            a1[1][0] = readA(cur, 1, 1, 0); a1[1][1] = readA(cur, 1, 1, 1);
#pragma unroll
            for (int n = 0; n < 4; ++n) {
                bfrag[n][0] = readB(cur, n, 0);
                bfrag[n][1] = readB(cur, n, 1);
            }
            if (t + 1 < nk) {
                writeB(rb0, 0, t + 1);
                writeB(rb1, 1, t + 1);
                stageA(0, t + 1);
                stageA(1, t + 1);
            }
            asm volatile("s_waitcnt lgkmcnt(8)" ::: "memory");
            __builtin_amdgcn_sched_barrier(0);
            __builtin_amdgcn_s_barrier();
            asm volatile("s_waitcnt lgkmcnt(0)" ::: "memory");
            __builtin_amdgcn_sched_barrier(0);

            __builtin_amdgcn_s_setprio(1);
#pragma unroll
            for (int ks = 0; ks < 2; ++ks) {
#pragma unroll
                for (int mm = 0; mm < 2; ++mm)
#pragma unroll
                    for (int n = 0; n < 4; ++n)
                        acc[mm][n] = __builtin_amdgcn_mfma_f32_16x16x32_bf16(
                            a0[mm][ks], bfrag[n][ks], acc[mm][n], 0, 0, 0);
#pragma unroll
                for (int mm = 0; mm < 2; ++mm)
#pragma unroll
                    for (int n = 0; n < 4; ++n)
                        acc[2 + mm][n] = __builtin_amdgcn_mfma_f32_16x16x32_bf16(
                            a1[mm][ks], bfrag[n][ks], acc[2 + mm][n], 0, 0, 0);
            }
            __builtin_amdgcn_s_setprio(0);
            __builtin_amdgcn_sched_barrier(0);
            __builtin_amdgcn_s_barrier();
        }

        // ======== phase 1: A-quads 2,3; issue B(t+2) reg-loads; counted vmcnt ========
        {
            bf16x8 a2[2][2], a3[2][2];
            a2[0][0] = readA(cur, 2, 0, 0); a2[0][1] = readA(cur, 2, 0, 1);
            a2[1][0] = readA(cur, 2, 1, 0); a2[1][1] = readA(cur, 2, 1, 1);
            a3[0][0] = readA(cur, 3, 0, 0); a3[0][1] = readA(cur, 3, 0, 1);
            a3[1][0] = readA(cur, 3, 1, 0); a3[1][1] = readA(cur, 3, 1, 1);
            if (t + 2 < nk) {
                loadB(rb0, 0, t + 2);
                loadB(rb1, 1, t + 2);
            }
            __builtin_amdgcn_sched_barrier(0);
            if (t + 2 < nk)      asm volatile("s_waitcnt vmcnt(8)" ::: "memory");  // A(t+1) landed; 8 B loads flying
            else if (t + 1 < nk) asm volatile("s_waitcnt vmcnt(0)" ::: "memory");  // final A drain
            __builtin_amdgcn_s_barrier();
            asm volatile("s_waitcnt lgkmcnt(0)" ::: "memory");
            __builtin_amdgcn_sched_barrier(0);

            __builtin_amdgcn_s_setprio(1);
#pragma unroll
            for (int ks = 0; ks < 2; ++ks) {
#pragma unroll
                for (int mm = 0; mm < 2; ++mm)
#pragma unroll
                    for (int n = 0; n < 4; ++n)
                        acc[4 + mm][n] = __builtin_amdgcn_mfma_f32_16x16x32_bf16(
                            a2[mm][ks], bfrag[n][ks], acc[4 + mm][n], 0, 0, 0);
#pragma unroll
                for (int mm = 0; mm < 2; ++mm)
#pragma unroll
                    for (int n = 0; n < 4; ++n)
                        acc[6 + mm][n] = __builtin_amdgcn_mfma_f32_16x16x32_bf16(
                            a3[mm][ks], bfrag[n][ks], acc[6 + mm][n], 0, 0, 0);
            }
            __builtin_amdgcn_s_setprio(0);
            __builtin_amdgcn_sched_barrier(0);
            __builtin_amdgcn_s_barrier();
        }
    }

    // epilogue: C/D layout col = lane&15, row = (lane>>4)*4 + reg (m89-verified)
#pragma unroll
    for (int m = 0; m < 8; ++m) {
#pragma unroll
        for (int n = 0; n < 4; ++n) {
            const int rb = row0 + wr * 128 + m * 16 + l4 * 4;
            const int cc = col0 + wc * 64 + n * 16 + l15;
#pragma unroll
            for (int j = 0; j < 4; ++j)
                C[cOff + (long)(rb + j) * ldC + cc] = __float2bfloat16(acc[m][n][j]);
        }
    }
}

// ---------------- host orchestration ----------------
extern "C" void kernel_launch(void* const* d_in, const int* in_sizes, int n_in,
                              void* d_out, int out_size, void* d_ws, size_t ws_size,
                              hipStream_t stream) {
    const int*   ids  = (const int*)d_in[0];
    const float* cosT = (const float*)d_in[2];
    const float* sinT = (const float*)d_in[3];
    const float* emb  = (const float*)d_in[4];
    const float* q_w  = (const float*)d_in[5];
    const float* k_w  = (const float*)d_in[6];
    const float* v_w  = (const float*)d_in[7];
    const float* o_w  = (const float*)d_in[8];
    const float* qn   = (const float*)d_in[9];
    const float* kn   = (const float*)d_in[10];
    const float* ln1  = (const float*)d_in[11];
    const float* ln2  = (const float*)d_in[12];
    const float* gw   = (const float*)d_in[13];
    const float* uw   = (const float*)d_in[14];
    const float* dw   = (const float*)d_in[15];

    char* W = (char*)d_ws;
    size_t off = 0;
    auto take = [&](size_t nb) { char* p = W + off; off += (nb + 255) & ~(size_t)255; return p; };

    // activations (weights read directly from d_in as f32)
    float*          h    = (float*)          take((size_t)SEQ * DM * 4);
    __hip_bfloat16* x    = (__hip_bfloat16*) take((size_t)SEQ * DM * 2);
    __hip_bfloat16* part = (__hip_bfloat16*) take((size_t)4 * SEQ * FFN * 2);  // bf16 split-K partials
    __hip_bfloat16* qb   = (__hip_bfloat16*) take((size_t)NHEAD * SEQ * HDIM * 2);
    __hip_bfloat16* kb   = (__hip_bfloat16*) take((size_t)NKVH * SEQ * HDIM * 2);
    __hip_bfloat16* vt   = (__hip_bfloat16*) take((size_t)NKVH * HDIM * SEQ * 2);
    __hip_bfloat16* ctx  = (__hip_bfloat16*) take((size_t)SEQ * NHEAD * HDIM * 2);
    __hip_bfloat16* go   = (__hip_bfloat16*) take((size_t)SEQ * FFN * 2);
    if (off > ws_size) return;

    embed_k<<<SEQ, 256, 0, stream>>>(ids, emb, h);
    rmsnorm_k<<<SEQ, 256, 0, stream>>>(h, ln1, x);

    const long nQKV = (long)SEQ * QKVN;
    const long nDM  = (long)SEQ * DM;
    const long nFFN = (long)SEQ * FFN;
    const int BIG = 1 << 30;

    for (int l = 0; l < NLAYER; ++l) {
        const float* qwl = q_w + (size_t)l * (NHEAD * HDIM) * DM;
        const float* kwl = k_w + (size_t)l * (NKVH * HDIM) * DM;
        const float* vwl = v_w + (size_t)l * (NKVH * HDIM) * DM;
        const float* owl = o_w + (size_t)l * DM * (NHEAD * HDIM);
        const float* gwl = gw  + (size_t)l * FFN * DM;
        const float* uwl = uw  + (size_t)l * FFN * DM;
        const float* dwl = dw  + (size_t)l * DM * FFN;

        // QKV fused (col segments q|k|v): split-K x2 -> bf16 partials
        g8p<0><<<dim3(QKVN / 256, SEQ / 256, 2), 512, 0, stream>>>(
            x, qwl, kwl, vwl, part, DM / 2, DM, DM, QKVN,
            NHEAD * HDIM, NHEAD * HDIM + NKVH * HDIM, nQKV, DM / 2, 2);

        qknorm_rope_k<<<SEQ * NHEAD / 4, 256, 0, stream>>>(
            part, nQKV, 0, qn + l * HDIM, cosT, sinT, qb, NHEAD);
        qknorm_rope_k<<<SEQ * NKVH / 4, 256, 0, stream>>>(
            part, nQKV, NHEAD * HDIM, kn + l * HDIM, cosT, sinT, kb, NKVH);
        vtrans_k<<<dim3(SEQ / 64, HDIM / 64, NKVH), 256, 0, stream>>>(
            part, nQKV, NHEAD * HDIM + NKVH * HDIM, vt);

        // flash attention v3: 16 slab-pairs x 16 heads = 256 blocks
        flash_k<<<dim3(16, NHEAD), 256, 0, stream>>>(qb, kb, vt, ctx);

        // O: split-K x4 -> fused (h += sum; x = rmsnorm(h)*ln2)
        g8p<0><<<dim3(DM / 256, SEQ / 256, 4), 512, 0, stream>>>(
            ctx, owl, owl, owl, part, (NHEAD * HDIM) / 4, NHEAD * HDIM, NHEAD * HDIM, DM,
            BIG, BIG, nDM, (NHEAD * HDIM) / 4, 4);
        rmsnorm_res4_k<<<SEQ, 256, 0, stream>>>(part, nDM, h, ln2 + l * DM, x);

        // gate+up: z/2 selects weight, z%2 selects K-half -> 768 blocks
        g8p<1><<<dim3(FFN / 256, SEQ / 256, 4), 512, 0, stream>>>(
            x, gwl, uwl, uwl, part, DM / 2, DM, DM, FFN,
            BIG, BIG, nFFN, DM / 2, 2);
        silu_red2_k<<<(int)(nFFN / 2048), 256, 0, stream>>>(part, nFFN, go);

        // down: split-K x4 -> fused with next layer's ln1 (or final reduce)
        g8p<0><<<dim3(DM / 256, SEQ / 256, 4), 512, 0, stream>>>(
            go, dwl, dwl, dwl, part, FFN / 4, FFN, FFN, DM,
            BIG, BIG, nDM, FFN / 4, 4);
        if (l + 1 < NLAYER)
            rmsnorm_res4_k<<<SEQ, 256, 0, stream>>>(part, nDM, h, ln1 + (l + 1) * DM, x);
        else
            red4res_k<<<(int)(nDM / 2048), 256, 0, stream>>>(part, nDM, h);
    }

    hipMemcpyAsync(d_out, h, (size_t)out_size * sizeof(float), hipMemcpyDeviceToDevice, stream);
}

// Round 14
// 831.397 us; speedup vs baseline: 1.6047x; 1.0136x over previous
//
#include <hip/hip_runtime.h>
#include <hip/hip_bf16.h>

// ---------------- model constants ----------------
static constexpr int SEQ   = 2048;
static constexpr int DM    = 2048;
static constexpr int NHEAD = 16;
static constexpr int NKVH  = 8;
static constexpr int HDIM  = 128;
static constexpr int FFN   = 6144;
static constexpr int NLAYER = 2;
static constexpr float EPSV = 1e-6f;
static constexpr int QKVN  = NHEAD * HDIM + 2 * NKVH * HDIM;  // 4096 fused QKV cols

typedef __attribute__((ext_vector_type(8))) short bf16x8;
typedef __attribute__((ext_vector_type(4))) float f32x4;

__device__ __forceinline__ float wave_sum(float v) {
#pragma unroll
    for (int o = 32; o > 0; o >>= 1) v += __shfl_xor(v, o);
    return v;
}

// async global->LDS, 16B per lane
__device__ __forceinline__ void gload16(const void* g, void* l) {
    __builtin_amdgcn_global_load_lds(
        (const __attribute__((address_space(1))) void*)g,
        (__attribute__((address_space(3))) void*)l,
        16, 0, 0);
}

// ---------------- fused embedding gather + RMSNorm (layer-0 ln1) ----------------
__global__ void embed_rms_k(const int* __restrict__ ids, const float* __restrict__ emb,
                            const float* __restrict__ g, float* __restrict__ h,
                            __hip_bfloat16* __restrict__ x) {
    const int row = blockIdx.x;
    const long src = (long)ids[row] * DM;
    const int tid = threadIdx.x;
    float v[8];
    float ss = 0.f;
#pragma unroll
    for (int t = 0; t < 8; ++t) {
        const int j = tid + t * 256;
        v[t] = emb[src + j];
        h[(long)row * DM + j] = v[t];
        ss += v[t] * v[t];
    }
    ss = wave_sum(ss);
    __shared__ float sp[4];
    if ((tid & 63) == 0) sp[tid >> 6] = ss;
    __syncthreads();
    ss = sp[0] + sp[1] + sp[2] + sp[3];
    const float inv = rsqrtf(ss * (1.f / DM) + EPSV);
    __hip_bfloat16* o_ = x + (long)row * DM;
#pragma unroll
    for (int t = 0; t < 8; ++t) {
        const int j = tid + t * 256;
        o_[j] = __float2bfloat16(v[t] * inv * g[j]);
    }
}

// ---------------- fused: h += sum of 4 bf16 split-K partials; x = rmsnorm(h)*g ----------------
__global__ void rmsnorm_res4_k(const __hip_bfloat16* __restrict__ part, long n,
                               float* __restrict__ h, const float* __restrict__ g,
                               __hip_bfloat16* __restrict__ x) {
    const int row = blockIdx.x;
    const int tid = threadIdx.x;
    const long base = (long)row * DM + tid * 8;
    float v[8];
    *(float4*)&v[0] = *(const float4*)(h + base);
    *(float4*)&v[4] = *(const float4*)(h + base + 4);
#pragma unroll
    for (int z = 0; z < 4; ++z) {
        union { bf16x8 vv; __hip_bfloat16 e[8]; } p;
        p.vv = *(const bf16x8*)(part + (long)z * n + base);
#pragma unroll
        for (int j = 0; j < 8; ++j) v[j] += __bfloat162float(p.e[j]);
    }
    *(float4*)(h + base) = *(float4*)&v[0];
    *(float4*)(h + base + 4) = *(float4*)&v[4];
    float ss = 0.f;
#pragma unroll
    for (int j = 0; j < 8; ++j) ss += v[j] * v[j];
    ss = wave_sum(ss);
    __shared__ float sp[4];
    if ((tid & 63) == 0) sp[tid >> 6] = ss;
    __syncthreads();
    ss = sp[0] + sp[1] + sp[2] + sp[3];
    const float inv = rsqrtf(ss * (1.f / DM) + EPSV);
    const float4 g0 = *(const float4*)(g + tid * 8);
    const float4 g1 = *(const float4*)(g + tid * 8 + 4);
    union { bf16x8 vv; __hip_bfloat16 e[8]; } o;
    o.e[0] = __float2bfloat16(v[0] * inv * g0.x); o.e[1] = __float2bfloat16(v[1] * inv * g0.y);
    o.e[2] = __float2bfloat16(v[2] * inv * g0.z); o.e[3] = __float2bfloat16(v[3] * inv * g0.w);
    o.e[4] = __float2bfloat16(v[4] * inv * g1.x); o.e[5] = __float2bfloat16(v[5] * inv * g1.y);
    o.e[6] = __float2bfloat16(v[6] * inv * g1.z); o.e[7] = __float2bfloat16(v[7] * inv * g1.w);
    *(bf16x8*)(x + base) = o.vv;
}

// ---------------- final: out = h + sum of 4 bf16 partials (writes d_out f32 directly) ----------------
__global__ void red4out_k(const __hip_bfloat16* __restrict__ p, long n,
                          const float* __restrict__ h, float* __restrict__ out) {
    const long i = ((long)blockIdx.x * 256 + threadIdx.x) * 8;
    float v[8];
    *(float4*)&v[0] = *(const float4*)(h + i);
    *(float4*)&v[4] = *(const float4*)(h + i + 4);
#pragma unroll
    for (int z = 0; z < 4; ++z) {
        union { bf16x8 vv; __hip_bfloat16 e[8]; } b;
        b.vv = *(const bf16x8*)(p + (long)z * n + i);
#pragma unroll
        for (int j = 0; j < 8; ++j) v[j] += __bfloat162float(b.e[j]);
    }
    *(float4*)(out + i) = *(float4*)&v[0];
    *(float4*)(out + i + 4) = *(float4*)&v[4];
}

// ---------------- merged QKV post-processing: q-norm+rope | k-norm+rope | v-transpose ----------------
// Role by blockIdx.x range: [0,8192) q rows, [8192,12288) k rows, [12288,12800) v tiles.
// Input = sum of 2 bf16 split-K partials (zStride apart).
__global__ void qkv_post_k(const __hip_bfloat16* __restrict__ in, long zStride,
                           const float* __restrict__ qns, const float* __restrict__ kns,
                           const float* __restrict__ cosT, const float* __restrict__ sinT,
                           __hip_bfloat16* __restrict__ qb, __hip_bfloat16* __restrict__ kb,
                           __hip_bfloat16* __restrict__ vt) {
    __shared__ float tile[64][65];
    const int bid = blockIdx.x;
    constexpr int QB = SEQ * NHEAD / 4;          // 8192
    constexpr int KB = QB + SEQ * NKVH / 4;      // 12288

    if (bid < KB) {
        // ---- q/k head-RMSNorm + RoPE (one wave per (s,head)) ----
        const bool isQ = bid < QB;
        const int nheads = isQ ? NHEAD : NKVH;
        const int inOff = isQ ? 0 : NHEAD * HDIM;
        const float* ns = isQ ? qns : kns;
        __hip_bfloat16* out = isQ ? qb : kb;
        const int idx = (isQ ? bid : bid - QB) * 4 + (threadIdx.x >> 6);
        const int lane = threadIdx.x & 63;
        const int s = idx / nheads;
        const int hh = idx - s * nheads;
        const long base = (long)s * QKVN + inOff + hh * HDIM;
        const float x1 = __bfloat162float(in[base + lane]) + __bfloat162float(in[zStride + base + lane]);
        const float x2 = __bfloat162float(in[base + lane + 64]) + __bfloat162float(in[zStride + base + lane + 64]);
        float ss = wave_sum(x1 * x1 + x2 * x2);
        const float inv = rsqrtf(ss * (1.f / HDIM) + EPSV);
        const float n1 = x1 * inv * ns[lane];
        const float n2 = x2 * inv * ns[lane + 64];
        const float c1 = cosT[s * HDIM + lane],      c2 = cosT[s * HDIM + 64 + lane];
        const float s1 = sinT[s * HDIM + lane],      s2 = sinT[s * HDIM + 64 + lane];
        __hip_bfloat16* w = out + ((long)hh * SEQ + s) * HDIM;
        w[lane]      = __float2bfloat16(n1 * c1 - n2 * s1);
        w[lane + 64] = __float2bfloat16(n2 * c2 + n1 * s2);
    } else {
        // ---- V transpose: [s][v-seg] partials -> vt [kv][d][s] ----
        const int lin = bid - KB;
        const int s0 = (lin & 31) * 64;
        const int d0 = ((lin >> 5) & 1) * 64;
        const int kv = lin >> 6;
        const int colOff = NHEAD * HDIM + NKVH * HDIM;
        const int lane = threadIdx.x & 63, part = threadIdx.x >> 6;
        for (int r = part; r < 64; r += 4) {
            const long idx = (long)(s0 + r) * QKVN + colOff + kv * HDIM + d0 + lane;
            tile[r][lane] = __bfloat162float(in[idx]) + __bfloat162float(in[zStride + idx]);
        }
        __syncthreads();
        for (int r = part; r < 64; r += 4)
            vt[((long)kv * HDIM + d0 + r) * SEQ + s0 + lane] = __float2bfloat16(tile[lane][r]);
    }
}

// ---------------- fused: out = silu(p0+p1) * (p2+p3)  (gate/up split-K partials) ----------------
__global__ void silu_red2_k(const __hip_bfloat16* __restrict__ p, long n,
                            __hip_bfloat16* __restrict__ out) {
    const long i = ((long)blockIdx.x * 256 + threadIdx.x) * 8;
    union { bf16x8 v; __hip_bfloat16 e[8]; } g0, g1, u0, u1, o;
    g0.v = *(const bf16x8*)(p + i);
    g1.v = *(const bf16x8*)(p + n + i);
    u0.v = *(const bf16x8*)(p + 2 * n + i);
    u1.v = *(const bf16x8*)(p + 3 * n + i);
#pragma unroll
    for (int j = 0; j < 8; ++j) {
        const float g = __bfloat162float(g0.e[j]) + __bfloat162float(g1.e[j]);
        const float u = __bfloat162float(u0.e[j]) + __bfloat162float(u1.e[j]);
        const float sv = g / (1.f + __expf(-g));
        o.e[j] = __float2bfloat16(sv * u);
    }
    *(bf16x8*)(out + i) = o.v;
}

// ============== flash attention v4: paired q-slabs + exact defer-max skip ==============
// Block = (slab pair, head); 4 waves; wave w owns q rows w*16..w*16+15 of the active slab.
// Slab pair (x, 31-x): 33 kv-tiles per block -- exactly uniform.
// Defer-max (THR=0, exact): when no row in the wave grew its max this tile, alpha==1
// exactly -> skip rescale bookkeeping (wave-uniform __any branch; numerics identical).
__global__ __launch_bounds__(256)
void flash_k(const __hip_bfloat16* __restrict__ qb, const __hip_bfloat16* __restrict__ kb,
             const __hip_bfloat16* __restrict__ vt, __hip_bfloat16* __restrict__ ctx) {
    __shared__ __align__(16) char ks[2][16384];   // [64 kv][128 d], swizzled
    __shared__ __align__(16) char vs[2][16384];   // [128 d][64 kv], swizzled
    __shared__ __align__(16) char ps[4][2048];    // per-wave P [16 q][64 kv], swizzled

    const int tid = threadIdx.x;
    const int lane = tid & 63;
    const int wid = tid >> 6;
    const int l15 = lane & 15;
    const int l4 = lane >> 4;

    const int h = blockIdx.y;
    const int kvh = h >> 1;          // GROUP = 2
    const float scale = 0.0883883476483184405f;  // 1/sqrt(128)

    auto stageK = [&](int buf, int kt) {
        const __hip_bfloat16* kg = kb + ((long)kvh * SEQ + kt * 64) * HDIM;
#pragma unroll
        for (int i = 0; i < 4; ++i) {
            const int c = i * 256 + tid;
            const int r = c >> 4, s = c & 15;
            gload16(kg + (long)r * HDIM + ((s ^ (r & 7)) * 8), ks[buf] + c * 16);
        }
    };
    auto stageV = [&](int buf, int kt) {
        const __hip_bfloat16* vg = vt + (long)kvh * HDIM * SEQ + kt * 64;
#pragma unroll
        for (int i = 0; i < 4; ++i) {
            const int c = i * 256 + tid;
            const int r = c >> 3, s = c & 7;
            gload16(vg + (long)r * SEQ + ((s ^ (r & 7)) * 8), vs[buf] + c * 16);
        }
    };

#pragma unroll
    for (int half = 0; half < 2; ++half) {
        const int x = half ? 31 - blockIdx.x : blockIdx.x;
        const int q0 = x * 64;
        const int nkt = x + 1;

        bf16x8 aq[4];
        {
            const __hip_bfloat16* qg = qb + ((long)h * SEQ + q0 + wid * 16 + l15) * HDIM + l4 * 8;
#pragma unroll
            for (int kk = 0; kk < 4; ++kk) aq[kk] = *(const bf16x8*)(qg + kk * 32);
        }

        float mreg[4], lreg[4];
#pragma unroll
        for (int j = 0; j < 4; ++j) { mreg[j] = -3.0e38f; lreg[j] = 0.f; }
        f32x4 oacc[8];
#pragma unroll
        for (int n = 0; n < 8; ++n) oacc[n] = (f32x4){0.f, 0.f, 0.f, 0.f};

        stageK(0, 0); stageV(0, 0);
        asm volatile("s_waitcnt vmcnt(0)" ::: "memory");
        __builtin_amdgcn_s_barrier();

        for (int kt = 0; kt < nkt; ++kt) {
            const int cur = kt & 1;
            if (kt + 1 < nkt) { stageK(cur ^ 1, kt + 1); stageV(cur ^ 1, kt + 1); }

            f32x4 sac[4];
#pragma unroll
            for (int n = 0; n < 4; ++n) sac[n] = (f32x4){0.f, 0.f, 0.f, 0.f};
            __builtin_amdgcn_s_setprio(1);
#pragma unroll
            for (int kk = 0; kk < 4; ++kk) {
#pragma unroll
                for (int n = 0; n < 4; ++n) {
                    const int r = n * 16 + l15;
                    const bf16x8 bk = *(const bf16x8*)(ks[cur] + r * 256 + (((kk * 4 + l4) ^ (r & 7)) << 4));
                    sac[n] = __builtin_amdgcn_mfma_f32_16x16x32_bf16(aq[kk], bk, sac[n], 0, 0, 0);
                }
            }
            __builtin_amdgcn_s_setprio(0);

            // ---- scale + mask + per-row max; detect wave-wide "no max growth" ----
            const bool diag = (kt + 1 == nkt);
            float mx[4];
            bool grew = false;
#pragma unroll
            for (int j = 0; j < 4; ++j) {
                float m_ = -3.0e38f;
#pragma unroll
                for (int n = 0; n < 4; ++n) {
                    float v = sac[n][j] * scale;
                    if (diag && (n * 16 + l15 > wid * 16 + l4 * 4 + j)) v = -3.0e38f;
                    sac[n][j] = v;
                    m_ = fmaxf(m_, v);
                }
#pragma unroll
                for (int o = 1; o < 16; o <<= 1) m_ = fmaxf(m_, __shfl_xor(m_, o));
                mx[j] = m_;
                grew = grew || (m_ > mreg[j]);
            }
            if (__any(grew)) {
                // full online-softmax update
#pragma unroll
                for (int j = 0; j < 4; ++j) {
                    const float mn = fmaxf(mreg[j], mx[j]);
                    const float al = __expf(mreg[j] - mn);
                    mreg[j] = mn;
                    float rs = 0.f;
#pragma unroll
                    for (int n = 0; n < 4; ++n) {
                        const float e = __expf(sac[n][j] - mn);
                        sac[n][j] = e;
                        rs += e;
                    }
#pragma unroll
                    for (int o = 1; o < 16; o <<= 1) rs += __shfl_xor(rs, o);
                    lreg[j] = lreg[j] * al + rs;
#pragma unroll
                    for (int n2 = 0; n2 < 8; ++n2) oacc[n2][j] *= al;
                }
            } else {
                // exact fast path: max unchanged -> alpha == 1, no rescale
#pragma unroll
                for (int j = 0; j < 4; ++j) {
                    float rs = 0.f;
#pragma unroll
                    for (int n = 0; n < 4; ++n) {
                        const float e = __expf(sac[n][j] - mreg[j]);
                        sac[n][j] = e;
                        rs += e;
                    }
#pragma unroll
                    for (int o = 1; o < 16; o <<= 1) rs += __shfl_xor(rs, o);
                    lreg[j] += rs;
                }
            }

            char* pw = ps[wid];
#pragma unroll
            for (int n = 0; n < 4; ++n)
#pragma unroll
                for (int j = 0; j < 4; ++j) {
                    const int r = l4 * 4 + j;
                    const int col = n * 16 + l15;
                    *(__hip_bfloat16*)(pw + r * 128 + (((col >> 3) ^ (r & 7)) << 4) + (col & 7) * 2) =
                        __float2bfloat16(sac[n][j]);
                }
            asm volatile("s_waitcnt lgkmcnt(0)" ::: "memory");
            __builtin_amdgcn_sched_barrier(0);
            __builtin_amdgcn_s_setprio(1);
#pragma unroll
            for (int kk = 0; kk < 2; ++kk) {
                const bf16x8 ap = *(const bf16x8*)(pw + l15 * 128 + (((kk * 4 + l4) ^ (l15 & 7)) << 4));
#pragma unroll
                for (int n2 = 0; n2 < 8; ++n2) {
                    const int r = n2 * 16 + l15;
                    const bf16x8 bv = *(const bf16x8*)(vs[cur] + r * 128 + (((kk * 4 + l4) ^ (r & 7)) << 4));
                    oacc[n2] = __builtin_amdgcn_mfma_f32_16x16x32_bf16(ap, bv, oacc[n2], 0, 0, 0);
                }
            }
            __builtin_amdgcn_s_setprio(0);

            asm volatile("s_waitcnt vmcnt(0)" ::: "memory");
            __builtin_amdgcn_s_barrier();
        }

#pragma unroll
        for (int j = 0; j < 4; ++j) {
            const float inv = 1.f / lreg[j];
            const long rowb = (long)(q0 + wid * 16 + l4 * 4 + j) * (NHEAD * HDIM) + h * HDIM;
#pragma unroll
            for (int n2 = 0; n2 < 8; ++n2)
                ctx[rowb + n2 * 16 + l15] = __float2bfloat16(oacc[n2][j] * inv);
        }
    }
}

// ============== 256x256 8-wave GEMM, 2-phase/K-tile; B = f32 reg-staged+cvt (R13-passing) ==============
template <int ZSEL>
__global__ __launch_bounds__(512, 2)
void g8p(const __hip_bfloat16* __restrict__ A,
         const float* __restrict__ Ba, const float* __restrict__ Bb, const float* __restrict__ Bc,
         __hip_bfloat16* __restrict__ C, int kLen, int ldA, int ldB, int ldC,
         int seg1, int seg2, long cZStride, int kZStride, int zDiv) {
    __shared__ __align__(16) char sA[2][2][16384];   // [buf][half][128 rows x 64 bf16]
    __shared__ __align__(16) char sB[2][2][16384];

    const int tid = threadIdx.x;
    const int lane = tid & 63;
    const int wid = tid >> 6;
    const int wr = wid >> 2;
    const int wc = wid & 3;
    const int l15 = lane & 15;
    const int l4 = lane >> 4;

    const int row0 = blockIdx.y * 256;
    const int col0 = blockIdx.x * 256;
    const int z = blockIdx.z;

    const float* B;
    int colB;
    if (ZSEL) {
        B = (z / zDiv) ? Bb : Ba; colB = col0;
    } else {
        if (col0 >= seg2)      { B = Bc; colB = col0 - seg2; }
        else if (col0 >= seg1) { B = Bb; colB = col0 - seg1; }
        else                   { B = Ba; colB = col0; }
    }
    const long cOff = (long)z * cZStride;
    const int k0z = (z % zDiv) * kZStride;
    const int nk = kLen / 64;

    f32x4 acc[8][4];
#pragma unroll
    for (int m = 0; m < 8; ++m)
#pragma unroll
        for (int n = 0; n < 4; ++n)
            acc[m][n] = (f32x4){0.f, 0.f, 0.f, 0.f};

    auto stageA = [&](int half, int kt) {
        const __hip_bfloat16* base = A + (long)(row0 + half * 128) * ldA;
        char* dst = sA[kt & 1][half];
        const int k0 = k0z + kt * 64;
#pragma unroll
        for (int i = 0; i < 2; ++i) {
            const int c = i * 512 + tid;
            const int r = c >> 3, s = c & 7;
            gload16(base + (long)r * ldA + k0 + ((s ^ (r & 7)) * 8), dst + c * 16);
        }
    };
    auto loadB = [&](float4* rb, int half, int kt) {
        const int k0 = k0z + kt * 64;
        const float* base = B + (long)(colB + half * 128) * ldB + k0;
#pragma unroll
        for (int i = 0; i < 2; ++i) {
            const int sidx = i * 512 + tid;
            const int r = sidx >> 3, q = sidx & 7;
            const float* p = base + (long)r * ldB + q * 8;
            rb[i * 2]     = *(const float4*)p;
            rb[i * 2 + 1] = *(const float4*)(p + 4);
        }
    };
    auto writeB = [&](const float4* rb, int half, int kt) {
        char* dst = sB[kt & 1][half];
#pragma unroll
        for (int i = 0; i < 2; ++i) {
            const int sidx = i * 512 + tid;
            const int r = sidx >> 3, q = sidx & 7;
            union { bf16x8 v; __hip_bfloat16 e[8]; } u;
            const float* f = (const float*)&rb[i * 2];
#pragma unroll
            for (int j = 0; j < 8; ++j) u.e[j] = __float2bfloat16(f[j]);
            *(bf16x8*)(dst + (r * 8 + (q ^ (r & 7))) * 16) = u.v;
        }
    };

    auto readA = [&](int buf, int p, int mm, int ks) -> bf16x8 {
        const int r = p * 32 + mm * 16 + l15;
        const int q = ks * 4 + l4;
        return *(const bf16x8*)(sA[buf][wr] + r * 128 + ((q ^ (r & 7)) << 4));
    };
    auto readB = [&](int buf, int nn, int ks) -> bf16x8 {
        const int r = (wc & 1) * 64 + nn * 16 + l15;
        const int q = ks * 4 + l4;
        return *(const bf16x8*)(sB[buf][wc >> 1] + r * 128 + ((q ^ (r & 7)) << 4));
    };

    float4 rb0[4], rb1[4];
    loadB(rb0, 0, 0);
    stageA(0, 0); stageA(1, 0);
    asm volatile("s_waitcnt vmcnt(4)" ::: "memory");
    writeB(rb0, 0, 0);
    loadB(rb1, 1, 0);
    asm volatile("s_waitcnt vmcnt(0)" ::: "memory");
    writeB(rb1, 1, 0);
    if (nk > 1) { loadB(rb0, 0, 1); loadB(rb1, 1, 1); }
    asm volatile("s_waitcnt lgkmcnt(0)" ::: "memory");
    __builtin_amdgcn_sched_barrier(0);
    __builtin_amdgcn_s_barrier();

    bf16x8 bfrag[4][2];
    for (int t = 0; t < nk; ++t) {
        const int cur = t & 1;

        // ======== phase 0: A-quads 0,1 + all B; stage tile t+1 ========
        {
            bf16x8 a0[2][2], a1[2][2];
            a0[0][0] = readA(cur, 0, 0, 0); a0[0][1] = readA(cur, 0, 0, 1);
            a0[1][0] = readA(cur, 0, 1, 0); a0[1][1] = readA(cur, 0, 1, 1);
            a1[0][0] = readA(cur, 1, 0, 0); a1[0][1] = readA(cur, 1, 0, 1);
            a1[1][0] = readA(cur, 1, 1, 0); a1[1][1] = readA(cur, 1, 1, 1);
#pragma unroll
            for (int n = 0; n < 4; ++n) {
                bfrag[n][0] = readB(cur, n, 0);
                bfrag[n][1] = readB(cur, n, 1);
            }
            if (t + 1 < nk) {
                writeB(rb0, 0, t + 1);
                writeB(rb1, 1, t + 1);
                stageA(0, t + 1);
                stageA(1, t + 1);
            }
            asm volatile("s_waitcnt lgkmcnt(8)" ::: "memory");
            __builtin_amdgcn_sched_barrier(0);
            __builtin_amdgcn_s_barrier();
            asm volatile("s_waitcnt lgkmcnt(0)" ::: "memory");
            __builtin_amdgcn_sched_barrier(0);

            __builtin_amdgcn_s_setprio(1);
#pragma unroll
            for (int ks = 0; ks < 2; ++ks) {
#pragma unroll
                for (int mm = 0; mm < 2; ++mm)
#pragma unroll
                    for (int n = 0; n < 4; ++n)
                        acc[mm][n] = __builtin_amdgcn_mfma_f32_16x16x32_bf16(
                            a0[mm][ks], bfrag[n][ks], acc[mm][n], 0, 0, 0);
#pragma unroll
                for (int mm = 0; mm < 2; ++mm)
#pragma unroll
                    for (int n = 0; n < 4; ++n)
                        acc[2 + mm][n] = __builtin_amdgcn_mfma_f32_16x16x32_bf16(
                            a1[mm][ks], bfrag[n][ks], acc[2 + mm][n], 0, 0, 0);
            }
            __builtin_amdgcn_s_setprio(0);
            __builtin_amdgcn_sched_barrier(0);
            __builtin_amdgcn_s_barrier();
        }

        // ======== phase 1: A-quads 2,3; issue B(t+2) reg-loads; counted vmcnt ========
        {
            bf16x8 a2[2][2], a3[2][2];
            a2[0][0] = readA(cur, 2, 0, 0); a2[0][1] = readA(cur, 2, 0, 1);
            a2[1][0] = readA(cur, 2, 1, 0); a2[1][1] = readA(cur, 2, 1, 1);
            a3[0][0] = readA(cur, 3, 0, 0); a3[0][1] = readA(cur, 3, 0, 1);
            a3[1][0] = readA(cur, 3, 1, 0); a3[1][1] = readA(cur, 3, 1, 1);
            if (t + 2 < nk) {
                loadB(rb0, 0, t + 2);
                loadB(rb1, 1, t + 2);
            }
            __builtin_amdgcn_sched_barrier(0);
            if (t + 2 < nk)      asm volatile("s_waitcnt vmcnt(8)" ::: "memory");
            else if (t + 1 < nk) asm volatile("s_waitcnt vmcnt(0)" ::: "memory");
            __builtin_amdgcn_s_barrier();
            asm volatile("s_waitcnt lgkmcnt(0)" ::: "memory");
            __builtin_amdgcn_sched_barrier(0);

            __builtin_amdgcn_s_setprio(1);
#pragma unroll
            for (int ks = 0; ks < 2; ++ks) {
#pragma unroll
                for (int mm = 0; mm < 2; ++mm)
#pragma unroll
                    for (int n = 0; n < 4; ++n)
                        acc[4 + mm][n] = __builtin_amdgcn_mfma_f32_16x16x32_bf16(
                            a2[mm][ks], bfrag[n][ks], acc[4 + mm][n], 0, 0, 0);
#pragma unroll
                for (int mm = 0; mm < 2; ++mm)
#pragma unroll
                    for (int n = 0; n < 4; ++n)
                        acc[6 + mm][n] = __builtin_amdgcn_mfma_f32_16x16x32_bf16(
                            a3[mm][ks], bfrag[n][ks], acc[6 + mm][n], 0, 0, 0);
            }
            __builtin_amdgcn_s_setprio(0);
            __builtin_amdgcn_sched_barrier(0);
            __builtin_amdgcn_s_barrier();
        }
    }

    // epilogue: C/D layout col = lane&15, row = (lane>>4)*4 + reg (m89-verified)
#pragma unroll
    for (int m = 0; m < 8; ++m) {
#pragma unroll
        for (int n = 0; n < 4; ++n) {
            const int rb = row0 + wr * 128 + m * 16 + l4 * 4;
            const int cc = col0 + wc * 64 + n * 16 + l15;
#pragma unroll
            for (int j = 0; j < 4; ++j)
                C[cOff + (long)(rb + j) * ldC + cc] = __float2bfloat16(acc[m][n][j]);
        }
    }
}

// ---------------- host orchestration ----------------
extern "C" void kernel_launch(void* const* d_in, const int* in_sizes, int n_in,
                              void* d_out, int out_size, void* d_ws, size_t ws_size,
                              hipStream_t stream) {
    const int*   ids  = (const int*)d_in[0];
    const float* cosT = (const float*)d_in[2];
    const float* sinT = (const float*)d_in[3];
    const float* emb  = (const float*)d_in[4];
    const float* q_w  = (const float*)d_in[5];
    const float* k_w  = (const float*)d_in[6];
    const float* v_w  = (const float*)d_in[7];
    const float* o_w  = (const float*)d_in[8];
    const float* qn   = (const float*)d_in[9];
    const float* kn   = (const float*)d_in[10];
    const float* ln1  = (const float*)d_in[11];
    const float* ln2  = (const float*)d_in[12];
    const float* gw   = (const float*)d_in[13];
    const float* uw   = (const float*)d_in[14];
    const float* dw   = (const float*)d_in[15];

    char* W = (char*)d_ws;
    size_t off = 0;
    auto take = [&](size_t nb) { char* p = W + off; off += (nb + 255) & ~(size_t)255; return p; };

    float*          h    = (float*)          take((size_t)SEQ * DM * 4);
    __hip_bfloat16* x    = (__hip_bfloat16*) take((size_t)SEQ * DM * 2);
    __hip_bfloat16* part = (__hip_bfloat16*) take((size_t)4 * SEQ * FFN * 2);
    __hip_bfloat16* qb   = (__hip_bfloat16*) take((size_t)NHEAD * SEQ * HDIM * 2);
    __hip_bfloat16* kb   = (__hip_bfloat16*) take((size_t)NKVH * SEQ * HDIM * 2);
    __hip_bfloat16* vt   = (__hip_bfloat16*) take((size_t)NKVH * HDIM * SEQ * 2);
    __hip_bfloat16* ctx  = (__hip_bfloat16*) take((size_t)SEQ * NHEAD * HDIM * 2);
    __hip_bfloat16* go   = (__hip_bfloat16*) take((size_t)SEQ * FFN * 2);
    if (off > ws_size) return;

    embed_rms_k<<<SEQ, 256, 0, stream>>>(ids, emb, ln1, h, x);

    const long nQKV = (long)SEQ * QKVN;
    const long nDM  = (long)SEQ * DM;
    const long nFFN = (long)SEQ * FFN;
    const int BIG = 1 << 30;
    const int POST_BLOCKS = SEQ * NHEAD / 4 + SEQ * NKVH / 4 + (SEQ / 64) * (HDIM / 64) * NKVH;

    for (int l = 0; l < NLAYER; ++l) {
        const float* qwl = q_w + (size_t)l * (NHEAD * HDIM) * DM;
        const float* kwl = k_w + (size_t)l * (NKVH * HDIM) * DM;
        const float* vwl = v_w + (size_t)l * (NKVH * HDIM) * DM;
        const float* owl = o_w + (size_t)l * DM * (NHEAD * HDIM);
        const float* gwl = gw  + (size_t)l * FFN * DM;
        const float* uwl = uw  + (size_t)l * FFN * DM;
        const float* dwl = dw  + (size_t)l * DM * FFN;

        // QKV fused (col segments q|k|v): split-K x2 -> bf16 partials
        g8p<0><<<dim3(QKVN / 256, SEQ / 256, 2), 512, 0, stream>>>(
            x, qwl, kwl, vwl, part, DM / 2, DM, DM, QKVN,
            NHEAD * HDIM, NHEAD * HDIM + NKVH * HDIM, nQKV, DM / 2, 2);

        // merged q-norm+rope | k-norm+rope | v-transpose
        qkv_post_k<<<POST_BLOCKS, 256, 0, stream>>>(
            part, nQKV, qn + l * HDIM, kn + l * HDIM, cosT, sinT, qb, kb, vt);

        // flash attention v4: 16 slab-pairs x 16 heads = 256 blocks
        flash_k<<<dim3(16, NHEAD), 256, 0, stream>>>(qb, kb, vt, ctx);

        // O: split-K x4 -> fused (h += sum; x = rmsnorm(h)*ln2)
        g8p<0><<<dim3(DM / 256, SEQ / 256, 4), 512, 0, stream>>>(
            ctx, owl, owl, owl, part, (NHEAD * HDIM) / 4, NHEAD * HDIM, NHEAD * HDIM, DM,
            BIG, BIG, nDM, (NHEAD * HDIM) / 4, 4);
        rmsnorm_res4_k<<<SEQ, 256, 0, stream>>>(part, nDM, h, ln2 + l * DM, x);

        // gate+up: z/2 selects weight, z%2 selects K-half -> 768 blocks
        g8p<1><<<dim3(FFN / 256, SEQ / 256, 4), 512, 0, stream>>>(
            x, gwl, uwl, uwl, part, DM / 2, DM, DM, FFN,
            BIG, BIG, nFFN, DM / 2, 2);
        silu_red2_k<<<(int)(nFFN / 2048), 256, 0, stream>>>(part, nFFN, go);

        // down: split-K x4 -> fused with next layer's ln1 (or final reduce -> d_out)
        g8p<0><<<dim3(DM / 256, SEQ / 256, 4), 512, 0, stream>>>(
            go, dwl, dwl, dwl, part, FFN / 4, FFN, FFN, DM,
            BIG, BIG, nDM, FFN / 4, 4);
        if (l + 1 < NLAYER)
            rmsnorm_res4_k<<<SEQ, 256, 0, stream>>>(part, nDM, h, ln1 + (l + 1) * DM, x);
        else
            red4out_k<<<(int)(nDM / 2048), 256, 0, stream>>>(part, nDM, h, (float*)d_out);
    }
}